// Round 1
// baseline (2796.742 us; speedup 1.0000x reference)
//
#include <hip/hip_runtime.h>
#include <math.h>

#define SDIM 1024
#define COUT 256

#define EPSV     1e-4f
#define SILU_INV 1.6778523489932886f   // 1/0.596
#define MPA      0.9191450300180579f   // 0.7/sqrt(0.58)
#define MPB      0.3939192985791677f   // 0.3/sqrt(0.58)

// ---------------- weight normalization: wn = w * gain / (EPS*sqrt(fanin) + ||row||)
__global__ __launch_bounds__(256) void wnorm(const float* __restrict__ w,
                                             float* __restrict__ wn,
                                             int fanin,
                                             const float* __restrict__ gain_ptr)
{
    int o = blockIdx.x;
    const float* row = w + (size_t)o * fanin;
    float ss = 0.f;
    for (int i = threadIdx.x; i < fanin; i += 256) { float v = row[i]; ss += v * v; }
    for (int off = 32; off >= 1; off >>= 1) ss += __shfl_down(ss, off);
    __shared__ float red[4];
    int lane = threadIdx.x & 63, wv = threadIdx.x >> 6;
    if (lane == 0) red[wv] = ss;
    __syncthreads();
    float tot = red[0] + red[1] + red[2] + red[3];
    float gain = gain_ptr ? *gain_ptr : 1.0f;
    float scale = gain / (EPSV * sqrtf((float)fanin) + sqrtf(tot));
    for (int i = threadIdx.x; i < fanin; i += 256)
        wn[(size_t)o * fanin + i] = row[i] * scale;
}

// ---------------- c = emb @ wemb_n^T + 1
__global__ __launch_bounds__(256) void emb_mm(const float* __restrict__ emb,
                                              const float* __restrict__ wemb,
                                              float* __restrict__ cvec)
{
    int n = blockIdx.x;
    int co = threadIdx.x;
    const float* e  = emb  + (size_t)n * 768;
    const float* wr = wemb + (size_t)co * 768;
    float s = 0.f;
    for (int i = 0; i < 768; i++) s = fmaf(e[i], wr[i], s);
    cvec[n * COUT + co] = s + 1.0f;
}

// ---------------- pixel norm over 256 channels, in place
__global__ __launch_bounds__(256) void pix_norm(float* x)
{
    int g = blockIdx.x * 256 + threadIdx.x;       // over N*S
    int n = g >> 10, s = g & 1023;
    float* base = x + (size_t)n * COUT * SDIM + s;
    float ss = 0.f;
    for (int c = 0; c < COUT; c++) { float v = base[(size_t)c * SDIM]; ss += v * v; }
    float sc = 1.0f / (EPSV + sqrtf(ss) * (1.0f / 16.0f));
    for (int c = 0; c < COUT; c++) base[(size_t)c * SDIM] *= sc;
}

// ---------------- qkv norm over 64 channels per (n,head,t,s), in place
__global__ __launch_bounds__(256) void qkv_norm(float* qkv)
{
    int g = blockIdx.x * 256 + threadIdx.x;       // over N*4*3*S
    int s = g & 1023;
    int rem = g >> 10;                            // n*12 + head*3 + t
    int t = rem % 3;
    int rem2 = rem / 3;
    int head = rem2 & 3;
    int n = rem2 >> 2;
    float* base = qkv + (size_t)n * 768 * SDIM + (size_t)(head * 192 + t) * SDIM + s;
    float ss = 0.f;
    for (int c = 0; c < 64; c++) { float v = base[(size_t)c * 3 * SDIM]; ss += v * v; }
    float sc = 1.0f / (EPSV + sqrtf(ss) * 0.125f);
    for (int c = 0; c < 64; c++) base[(size_t)c * 3 * SDIM] *= sc;
}

// ---------------- generic conv-as-GEMM: C[n;co,s] = sum_k W[co,k] * im2col(X)[n;k,s]
// MODE 0: plain store. 1: *cvec. 2: mp_sum with resid (store to Out). 3: mp_sum + clip.
template<int KSIZE, int MODE, bool SILU>
__global__ __launch_bounds__(256) void conv_gemm(
    const float* __restrict__ W,    // [Co, K]
    const float* __restrict__ X,    // [N, Ci, 32, 32]
    float* Out,                     // [N, Co, 32, 32]
    const float* __restrict__ cvec, // [N, 256]
    const float* resid,             // [N, 256, 32, 32]
    int Ci, int Co)
{
    const int K   = Ci * KSIZE * KSIZE;
    const int n   = blockIdx.z;
    const int co0 = blockIdx.y * 64;
    const int s0  = blockIdx.x * 64;
    const int tid = threadIdx.x;
    const int tx = tid & 15, ty = tid >> 4;

    __shared__ float As[16][65];
    __shared__ float Bs[16][64];

    const float* Xn = X + (size_t)n * Ci * SDIM;

    float acc[4][4];
#pragma unroll
    for (int a = 0; a < 4; a++)
#pragma unroll
        for (int b = 0; b < 4; b++) acc[a][b] = 0.f;

    const int arow = tid >> 4;
    const int akk  = tid & 15;

    for (int k0 = 0; k0 < K; k0 += 16) {
#pragma unroll
        for (int i = 0; i < 4; i++) {
            int co = arow + i * 16;
            As[akk][co] = W[(size_t)(co0 + co) * K + (k0 + akk)];
        }
#pragma unroll
        for (int i = 0; i < 4; i++) {
            int flat = tid + i * 256;
            int kk = flat >> 6;
            int ss = flat & 63;
            int k = k0 + kk;
            float v;
            if (KSIZE == 1) {
                v = Xn[(size_t)k * SDIM + s0 + ss];
            } else {
                int ci = k / 9;
                int r  = k - ci * 9;
                int r3 = r / 3;
                int dy = r3 - 1, dx = (r - r3 * 3) - 1;
                int sp = s0 + ss;
                int h = (sp >> 5) + dy, w = (sp & 31) + dx;
                v = ((unsigned)h < 32u && (unsigned)w < 32u)
                        ? Xn[(size_t)ci * SDIM + (h << 5) + w] : 0.f;
            }
            if (SILU) v = v * SILU_INV / (1.f + __expf(-v));
            Bs[kk][ss] = v;
        }
        __syncthreads();
#pragma unroll
        for (int kk = 0; kk < 16; kk++) {
            float a[4], b[4];
#pragma unroll
            for (int m = 0; m < 4; m++) a[m] = As[kk][ty + m * 16];
#pragma unroll
            for (int nn = 0; nn < 4; nn++) b[nn] = Bs[kk][tx + nn * 16];
#pragma unroll
            for (int m = 0; m < 4; m++)
#pragma unroll
                for (int nn = 0; nn < 4; nn++)
                    acc[m][nn] = fmaf(a[m], b[nn], acc[m][nn]);
        }
        __syncthreads();
    }

    float cm[4];
    if (MODE == 1) {
#pragma unroll
        for (int m = 0; m < 4; m++) cm[m] = cvec[n * COUT + co0 + ty + m * 16];
    }
    float rv[4][4];
    if (MODE == 2 || MODE == 3) {
#pragma unroll
        for (int m = 0; m < 4; m++) {
            int co = co0 + ty + m * 16;
#pragma unroll
            for (int nn = 0; nn < 4; nn++)
                rv[m][nn] = resid[(size_t)n * COUT * SDIM + (size_t)co * SDIM + s0 + tx + nn * 16];
        }
    }
#pragma unroll
    for (int m = 0; m < 4; m++) {
        int co = co0 + ty + m * 16;
#pragma unroll
        for (int nn = 0; nn < 4; nn++) {
            int sp = s0 + tx + nn * 16;
            size_t idx = (size_t)n * Co * SDIM + (size_t)co * SDIM + sp;
            float v = acc[m][nn];
            if (MODE == 1) v *= cm[m];
            if (MODE == 2) v = MPA * rv[m][nn] + MPB * v;
            if (MODE == 3) {
                v = MPA * rv[m][nn] + MPB * v;
                v = fminf(fmaxf(v, -256.f), 256.f);
            }
            Out[idx] = v;
        }
    }
}

// ---------------- flash attention: one block per (n, head, 64-query tile)
__global__ __launch_bounds__(256) void attn(const float* __restrict__ qkv, float* out)
{
    const int n = blockIdx.z, head = blockIdx.y, q0 = blockIdx.x * 64;
    const int tid = threadIdx.x, tx = tid & 15, ty = tid >> 4;

    __shared__ float Qs[64 * 64];   // [c][i]
    __shared__ float Ks[64 * 32];   // [c][j]
    __shared__ float Vs[32 * 65];   // [j][c] padded
    __shared__ float Ps[64 * 33];   // [i][j] padded

    const float* base = qkv + (size_t)n * 768 * SDIM + (size_t)head * 192 * SDIM;

#pragma unroll
    for (int it = 0; it < 16; it++) {
        int flat = tid + it * 256;
        int c = flat >> 6, i = flat & 63;
        Qs[c * 64 + i] = base[(size_t)(c * 3) * SDIM + q0 + i];
    }

    float acc[4][4];
#pragma unroll
    for (int a = 0; a < 4; a++)
#pragma unroll
        for (int b = 0; b < 4; b++) acc[a][b] = 0.f;
    float mrow[4], lrow[4];
#pragma unroll
    for (int m_ = 0; m_ < 4; m_++) { mrow[m_] = -1e30f; lrow[m_] = 0.f; }

    for (int kt = 0; kt < 32; kt++) {
        int k0 = kt * 32;
        __syncthreads();
#pragma unroll
        for (int it = 0; it < 8; it++) {
            int flat = tid + it * 256;
            int c = flat >> 5, j = flat & 31;
            Ks[c * 32 + j] = base[(size_t)(c * 3 + 1) * SDIM + k0 + j];
        }
#pragma unroll
        for (int it = 0; it < 8; it++) {
            int flat = tid + it * 256;
            int c = flat >> 5, j = flat & 31;
            Vs[j * 65 + c] = base[(size_t)(c * 3 + 2) * SDIM + k0 + j];
        }
        __syncthreads();

        float sc[4][2];
#pragma unroll
        for (int m_ = 0; m_ < 4; m_++) { sc[m_][0] = 0.f; sc[m_][1] = 0.f; }
        for (int c = 0; c < 64; c++) {
            float a[4], b[2];
#pragma unroll
            for (int m_ = 0; m_ < 4; m_++) a[m_] = Qs[c * 64 + ty + m_ * 16];
#pragma unroll
            for (int n_ = 0; n_ < 2; n_++) b[n_] = Ks[c * 32 + tx + n_ * 16];
#pragma unroll
            for (int m_ = 0; m_ < 4; m_++)
#pragma unroll
                for (int n_ = 0; n_ < 2; n_++)
                    sc[m_][n_] = fmaf(a[m_], b[n_], sc[m_][n_]);
        }
#pragma unroll
        for (int m_ = 0; m_ < 4; m_++) {
            float s0v = sc[m_][0] * 0.125f;
            float s1v = sc[m_][1] * 0.125f;
            float tmax = fmaxf(s0v, s1v);
            for (int off = 1; off < 16; off <<= 1)
                tmax = fmaxf(tmax, __shfl_xor(tmax, off));
            float mnew  = fmaxf(mrow[m_], tmax);
            float alpha = __expf(mrow[m_] - mnew);
            float p0 = __expf(s0v - mnew);
            float p1 = __expf(s1v - mnew);
            float rs = p0 + p1;
            for (int off = 1; off < 16; off <<= 1)
                rs += __shfl_xor(rs, off);
            lrow[m_] = lrow[m_] * alpha + rs;
            mrow[m_] = mnew;
            int ii = ty + m_ * 16;
            Ps[ii * 33 + tx]      = p0;
            Ps[ii * 33 + tx + 16] = p1;
#pragma unroll
            for (int n_ = 0; n_ < 4; n_++) acc[m_][n_] *= alpha;
        }
        __syncthreads();
        for (int j = 0; j < 32; j++) {
            float v[4], pr[4];
#pragma unroll
            for (int n_ = 0; n_ < 4; n_++) v[n_] = Vs[j * 65 + tx + n_ * 16];
#pragma unroll
            for (int m_ = 0; m_ < 4; m_++) pr[m_] = Ps[(ty + m_ * 16) * 33 + j];
#pragma unroll
            for (int m_ = 0; m_ < 4; m_++)
#pragma unroll
                for (int n_ = 0; n_ < 4; n_++)
                    acc[m_][n_] = fmaf(pr[m_], v[n_], acc[m_][n_]);
        }
    }

    __syncthreads();
    // stage output (transpose) through Qs, then coalesced global write
#pragma unroll
    for (int m_ = 0; m_ < 4; m_++) {
        float inv = 1.0f / lrow[m_];
        int ii = ty + m_ * 16;
#pragma unroll
        for (int n_ = 0; n_ < 4; n_++) {
            int cc = tx + n_ * 16;
            Qs[cc * 64 + ii] = acc[m_][n_] * inv;
        }
    }
    __syncthreads();
    float* obase = out + (size_t)n * COUT * SDIM + (size_t)(head * 64) * SDIM + q0;
#pragma unroll
    for (int it = 0; it < 16; it++) {
        int flat = tid + it * 256;
        int cc = flat >> 6, ii = flat & 63;
        obase[(size_t)cc * SDIM + ii] = Qs[cc * 64 + ii];
    }
}

extern "C" void kernel_launch(void* const* d_in, const int* in_sizes, int n_in,
                              void* d_out, int out_size, void* d_ws, size_t ws_size,
                              hipStream_t stream)
{
    const float* x      = (const float*)d_in[0];
    const float* emb    = (const float*)d_in[1];
    const float* w_skip = (const float*)d_in[2];
    const float* w_res0 = (const float*)d_in[3];
    const float* w_res1 = (const float*)d_in[4];
    const float* w_emb  = (const float*)d_in[5];
    const float* e_gain = (const float*)d_in[6];
    const float* w_qkv  = (const float*)d_in[7];
    const float* w_proj = (const float*)d_in[8];
    float* out = (float*)d_out;

    float* p = (float*)d_ws;
    float* wskip_n = p; p += 256 * 192;
    float* wres0_n = p; p += 256 * 2304;
    float* wres1_n = p; p += 256 * 2304;
    float* wemb_n  = p; p += 256 * 768;
    float* wqkv_n  = p; p += 768 * 256;
    float* wproj_n = p; p += 256 * 256;
    float* cvec    = p; p += 16 * 256;
    float* xn      = p; p += (size_t)16 * 256 * 1024;
    float* ybuf    = p; p += (size_t)16 * 256 * 1024;
    float* qkvb    = p; p += (size_t)16 * 768 * 1024;

    wnorm<<<256, 256, 0, stream>>>(w_skip, wskip_n, 192, nullptr);
    wnorm<<<256, 256, 0, stream>>>(w_res0, wres0_n, 2304, nullptr);
    wnorm<<<256, 256, 0, stream>>>(w_res1, wres1_n, 2304, nullptr);
    wnorm<<<256, 256, 0, stream>>>(w_emb,  wemb_n,  768, e_gain);
    wnorm<<<768, 256, 0, stream>>>(w_qkv,  wqkv_n,  256, nullptr);
    wnorm<<<256, 256, 0, stream>>>(w_proj, wproj_n, 256, nullptr);

    emb_mm<<<16, 256, 0, stream>>>(emb, wemb_n, cvec);

    // x1 = conv1x1(x, w_skip_n) -> xn
    conv_gemm<1, 0, false><<<dim3(16, 4, 16), 256, 0, stream>>>(wskip_n, x, xn, nullptr, nullptr, 192, 256);
    // pixel norm in place
    pix_norm<<<64, 256, 0, stream>>>(xn);
    // y = conv3x3(silu(xn), w_res0_n) * c -> ybuf
    conv_gemm<3, 1, true><<<dim3(16, 4, 16), 256, 0, stream>>>(wres0_n, xn, ybuf, cvec, nullptr, 256, 256);
    // x2 = mp_sum(xn, conv3x3(silu(ybuf), w_res1_n)) -> xn (in place)
    conv_gemm<3, 2, true><<<dim3(16, 4, 16), 256, 0, stream>>>(wres1_n, ybuf, xn, nullptr, xn, 256, 256);
    // qkv = conv1x1(xn, w_qkv_n) -> qkvb
    conv_gemm<1, 0, false><<<dim3(16, 12, 16), 256, 0, stream>>>(wqkv_n, xn, qkvb, nullptr, nullptr, 256, 768);
    // normalize qkv per (n,h,t,s) over 64 channels
    qkv_norm<<<768, 256, 0, stream>>>(qkvb);
    // attention -> ybuf
    attn<<<dim3(16, 4, 16), 256, 0, stream>>>(qkvb, ybuf);
    // out = clip(mp_sum(xn, conv1x1(ybuf, w_proj_n)))
    conv_gemm<1, 3, false><<<dim3(16, 4, 16), 256, 0, stream>>>(wproj_n, ybuf, out, nullptr, xn, 256, 256);
}

// Round 2
// 1461.655 us; speedup vs baseline: 1.9134x; 1.9134x over previous
//
#include <hip/hip_runtime.h>
#include <math.h>

#define SDIM 1024
#define COUT 256

#define EPSV     1e-4f
#define SILU_INV 1.6778523489932886f   // 1/0.596
#define MPA      0.9191450300180579f   // 0.7/sqrt(0.58)
#define MPB      0.3939192985791677f   // 0.3/sqrt(0.58)

typedef short s16x8 __attribute__((ext_vector_type(8)));
typedef float f32x4 __attribute__((ext_vector_type(4)));

__device__ inline unsigned short f2bs(float f) {
    unsigned u = __float_as_uint(f);
    u += 0x7fffu + ((u >> 16) & 1u);        // round-nearest-even
    return (unsigned short)(u >> 16);
}

union F8 { s16x8 v; uint2 d[2]; };

__device__ inline s16x8 ldsA(const unsigned short* p) {
    F8 r;
    r.d[0] = *(const uint2*)p;
    r.d[1] = *(const uint2*)(p + 4);
    return r.v;
}

// ---------------- weight normalization: wn = w * gain / (EPS*sqrt(fanin) + ||row||)
__global__ __launch_bounds__(256) void wnorm(const float* __restrict__ w,
                                             float* __restrict__ wn,
                                             int fanin,
                                             const float* __restrict__ gain_ptr)
{
    int o = blockIdx.x;
    const float* row = w + (size_t)o * fanin;
    float ss = 0.f;
    for (int i = threadIdx.x; i < fanin; i += 256) { float v = row[i]; ss += v * v; }
    for (int off = 32; off >= 1; off >>= 1) ss += __shfl_down(ss, off);
    __shared__ float red[4];
    int lane = threadIdx.x & 63, wv = threadIdx.x >> 6;
    if (lane == 0) red[wv] = ss;
    __syncthreads();
    float tot = red[0] + red[1] + red[2] + red[3];
    float gain = gain_ptr ? *gain_ptr : 1.0f;
    float scale = gain / (EPSV * sqrtf((float)fanin) + sqrtf(tot));
    for (int i = threadIdx.x; i < fanin; i += 256)
        wn[(size_t)o * fanin + i] = row[i] * scale;
}

// ---------------- c = emb @ wemb_n^T + 1
__global__ __launch_bounds__(256) void emb_mm(const float* __restrict__ emb,
                                              const float* __restrict__ wemb,
                                              float* __restrict__ cvec)
{
    int n = blockIdx.x;
    int co = threadIdx.x;
    const float* e  = emb  + (size_t)n * 768;
    const float* wr = wemb + (size_t)co * 768;
    float s = 0.f;
    for (int i = 0; i < 768; i++) s = fmaf(e[i], wr[i], s);
    cvec[n * COUT + co] = s + 1.0f;
}

// ---------------- pixel norm over 256 channels, in place
__global__ __launch_bounds__(256) void pix_norm(float* x)
{
    int g = blockIdx.x * 256 + threadIdx.x;       // over N*S
    int n = g >> 10, s = g & 1023;
    float* base = x + (size_t)n * COUT * SDIM + s;
    float ss = 0.f;
    for (int c = 0; c < COUT; c++) { float v = base[(size_t)c * SDIM]; ss += v * v; }
    float sc = 1.0f / (EPSV + sqrtf(ss) * (1.0f / 16.0f));
    for (int c = 0; c < COUT; c++) base[(size_t)c * SDIM] *= sc;
}

// ---------------- qkv norm over 64 channels per (n,head,t,s), in place.
// q additionally pre-scaled by 1/8 (attention score scale).
__global__ __launch_bounds__(256) void qkv_norm(float* qkv)
{
    int g = blockIdx.x * 256 + threadIdx.x;       // over N*4*3*S
    int s = g & 1023;
    int rem = g >> 10;                            // n*12 + head*3 + t
    int t = rem % 3;
    int rem2 = rem / 3;
    int head = rem2 & 3;
    int n = rem2 >> 2;
    float* base = qkv + (size_t)n * 768 * SDIM + (size_t)(head * 192 + t) * SDIM + s;
    float ss = 0.f;
    for (int c = 0; c < 64; c++) { float v = base[(size_t)c * 3 * SDIM]; ss += v * v; }
    float sc = 1.0f / (EPSV + sqrtf(ss) * 0.125f);
    if (t == 0) sc *= 0.125f;
    for (int c = 0; c < 64; c++) base[(size_t)c * 3 * SDIM] *= sc;
}

// ---------------- generic conv-as-GEMM: C[n;co,s] = sum_k W[co,k] * im2col(X)[n;k,s]
// MODE 0: plain store. 1: *cvec. 2: mp_sum with resid (store to Out). 3: mp_sum + clip.
template<int KSIZE, int MODE, bool SILU>
__global__ __launch_bounds__(256) void conv_gemm(
    const float* __restrict__ W,    // [Co, K]
    const float* __restrict__ X,    // [N, Ci, 32, 32]
    float* Out,                     // [N, Co, 32, 32]
    const float* __restrict__ cvec, // [N, 256]
    const float* resid,             // [N, 256, 32, 32]
    int Ci, int Co)
{
    const int K   = Ci * KSIZE * KSIZE;
    const int n   = blockIdx.z;
    const int co0 = blockIdx.y * 64;
    const int s0  = blockIdx.x * 64;
    const int tid = threadIdx.x;
    const int tx = tid & 15, ty = tid >> 4;

    __shared__ float As[16][65];
    __shared__ float Bs[16][64];

    const float* Xn = X + (size_t)n * Ci * SDIM;

    float acc[4][4];
#pragma unroll
    for (int a = 0; a < 4; a++)
#pragma unroll
        for (int b = 0; b < 4; b++) acc[a][b] = 0.f;

    const int arow = tid >> 4;
    const int akk  = tid & 15;

    for (int k0 = 0; k0 < K; k0 += 16) {
#pragma unroll
        for (int i = 0; i < 4; i++) {
            int co = arow + i * 16;
            As[akk][co] = W[(size_t)(co0 + co) * K + (k0 + akk)];
        }
#pragma unroll
        for (int i = 0; i < 4; i++) {
            int flat = tid + i * 256;
            int kk = flat >> 6;
            int ss = flat & 63;
            int k = k0 + kk;
            float v;
            if (KSIZE == 1) {
                v = Xn[(size_t)k * SDIM + s0 + ss];
            } else {
                int ci = k / 9;
                int r  = k - ci * 9;
                int r3 = r / 3;
                int dy = r3 - 1, dx = (r - r3 * 3) - 1;
                int sp = s0 + ss;
                int h = (sp >> 5) + dy, w = (sp & 31) + dx;
                v = ((unsigned)h < 32u && (unsigned)w < 32u)
                        ? Xn[(size_t)ci * SDIM + (h << 5) + w] : 0.f;
            }
            if (SILU) v = v * SILU_INV / (1.f + __expf(-v));
            Bs[kk][ss] = v;
        }
        __syncthreads();
#pragma unroll
        for (int kk = 0; kk < 16; kk++) {
            float a[4], b[4];
#pragma unroll
            for (int m = 0; m < 4; m++) a[m] = As[kk][ty + m * 16];
#pragma unroll
            for (int nn = 0; nn < 4; nn++) b[nn] = Bs[kk][tx + nn * 16];
#pragma unroll
            for (int m = 0; m < 4; m++)
#pragma unroll
                for (int nn = 0; nn < 4; nn++)
                    acc[m][nn] = fmaf(a[m], b[nn], acc[m][nn]);
        }
        __syncthreads();
    }

    float cm[4];
    if (MODE == 1) {
#pragma unroll
        for (int m = 0; m < 4; m++) cm[m] = cvec[n * COUT + co0 + ty + m * 16];
    }
    float rv[4][4];
    if (MODE == 2 || MODE == 3) {
#pragma unroll
        for (int m = 0; m < 4; m++) {
            int co = co0 + ty + m * 16;
#pragma unroll
            for (int nn = 0; nn < 4; nn++)
                rv[m][nn] = resid[(size_t)n * COUT * SDIM + (size_t)co * SDIM + s0 + tx + nn * 16];
        }
    }
#pragma unroll
    for (int m = 0; m < 4; m++) {
        int co = co0 + ty + m * 16;
#pragma unroll
        for (int nn = 0; nn < 4; nn++) {
            int sp = s0 + tx + nn * 16;
            size_t idx = (size_t)n * Co * SDIM + (size_t)co * SDIM + sp;
            float v = acc[m][nn];
            if (MODE == 1) v *= cm[m];
            if (MODE == 2) v = MPA * rv[m][nn] + MPB * v;
            if (MODE == 3) {
                v = MPA * rv[m][nn] + MPB * v;
                v = fminf(fmaxf(v, -256.f), 256.f);
            }
            Out[idx] = v;
        }
    }
}

// ---------------- MFMA flash attention.
// Block = (qtile of 256, head, n); 4 waves, wave w owns q in [q0+64w, q0+64w+64).
// No running-max: |score| <= 8 guaranteed by normalization, exp() is fp32-safe.
__global__ __launch_bounds__(256, 1) void attn_mfma(const float* __restrict__ qkv,
                                                    float* __restrict__ out)
{
    const int n = blockIdx.z, head = blockIdx.y, q0 = blockIdx.x * 256;
    const int tid  = threadIdx.x;
    const int w    = tid >> 6, lane = tid & 63;
    const int tx   = lane & 15, quad = lane >> 4;

    __shared__ unsigned short Kl[64 * 72];      // [key][c]
    __shared__ unsigned short Vl[64 * 72];      // [c][key]
    __shared__ unsigned short Pl[4][64 * 72];   // per-wave [q][key]; also Q stage / O stage

    const float* base = qkv + (size_t)n * 768 * SDIM + (size_t)head * 192 * SDIM;
    const int qw = q0 + w * 64;

    // ---- stage Q (already scaled by 1/8) into Pl[w] as [q][c] bf16, pull A-frags
#pragma unroll 8
    for (int c = 0; c < 64; c++)
        Pl[w][lane * 72 + c] = f2bs(base[(size_t)(c * 3) * SDIM + qw + lane]);
    __syncthreads();

    s16x8 qf[4][2];
#pragma unroll
    for (int mt = 0; mt < 4; mt++)
#pragma unroll
        for (int kc = 0; kc < 2; kc++)
            qf[mt][kc] = ldsA(&Pl[w][(mt * 16 + tx) * 72 + kc * 32 + quad * 8]);

    f32x4 acco[4][4];
    float lpart[4][4];
#pragma unroll
    for (int mt = 0; mt < 4; mt++)
#pragma unroll
        for (int nt = 0; nt < 4; nt++) {
            acco[mt][nt] = (f32x4){0.f, 0.f, 0.f, 0.f};
            lpart[mt][nt] = 0.f;
        }

    // prefetch K/V tile 0 into registers
    float kr[16], vr[16];
#pragma unroll
    for (int j = 0; j < 16; j++) {
        int i = tid + j * 256;
        int c = i >> 6, s = i & 63;
        kr[j] = base[(size_t)(c * 3 + 1) * SDIM + s];
        vr[j] = base[(size_t)(c * 3 + 2) * SDIM + s];
    }

    for (int kt = 0; kt < 16; kt++) {
        __syncthreads();                 // prev tile consumed; drains prefetch vmcnt
#pragma unroll
        for (int j = 0; j < 16; j++) {
            int i = tid + j * 256;
            int c = i >> 6, s = i & 63;
            Kl[s * 72 + c] = f2bs(kr[j]);
            Vl[c * 72 + s] = f2bs(vr[j]);
        }
        __syncthreads();
        if (kt < 15) {                   // prefetch next tile; covered by compute below
            int k0 = (kt + 1) * 64;
#pragma unroll
            for (int j = 0; j < 16; j++) {
                int i = tid + j * 256;
                int c = i >> 6, s = i & 63;
                kr[j] = base[(size_t)(c * 3 + 1) * SDIM + k0 + s];
                vr[j] = base[(size_t)(c * 3 + 2) * SDIM + k0 + s];
            }
        }

        // ---- S = Q K^T  (64q x 64key per wave)
        f32x4 accs[4][4];
#pragma unroll
        for (int mt = 0; mt < 4; mt++)
#pragma unroll
            for (int nt = 0; nt < 4; nt++) accs[mt][nt] = (f32x4){0.f, 0.f, 0.f, 0.f};
#pragma unroll
        for (int kc = 0; kc < 2; kc++)
#pragma unroll
            for (int nt = 0; nt < 4; nt++) {
                s16x8 kf = ldsA(&Kl[(nt * 16 + tx) * 72 + kc * 32 + quad * 8]);
#pragma unroll
                for (int mt = 0; mt < 4; mt++)
                    accs[mt][nt] = __builtin_amdgcn_mfma_f32_16x16x32_bf16(
                        qf[mt][kc], kf, accs[mt][nt], 0, 0, 0);
            }

        // ---- P = exp(S): accumulate row-sums, write bf16 P to per-wave LDS
#pragma unroll
        for (int mt = 0; mt < 4; mt++)
#pragma unroll
            for (int nt = 0; nt < 4; nt++)
#pragma unroll
                for (int r = 0; r < 4; r++) {
                    float p = __expf(accs[mt][nt][r]);
                    lpart[mt][r] += p;
                    Pl[w][(mt * 16 + quad * 4 + r) * 72 + nt * 16 + tx] = f2bs(p);
                }
        asm volatile("s_waitcnt lgkmcnt(0)" ::: "memory");   // P visible to own wave

        // ---- O += P V
#pragma unroll
        for (int kc = 0; kc < 2; kc++) {
            s16x8 pf[4];
#pragma unroll
            for (int mt = 0; mt < 4; mt++)
                pf[mt] = ldsA(&Pl[w][(mt * 16 + tx) * 72 + kc * 32 + quad * 8]);
#pragma unroll
            for (int nt = 0; nt < 4; nt++) {
                s16x8 vf = ldsA(&Vl[(nt * 16 + tx) * 72 + kc * 32 + quad * 8]);
#pragma unroll
                for (int mt = 0; mt < 4; mt++)
                    acco[mt][nt] = __builtin_amdgcn_mfma_f32_16x16x32_bf16(
                        pf[mt], vf, acco[mt][nt], 0, 0, 0);
            }
        }
    }

    // ---- finalize: O /= l   (row q = mt*16 + quad*4 + r)
    float inv[4][4];
#pragma unroll
    for (int mt = 0; mt < 4; mt++)
#pragma unroll
        for (int r = 0; r < 4; r++) {
            float l = lpart[mt][r];
            l += __shfl_xor(l, 1); l += __shfl_xor(l, 2);
            l += __shfl_xor(l, 4); l += __shfl_xor(l, 8);
            inv[mt][r] = 1.0f / l;
        }
#pragma unroll
    for (int mt = 0; mt < 4; mt++)
#pragma unroll
        for (int nt = 0; nt < 4; nt++)
#pragma unroll
            for (int r = 0; r < 4; r++) acco[mt][nt][r] *= inv[mt][r];

    // ---- transpose 64q x 64c -> global [c][q], two 32-channel halves via Pl[w]
    float* Ow = (float*)&Pl[w][0];       // 32 x 68 floats = 8704 B < 9216 B
    float* ob = out + (size_t)n * COUT * SDIM + (size_t)(head * 64) * SDIM + qw;
#pragma unroll
    for (int h = 0; h < 2; h++) {
        __syncthreads();
#pragma unroll
        for (int mt = 0; mt < 4; mt++)
#pragma unroll
            for (int nt2 = 0; nt2 < 2; nt2++) {
                int nt = 2 * h + nt2;
#pragma unroll
                for (int r = 0; r < 4; r++)
                    Ow[(nt2 * 16 + tx) * 68 + mt * 16 + quad * 4 + r] = acco[mt][nt][r];
            }
        __syncthreads();
#pragma unroll 8
        for (int cc = 0; cc < 32; cc++)
            ob[(size_t)(h * 32 + cc) * SDIM + lane] = Ow[cc * 68 + lane];
    }
}

extern "C" void kernel_launch(void* const* d_in, const int* in_sizes, int n_in,
                              void* d_out, int out_size, void* d_ws, size_t ws_size,
                              hipStream_t stream)
{
    const float* x      = (const float*)d_in[0];
    const float* emb    = (const float*)d_in[1];
    const float* w_skip = (const float*)d_in[2];
    const float* w_res0 = (const float*)d_in[3];
    const float* w_res1 = (const float*)d_in[4];
    const float* w_emb  = (const float*)d_in[5];
    const float* e_gain = (const float*)d_in[6];
    const float* w_qkv  = (const float*)d_in[7];
    const float* w_proj = (const float*)d_in[8];
    float* out = (float*)d_out;

    float* p = (float*)d_ws;
    float* wskip_n = p; p += 256 * 192;
    float* wres0_n = p; p += 256 * 2304;
    float* wres1_n = p; p += 256 * 2304;
    float* wemb_n  = p; p += 256 * 768;
    float* wqkv_n  = p; p += 768 * 256;
    float* wproj_n = p; p += 256 * 256;
    float* cvec    = p; p += 16 * 256;
    float* xn      = p; p += (size_t)16 * 256 * 1024;
    float* ybuf    = p; p += (size_t)16 * 256 * 1024;
    float* qkvb    = p; p += (size_t)16 * 768 * 1024;

    wnorm<<<256, 256, 0, stream>>>(w_skip, wskip_n, 192, nullptr);
    wnorm<<<256, 256, 0, stream>>>(w_res0, wres0_n, 2304, nullptr);
    wnorm<<<256, 256, 0, stream>>>(w_res1, wres1_n, 2304, nullptr);
    wnorm<<<256, 256, 0, stream>>>(w_emb,  wemb_n,  768, e_gain);
    wnorm<<<768, 256, 0, stream>>>(w_qkv,  wqkv_n,  256, nullptr);
    wnorm<<<256, 256, 0, stream>>>(w_proj, wproj_n, 256, nullptr);

    emb_mm<<<16, 256, 0, stream>>>(emb, wemb_n, cvec);

    // x1 = conv1x1(x, w_skip_n) -> xn
    conv_gemm<1, 0, false><<<dim3(16, 4, 16), 256, 0, stream>>>(wskip_n, x, xn, nullptr, nullptr, 192, 256);
    // pixel norm in place
    pix_norm<<<64, 256, 0, stream>>>(xn);
    // y = conv3x3(silu(xn), w_res0_n) * c -> ybuf
    conv_gemm<3, 1, true><<<dim3(16, 4, 16), 256, 0, stream>>>(wres0_n, xn, ybuf, cvec, nullptr, 256, 256);
    // x2 = mp_sum(xn, conv3x3(silu(ybuf), w_res1_n)) -> xn (in place)
    conv_gemm<3, 2, true><<<dim3(16, 4, 16), 256, 0, stream>>>(wres1_n, ybuf, xn, nullptr, xn, 256, 256);
    // qkv = conv1x1(xn, w_qkv_n) -> qkvb
    conv_gemm<1, 0, false><<<dim3(16, 12, 16), 256, 0, stream>>>(wqkv_n, xn, qkvb, nullptr, nullptr, 256, 768);
    // normalize qkv per (n,h,t,s) over 64 channels (q pre-scaled by 1/8)
    qkv_norm<<<768, 256, 0, stream>>>(qkvb);
    // attention -> ybuf
    attn_mfma<<<dim3(4, 4, 16), 256, 0, stream>>>(qkvb, ybuf);
    // out = clip(mp_sum(xn, conv1x1(ybuf, w_proj_n)))
    conv_gemm<1, 3, false><<<dim3(16, 4, 16), 256, 0, stream>>>(wproj_n, ybuf, out, nullptr, xn, 256, 256);
}

// Round 3
// 451.934 us; speedup vs baseline: 6.1884x; 3.2342x over previous
//
#include <hip/hip_runtime.h>
#include <math.h>

#define SDIM 1024
#define COUT 256

#define EPSV     1e-4f
#define SILU_INV 1.6778523489932886f   // 1/0.596
#define MPA      0.9191450300180579f   // 0.7/sqrt(0.58)
#define MPB      0.3939192985791677f   // 0.3/sqrt(0.58)

typedef short s16x8 __attribute__((ext_vector_type(8)));
typedef float f32x4 __attribute__((ext_vector_type(4)));
typedef unsigned short ushort_t;

__device__ inline ushort_t f2bs(float f) {
    unsigned u = __float_as_uint(f);
    u += 0x7fffu + ((u >> 16) & 1u);        // round-nearest-even
    return (ushort_t)(u >> 16);
}
__device__ inline float bs2f(ushort_t u) { return __uint_as_float(((unsigned)u) << 16); }
__device__ inline float silu_mp(float v) { return v * SILU_INV / (1.f + __expf(-v)); }

union F8 { s16x8 v; uint4 q; };
__device__ inline s16x8 ldsA(const ushort_t* p) {   // p is 16B-aligned by construction
    F8 r; r.q = *(const uint4*)p; return r.v;
}

// ---------------- weight normalization (fp32 out, for w_emb)
__global__ __launch_bounds__(256) void wnorm(const float* __restrict__ w,
                                             float* __restrict__ wn,
                                             int fanin,
                                             const float* __restrict__ gain_ptr)
{
    int o = blockIdx.x;
    const float* row = w + (size_t)o * fanin;
    float ss = 0.f;
    for (int i = threadIdx.x; i < fanin; i += 256) { float v = row[i]; ss += v * v; }
    for (int off = 32; off >= 1; off >>= 1) ss += __shfl_down(ss, off);
    __shared__ float red[4];
    int lane = threadIdx.x & 63, wv = threadIdx.x >> 6;
    if (lane == 0) red[wv] = ss;
    __syncthreads();
    float tot = red[0] + red[1] + red[2] + red[3];
    float gain = gain_ptr ? *gain_ptr : 1.0f;
    float scale = gain / (EPSV * sqrtf((float)fanin) + sqrtf(tot));
    for (int i = threadIdx.x; i < fanin; i += 256)
        wn[(size_t)o * fanin + i] = row[i] * scale;
}

// ---------------- weight normalization -> bf16 (optional K reorder (ci,3,3)->(3x3,ci))
template<bool REORDER>
__global__ __launch_bounds__(256) void wnorm_bf16(const float* __restrict__ w,
                                                  ushort_t* __restrict__ wn,
                                                  int fanin)
{
    int o = blockIdx.x;
    const float* row = w + (size_t)o * fanin;
    float ss = 0.f;
    for (int i = threadIdx.x; i < fanin; i += 256) { float v = row[i]; ss += v * v; }
    for (int off = 32; off >= 1; off >>= 1) ss += __shfl_down(ss, off);
    __shared__ float red[4];
    int lane = threadIdx.x & 63, wv = threadIdx.x >> 6;
    if (lane == 0) red[wv] = ss;
    __syncthreads();
    float tot = red[0] + red[1] + red[2] + red[3];
    float scale = 1.0f / (EPSV * sqrtf((float)fanin) + sqrtf(tot));
    for (int i = threadIdx.x; i < fanin; i += 256) {
        int kd = i;
        if (REORDER) { int ci = i / 9; int r9 = i - ci * 9; kd = r9 * 256 + ci; }
        wn[(size_t)o * fanin + kd] = f2bs(row[i] * scale);
    }
}

// ---------------- c = emb @ wemb_n^T + 1
__global__ __launch_bounds__(256) void emb_mm(const float* __restrict__ emb,
                                              const float* __restrict__ wemb,
                                              float* __restrict__ cvec)
{
    int n = blockIdx.x;
    int co = threadIdx.x;
    const float* e  = emb  + (size_t)n * 768;
    const float* wr = wemb + (size_t)co * 768;
    float s = 0.f;
    for (int i = 0; i < 768; i++) s = fmaf(e[i], wr[i], s);
    cvec[n * COUT + co] = s + 1.0f;
}

// ---------------- transpose x [n][192][1024] fp32 -> xT [n][1024][192] bf16
__global__ __launch_bounds__(256) void prep_xT(const float* __restrict__ x,
                                               ushort_t* __restrict__ xT)
{
    const int n = blockIdx.z, ci0 = blockIdx.y * 64, s0 = blockIdx.x * 64;
    const int tid = threadIdx.x;
    __shared__ float T[64 * 65];
#pragma unroll
    for (int i = 0; i < 16; i++) {
        int ch = tid + i * 256; int row = ch >> 6, cc = ch & 63;
        T[row * 65 + cc] = x[((size_t)n * 192 + ci0 + row) * SDIM + s0 + cc];
    }
    __syncthreads();
#pragma unroll
    for (int i = 0; i < 2; i++) {
        int ch = tid + i * 256; int srow = ch >> 3, c8 = ch & 7;
        ushort_t tmp[8];
#pragma unroll
        for (int j = 0; j < 8; j++) tmp[j] = f2bs(T[(c8 * 8 + j) * 65 + srow]);
        *(uint4*)(xT + ((size_t)n * SDIM + s0 + srow) * 192 + ci0 + c8 * 8) = *(uint4*)tmp;
    }
}

// ---------------- fused: x1 = conv1x1(x, wskip); xn = pix_norm(x1); sxT = silu(xn)
// block: M=256 (ALL co) x N=64 s; 4 waves stacked in M -> cross-channel norm in-block
__global__ __launch_bounds__(256, 1) void skip_fused(const ushort_t* __restrict__ Wp,   // [256][192]
                                                     const ushort_t* __restrict__ xT,   // [n][1024][192]
                                                     float* __restrict__ xn,
                                                     ushort_t* __restrict__ sxT)
{
    const int n = blockIdx.z, s0 = blockIdx.x * 64;
    const int tid = threadIdx.x, w = tid >> 6, lane = tid & 63;
    const int tx = lane & 15, quad = lane >> 4;

    __shared__ ushort_t As[256 * 72];
    __shared__ ushort_t Bs[64 * 72];
    __shared__ float csum[4][64];

    f32x4 acc[4][4];
#pragma unroll
    for (int a = 0; a < 4; a++)
#pragma unroll
        for (int b = 0; b < 4; b++) acc[a][b] = (f32x4){0.f, 0.f, 0.f, 0.f};

    for (int k0 = 0; k0 < 192; k0 += 64) {
        __syncthreads();
#pragma unroll
        for (int i = 0; i < 8; i++) {
            int ch = tid + i * 256; int row = ch >> 3, c8 = ch & 7;
            *(uint4*)&As[row * 72 + c8 * 8] = *(const uint4*)(Wp + (size_t)row * 192 + k0 + c8 * 8);
        }
#pragma unroll
        for (int i = 0; i < 2; i++) {
            int ch = tid + i * 256; int row = ch >> 3, c8 = ch & 7;
            *(uint4*)&Bs[row * 72 + c8 * 8] =
                *(const uint4*)(xT + ((size_t)n * SDIM + s0 + row) * 192 + k0 + c8 * 8);
        }
        __syncthreads();
#pragma unroll
        for (int kc = 0; kc < 2; kc++) {
            s16x8 af[4], bf_[4];
#pragma unroll
            for (int mt = 0; mt < 4; mt++) af[mt] = ldsA(&As[(w * 64 + mt * 16 + tx) * 72 + kc * 32 + quad * 8]);
#pragma unroll
            for (int nt = 0; nt < 4; nt++) bf_[nt] = ldsA(&Bs[(nt * 16 + tx) * 72 + kc * 32 + quad * 8]);
#pragma unroll
            for (int mt = 0; mt < 4; mt++)
#pragma unroll
                for (int nt = 0; nt < 4; nt++)
                    acc[mt][nt] = __builtin_amdgcn_mfma_f32_16x16x32_bf16(af[mt], bf_[nt], acc[mt][nt], 0, 0, 0);
        }
    }

    // per-column (pixel) sum of squares across all 256 co
#pragma unroll
    for (int nt = 0; nt < 4; nt++) {
        float s2 = 0.f;
#pragma unroll
        for (int mt = 0; mt < 4; mt++)
#pragma unroll
            for (int r = 0; r < 4; r++) s2 = fmaf(acc[mt][nt][r], acc[mt][nt][r], s2);
        s2 += __shfl_xor(s2, 16); s2 += __shfl_xor(s2, 32);
        if (quad == 0) csum[w][nt * 16 + tx] = s2;
    }
    __syncthreads();
    float f[4];
#pragma unroll
    for (int nt = 0; nt < 4; nt++) {
        int col = nt * 16 + tx;
        float tot = csum[0][col] + csum[1][col] + csum[2][col] + csum[3][col];
        f[nt] = 1.f / (EPSV + sqrtf(tot) * 0.0625f);
    }
    ushort_t* Ls = As;                      // [64 s][264 co] (As is dead now; all waves past barrier)
    float* xb = xn + (size_t)n * COUT * SDIM;
#pragma unroll
    for (int mt = 0; mt < 4; mt++)
#pragma unroll
        for (int r = 0; r < 4; r++) {
            int co = w * 64 + mt * 16 + quad * 4 + r;
#pragma unroll
            for (int nt = 0; nt < 4; nt++) {
                int sp = s0 + nt * 16 + tx;
                float v = acc[mt][nt][r] * f[nt];
                xb[(size_t)co * SDIM + sp] = v;
                Ls[(nt * 16 + tx) * 264 + co] = f2bs(silu_mp(v));
            }
        }
    __syncthreads();
#pragma unroll
    for (int i = 0; i < 8; i++) {
        int ch = tid + i * 256; int row = ch >> 5, c16 = ch & 31;
        *(uint4*)(sxT + ((size_t)n * SDIM + s0 + row) * 256 + c16 * 8) = *(uint4*)&Ls[row * 264 + c16 * 8];
    }
}

// ---------------- generic bf16 MFMA conv GEMM, 128co x 128s tile, BK=64, reg-prefetch.
// B source is transposed activations [n][1024][256] bf16; GATHER3 does the 9-segment
// shifted gather (K order = (dy*3+dx)*256 + ci, matching wnorm_bf16<true>).
// MODE 0: qkv  -> OutT bf16 [n][768][1024]
// MODE 1: res0 -> *cvec, silu, OutT bf16 [n][1024][256] (transposed)
// MODE 2: res1 -> x2 = MPA*xn+MPB*acc; xn fp32 in place; OutT bf16 [n][1024][256]
// MODE 3: proj -> Outf = clip(MPA*RX+MPB*acc) fp32 [n][256][1024]
template<int KDIM, bool GATHER3, int MODE>
__global__ __launch_bounds__(256, 1) void gemm128(const ushort_t* __restrict__ Wp,
                                                  const ushort_t* __restrict__ Bsrc,
                                                  float* RX, float* Outf,
                                                  ushort_t* OutT,
                                                  const float* __restrict__ cvec)
{
    const int n = blockIdx.z, co0 = blockIdx.y * 128, s0 = blockIdx.x * 128;
    const int tid = threadIdx.x, w = tid >> 6, lane = tid & 63;
    const int tx = lane & 15, quad = lane >> 4;
    const int wm = w >> 1, ws = w & 1;

    __shared__ ushort_t SH[2 * 128 * 72];
    ushort_t* As = SH;
    ushort_t* Bs = SH + 128 * 72;
    const ushort_t* bn = Bsrc + (size_t)n * SDIM * 256;

    uint4 ra[4], rb[4];
    auto loadA = [&](int k0) {
#pragma unroll
        for (int i = 0; i < 4; i++) {
            int ch = tid + i * 256; int row = ch >> 3, c8 = ch & 7;
            ra[i] = *(const uint4*)(Wp + (size_t)(co0 + row) * KDIM + k0 + c8 * 8);
        }
    };
    auto loadB = [&](int k0) {
        int ci0 = k0, dy = 0, dx = 0;
        if (GATHER3) { int seg = k0 >> 8; ci0 = k0 & 255; int s3 = seg / 3; dy = s3 - 1; dx = seg - s3 * 3 - 1; }
#pragma unroll
        for (int i = 0; i < 4; i++) {
            int ch = tid + i * 256; int row = ch >> 3, c8 = ch & 7;
            int sImg = s0 + row;
            bool valid = true; int sSrc = sImg;
            if (GATHER3) {
                int h = (sImg >> 5) + dy, ww = (sImg & 31) + dx;
                valid = ((unsigned)h < 32u) && ((unsigned)ww < 32u);
                sSrc = (h << 5) | ww;
            }
            rb[i] = valid ? *(const uint4*)(bn + (size_t)sSrc * 256 + ci0 + c8 * 8)
                          : make_uint4(0u, 0u, 0u, 0u);
        }
    };

    f32x4 acc[4][4];
#pragma unroll
    for (int a = 0; a < 4; a++)
#pragma unroll
        for (int b = 0; b < 4; b++) acc[a][b] = (f32x4){0.f, 0.f, 0.f, 0.f};

    loadA(0); loadB(0);
    for (int k0 = 0; k0 < KDIM; k0 += 64) {
        __syncthreads();
#pragma unroll
        for (int i = 0; i < 4; i++) {
            int ch = tid + i * 256; int row = ch >> 3, c8 = ch & 7;
            *(uint4*)&As[row * 72 + c8 * 8] = ra[i];
            *(uint4*)&Bs[row * 72 + c8 * 8] = rb[i];
        }
        __syncthreads();
        if (k0 + 64 < KDIM) { loadA(k0 + 64); loadB(k0 + 64); }
#pragma unroll
        for (int kc = 0; kc < 2; kc++) {
            s16x8 af[4], bf_[4];
#pragma unroll
            for (int mt = 0; mt < 4; mt++) af[mt] = ldsA(&As[(wm * 64 + mt * 16 + tx) * 72 + kc * 32 + quad * 8]);
#pragma unroll
            for (int nt = 0; nt < 4; nt++) bf_[nt] = ldsA(&Bs[(ws * 64 + nt * 16 + tx) * 72 + kc * 32 + quad * 8]);
#pragma unroll
            for (int mt = 0; mt < 4; mt++)
#pragma unroll
                for (int nt = 0; nt < 4; nt++)
                    acc[mt][nt] = __builtin_amdgcn_mfma_f32_16x16x32_bf16(af[mt], bf_[nt], acc[mt][nt], 0, 0, 0);
        }
    }

    if (MODE == 0) {      // qkv: bf16 [co][s] out via LDS repack
        __syncthreads();
        ushort_t* Ls = SH;                  // [128 co][136 s]
#pragma unroll
        for (int mt = 0; mt < 4; mt++)
#pragma unroll
            for (int nt = 0; nt < 4; nt++)
#pragma unroll
                for (int r = 0; r < 4; r++)
                    Ls[(wm * 64 + mt * 16 + quad * 4 + r) * 136 + ws * 64 + nt * 16 + tx] = f2bs(acc[mt][nt][r]);
        __syncthreads();
        ushort_t* dst = OutT + (size_t)n * 768 * SDIM;
#pragma unroll
        for (int i = 0; i < 8; i++) {
            int ch = tid + i * 256; int row = ch >> 4, c16 = ch & 15;
            *(uint4*)(dst + (size_t)(co0 + row) * SDIM + s0 + c16 * 8) = *(uint4*)&Ls[row * 136 + c16 * 8];
        }
    }
    if (MODE == 1) {      // res0: *c, silu, transposed bf16 out
        float cm[4][4];
#pragma unroll
        for (int mt = 0; mt < 4; mt++)
#pragma unroll
            for (int r = 0; r < 4; r++)
                cm[mt][r] = cvec[n * COUT + co0 + wm * 64 + mt * 16 + quad * 4 + r];
        __syncthreads();
        ushort_t* Ls = SH;                  // [128 s][136 co]
#pragma unroll
        for (int mt = 0; mt < 4; mt++)
#pragma unroll
            for (int nt = 0; nt < 4; nt++)
#pragma unroll
                for (int r = 0; r < 4; r++) {
                    float v = silu_mp(acc[mt][nt][r] * cm[mt][r]);
                    Ls[(ws * 64 + nt * 16 + tx) * 136 + wm * 64 + mt * 16 + quad * 4 + r] = f2bs(v);
                }
        __syncthreads();
#pragma unroll
        for (int i = 0; i < 8; i++) {
            int ch = tid + i * 256; int row = ch >> 4, c16 = ch & 15;
            *(uint4*)(OutT + ((size_t)n * SDIM + s0 + row) * 256 + co0 + c16 * 8) = *(uint4*)&Ls[row * 136 + c16 * 8];
        }
    }
    if (MODE == 2) {      // res1: mp_sum in place on xn, + transposed bf16 out
        __syncthreads();
        ushort_t* Ls = SH;                  // [128 s][136 co]
#pragma unroll
        for (int mt = 0; mt < 4; mt++)
#pragma unroll
            for (int r = 0; r < 4; r++) {
                int col = wm * 64 + mt * 16 + quad * 4 + r;
                float* xp = RX + ((size_t)n * COUT + co0 + col) * SDIM + s0 + ws * 64;
#pragma unroll
                for (int nt = 0; nt < 4; nt++) {
                    float v = MPA * xp[nt * 16 + tx] + MPB * acc[mt][nt][r];
                    xp[nt * 16 + tx] = v;
                    Ls[(ws * 64 + nt * 16 + tx) * 136 + col] = f2bs(v);
                }
            }
        __syncthreads();
#pragma unroll
        for (int i = 0; i < 8; i++) {
            int ch = tid + i * 256; int row = ch >> 4, c16 = ch & 15;
            *(uint4*)(OutT + ((size_t)n * SDIM + s0 + row) * 256 + co0 + c16 * 8) = *(uint4*)&Ls[row * 136 + c16 * 8];
        }
    }
    if (MODE == 3) {      // proj: clip(mp_sum) fp32 out
#pragma unroll
        for (int mt = 0; mt < 4; mt++)
#pragma unroll
            for (int r = 0; r < 4; r++) {
                int co = co0 + wm * 64 + mt * 16 + quad * 4 + r;
                const float* xp = RX + ((size_t)n * COUT + co) * SDIM + s0 + ws * 64;
                float* op = Outf + ((size_t)n * COUT + co) * SDIM + s0 + ws * 64;
#pragma unroll
                for (int nt = 0; nt < 4; nt++) {
                    float v = MPA * xp[nt * 16 + tx] + MPB * acc[mt][nt][r];
                    op[nt * 16 + tx] = fminf(fmaxf(v, -256.f), 256.f);
                }
            }
    }
}

// ---------------- qkv norm over 64 channels per (n,head,t,s), bf16 in place (q * 1/8)
__global__ __launch_bounds__(256) void qkv_norm(ushort_t* qkv)
{
    int g = blockIdx.x * 256 + threadIdx.x;
    int s = g & 1023;
    int rem = g >> 10;
    int t = rem % 3;
    int rem2 = rem / 3;
    int head = rem2 & 3;
    int n = rem2 >> 2;
    ushort_t* base = qkv + (size_t)n * 768 * SDIM + (size_t)(head * 192 + t) * SDIM + s;
    float v[64]; float ss = 0.f;
#pragma unroll
    for (int c = 0; c < 64; c++) { v[c] = bs2f(base[(size_t)c * 3 * SDIM]); ss = fmaf(v[c], v[c], ss); }
    float sc = 1.f / (EPSV + sqrtf(ss) * 0.125f);
    if (t == 0) sc *= 0.125f;
#pragma unroll
    for (int c = 0; c < 64; c++) base[(size_t)c * 3 * SDIM] = f2bs(v[c] * sc);
}

// ---------------- MFMA flash attention (bf16 in, bf16 transposed out aT[n][s][256])
__global__ __launch_bounds__(256, 1) void attn_mfma(const ushort_t* __restrict__ qkv,
                                                    ushort_t* __restrict__ aT)
{
    const int n = blockIdx.z, head = blockIdx.y, q0 = blockIdx.x * 256;
    const int tid  = threadIdx.x;
    const int w    = tid >> 6, lane = tid & 63;
    const int tx   = lane & 15, quad = lane >> 4;

    __shared__ ushort_t Kl[64 * 72];      // [key][c]
    __shared__ ushort_t Vl[64 * 72];      // [c][key]
    __shared__ ushort_t Pl[4][64 * 72];   // per-wave [q][key] / Q stage / O stage

    const ushort_t* base = qkv + (size_t)n * 768 * SDIM + (size_t)head * 192 * SDIM;
    const int qw = q0 + w * 64;

#pragma unroll 8
    for (int c = 0; c < 64; c++)
        Pl[w][lane * 72 + c] = base[(size_t)(c * 3) * SDIM + qw + lane];
    __syncthreads();

    s16x8 qf[4][2];
#pragma unroll
    for (int mt = 0; mt < 4; mt++)
#pragma unroll
        for (int kc = 0; kc < 2; kc++)
            qf[mt][kc] = ldsA(&Pl[w][(mt * 16 + tx) * 72 + kc * 32 + quad * 8]);

    f32x4 acco[4][4];
    float lpart[4][4];
#pragma unroll
    for (int mt = 0; mt < 4; mt++)
#pragma unroll
        for (int nt = 0; nt < 4; nt++) {
            acco[mt][nt] = (f32x4){0.f, 0.f, 0.f, 0.f};
            lpart[mt][nt] = 0.f;
        }

    ushort_t kr[16], vr[16];
#pragma unroll
    for (int j = 0; j < 16; j++) {
        int i = tid + j * 256;
        int c = i >> 6, s = i & 63;
        kr[j] = base[(size_t)(c * 3 + 1) * SDIM + s];
        vr[j] = base[(size_t)(c * 3 + 2) * SDIM + s];
    }

    for (int kt = 0; kt < 16; kt++) {
        __syncthreads();
#pragma unroll
        for (int j = 0; j < 16; j++) {
            int i = tid + j * 256;
            int c = i >> 6, s = i & 63;
            Kl[s * 72 + c] = kr[j];
            Vl[c * 72 + s] = vr[j];
        }
        __syncthreads();
        if (kt < 15) {
            int k0 = (kt + 1) * 64;
#pragma unroll
            for (int j = 0; j < 16; j++) {
                int i = tid + j * 256;
                int c = i >> 6, s = i & 63;
                kr[j] = base[(size_t)(c * 3 + 1) * SDIM + k0 + s];
                vr[j] = base[(size_t)(c * 3 + 2) * SDIM + k0 + s];
            }
        }

        f32x4 accs[4][4];
#pragma unroll
        for (int mt = 0; mt < 4; mt++)
#pragma unroll
            for (int nt = 0; nt < 4; nt++) accs[mt][nt] = (f32x4){0.f, 0.f, 0.f, 0.f};
#pragma unroll
        for (int kc = 0; kc < 2; kc++)
#pragma unroll
            for (int nt = 0; nt < 4; nt++) {
                s16x8 kf = ldsA(&Kl[(nt * 16 + tx) * 72 + kc * 32 + quad * 8]);
#pragma unroll
                for (int mt = 0; mt < 4; mt++)
                    accs[mt][nt] = __builtin_amdgcn_mfma_f32_16x16x32_bf16(
                        qf[mt][kc], kf, accs[mt][nt], 0, 0, 0);
            }

#pragma unroll
        for (int mt = 0; mt < 4; mt++)
#pragma unroll
            for (int nt = 0; nt < 4; nt++)
#pragma unroll
                for (int r = 0; r < 4; r++) {
                    float p = __expf(accs[mt][nt][r]);
                    lpart[mt][r] += p;
                    Pl[w][(mt * 16 + quad * 4 + r) * 72 + nt * 16 + tx] = f2bs(p);
                }
        asm volatile("s_waitcnt lgkmcnt(0)" ::: "memory");

#pragma unroll
        for (int kc = 0; kc < 2; kc++) {
            s16x8 pf[4];
#pragma unroll
            for (int mt = 0; mt < 4; mt++)
                pf[mt] = ldsA(&Pl[w][(mt * 16 + tx) * 72 + kc * 32 + quad * 8]);
#pragma unroll
            for (int nt = 0; nt < 4; nt++) {
                s16x8 vf = ldsA(&Vl[(nt * 16 + tx) * 72 + kc * 32 + quad * 8]);
#pragma unroll
                for (int mt = 0; mt < 4; mt++)
                    acco[mt][nt] = __builtin_amdgcn_mfma_f32_16x16x32_bf16(
                        pf[mt], vf, acco[mt][nt], 0, 0, 0);
            }
        }
    }

    float inv[4][4];
#pragma unroll
    for (int mt = 0; mt < 4; mt++)
#pragma unroll
        for (int r = 0; r < 4; r++) {
            float l = lpart[mt][r];
            l += __shfl_xor(l, 1); l += __shfl_xor(l, 2);
            l += __shfl_xor(l, 4); l += __shfl_xor(l, 8);
            inv[mt][r] = 1.0f / l;
        }

    // O is already [q][c] in acc layout -> stage bf16 rows, write aT[n][qw+q][head*64 + c]
#pragma unroll
    for (int mt = 0; mt < 4; mt++)
#pragma unroll
        for (int nt = 0; nt < 4; nt++)
#pragma unroll
            for (int r = 0; r < 4; r++)
                Pl[w][(mt * 16 + quad * 4 + r) * 72 + nt * 16 + tx] = f2bs(acco[mt][nt][r] * inv[mt][r]);
    asm volatile("s_waitcnt lgkmcnt(0)" ::: "memory");
    ushort_t* dst = aT + ((size_t)n * SDIM + qw) * 256 + head * 64;
#pragma unroll
    for (int i = 0; i < 8; i++) {
        int ch = lane + i * 64; int row = ch >> 3, c8 = ch & 7;
        *(uint4*)(dst + (size_t)row * 256 + c8 * 8) = *(uint4*)&Pl[w][row * 72 + c8 * 8];
    }
}

extern "C" void kernel_launch(void* const* d_in, const int* in_sizes, int n_in,
                              void* d_out, int out_size, void* d_ws, size_t ws_size,
                              hipStream_t stream)
{
    const float* x      = (const float*)d_in[0];
    const float* emb    = (const float*)d_in[1];
    const float* w_skip = (const float*)d_in[2];
    const float* w_res0 = (const float*)d_in[3];
    const float* w_res1 = (const float*)d_in[4];
    const float* w_emb  = (const float*)d_in[5];
    const float* e_gain = (const float*)d_in[6];
    const float* w_qkv  = (const float*)d_in[7];
    const float* w_proj = (const float*)d_in[8];
    float* out = (float*)d_out;

    char* p = (char*)d_ws;
    auto alloc = [&](size_t bytes) { void* r = (void*)p; p += (bytes + 255) & ~(size_t)255; return r; };
    ushort_t* wskip_bf = (ushort_t*)alloc(256 * 192 * 2);
    ushort_t* wres0_bf = (ushort_t*)alloc(256 * 2304 * 2);
    ushort_t* wres1_bf = (ushort_t*)alloc(256 * 2304 * 2);
    ushort_t* wqkv_bf  = (ushort_t*)alloc(768 * 256 * 2);
    ushort_t* wproj_bf = (ushort_t*)alloc(256 * 256 * 2);
    float*    wemb_n   = (float*)alloc(256 * 768 * 4);
    float*    cvec     = (float*)alloc(16 * 256 * 4);
    ushort_t* xT   = (ushort_t*)alloc((size_t)16 * 1024 * 192 * 2);
    ushort_t* sxT  = (ushort_t*)alloc((size_t)16 * 1024 * 256 * 2);
    ushort_t* ysT  = (ushort_t*)alloc((size_t)16 * 1024 * 256 * 2);
    ushort_t* x2T  = (ushort_t*)alloc((size_t)16 * 1024 * 256 * 2);
    ushort_t* aT   = (ushort_t*)alloc((size_t)16 * 1024 * 256 * 2);
    float*    xn   = (float*)alloc((size_t)16 * 256 * 1024 * 4);
    ushort_t* qkvb = (ushort_t*)alloc((size_t)16 * 768 * 1024 * 2);

    wnorm_bf16<false><<<256, 256, 0, stream>>>(w_skip, wskip_bf, 192);
    wnorm_bf16<true ><<<256, 256, 0, stream>>>(w_res0, wres0_bf, 2304);
    wnorm_bf16<true ><<<256, 256, 0, stream>>>(w_res1, wres1_bf, 2304);
    wnorm_bf16<false><<<768, 256, 0, stream>>>(w_qkv,  wqkv_bf,  256);
    wnorm_bf16<false><<<256, 256, 0, stream>>>(w_proj, wproj_bf, 256);
    wnorm<<<256, 256, 0, stream>>>(w_emb, wemb_n, 768, e_gain);

    emb_mm<<<16, 256, 0, stream>>>(emb, wemb_n, cvec);
    prep_xT<<<dim3(16, 3, 16), 256, 0, stream>>>(x, xT);

    // fused skip conv + pix_norm + silu
    skip_fused<<<dim3(16, 1, 16), 256, 0, stream>>>(wskip_bf, xT, xn, sxT);
    // res0: y = conv3x3(sx) * c; ysT = silu(y)
    gemm128<2304, true, 1><<<dim3(8, 2, 16), 256, 0, stream>>>(wres0_bf, sxT, nullptr, nullptr, ysT, cvec);
    // res1: x2 = mp_sum(xn, conv3x3(ys)); xn <- x2 (in place) + x2T
    gemm128<2304, true, 2><<<dim3(8, 2, 16), 256, 0, stream>>>(wres1_bf, ysT, xn, nullptr, x2T, nullptr);
    // qkv = conv1x1(x2) -> bf16 [co][s]
    gemm128<256, false, 0><<<dim3(8, 6, 16), 256, 0, stream>>>(wqkv_bf, x2T, nullptr, nullptr, qkvb, nullptr);
    // per-(n,h,t,s) norm over 64 ch (q pre-scaled by 1/8)
    qkv_norm<<<768, 256, 0, stream>>>(qkvb);
    // attention -> aT [n][s][256] bf16
    attn_mfma<<<dim3(4, 4, 16), 256, 0, stream>>>(qkvb, aT);
    // out = clip(mp_sum(x2, conv1x1(attn)))
    gemm128<256, false, 3><<<dim3(8, 2, 16), 256, 0, stream>>>(wproj_bf, aT, xn, out, nullptr, nullptr);
}

// Round 4
// 447.010 us; speedup vs baseline: 6.2566x; 1.0110x over previous
//
#include <hip/hip_runtime.h>
#include <math.h>

#define SDIM 1024
#define COUT 256

#define EPSV     1e-4f
#define SILU_INV 1.6778523489932886f   // 1/0.596
#define MPA      0.9191450300180579f   // 0.7/sqrt(0.58)
#define MPB      0.3939192985791677f   // 0.3/sqrt(0.58)

typedef short s16x8 __attribute__((ext_vector_type(8)));
typedef float f32x4 __attribute__((ext_vector_type(4)));
typedef unsigned short ushort_t;

__device__ inline ushort_t f2bs(float f) {
    unsigned u = __float_as_uint(f);
    u += 0x7fffu + ((u >> 16) & 1u);        // round-nearest-even
    return (ushort_t)(u >> 16);
}
__device__ inline float bs2f(ushort_t u) { return __uint_as_float(((unsigned)u) << 16); }
__device__ inline float silu_mp(float v) { return v * SILU_INV / (1.f + __expf(-v)); }

union F8 { s16x8 v; uint4 q; };
__device__ inline s16x8 ldsA(const ushort_t* p) {   // p is 16B-aligned by construction
    F8 r; r.q = *(const uint4*)p; return r.v;
}

// ---------------- weight normalization (fp32 out, for w_emb)
__global__ __launch_bounds__(256) void wnorm(const float* __restrict__ w,
                                             float* __restrict__ wn,
                                             int fanin,
                                             const float* __restrict__ gain_ptr)
{
    int o = blockIdx.x;
    const float* row = w + (size_t)o * fanin;
    float ss = 0.f;
    for (int i = threadIdx.x; i < fanin; i += 256) { float v = row[i]; ss += v * v; }
    for (int off = 32; off >= 1; off >>= 1) ss += __shfl_down(ss, off);
    __shared__ float red[4];
    int lane = threadIdx.x & 63, wv = threadIdx.x >> 6;
    if (lane == 0) red[wv] = ss;
    __syncthreads();
    float tot = red[0] + red[1] + red[2] + red[3];
    float gain = gain_ptr ? *gain_ptr : 1.0f;
    float scale = gain / (EPSV * sqrtf((float)fanin) + sqrtf(tot));
    for (int i = threadIdx.x; i < fanin; i += 256)
        wn[(size_t)o * fanin + i] = row[i] * scale;
}

// ---------------- weight normalization -> bf16 (optional K reorder (ci,3,3)->(3x3,ci))
template<bool REORDER>
__global__ __launch_bounds__(256) void wnorm_bf16(const float* __restrict__ w,
                                                  ushort_t* __restrict__ wn,
                                                  int fanin)
{
    int o = blockIdx.x;
    const float* row = w + (size_t)o * fanin;
    float ss = 0.f;
    for (int i = threadIdx.x; i < fanin; i += 256) { float v = row[i]; ss += v * v; }
    for (int off = 32; off >= 1; off >>= 1) ss += __shfl_down(ss, off);
    __shared__ float red[4];
    int lane = threadIdx.x & 63, wv = threadIdx.x >> 6;
    if (lane == 0) red[wv] = ss;
    __syncthreads();
    float tot = red[0] + red[1] + red[2] + red[3];
    float scale = 1.0f / (EPSV * sqrtf((float)fanin) + sqrtf(tot));
    for (int i = threadIdx.x; i < fanin; i += 256) {
        int kd = i;
        if (REORDER) { int ci = i / 9; int r9 = i - ci * 9; kd = r9 * 256 + ci; }
        wn[(size_t)o * fanin + kd] = f2bs(row[i] * scale);
    }
}

// ---------------- c = emb @ wemb_n^T + 1
__global__ __launch_bounds__(256) void emb_mm(const float* __restrict__ emb,
                                              const float* __restrict__ wemb,
                                              float* __restrict__ cvec)
{
    int n = blockIdx.x;
    int co = threadIdx.x;
    const float* e  = emb  + (size_t)n * 768;
    const float* wr = wemb + (size_t)co * 768;
    float s = 0.f;
    for (int i = 0; i < 768; i++) s = fmaf(e[i], wr[i], s);
    cvec[n * COUT + co] = s + 1.0f;
}

// ---------------- transpose x [n][192][1024] fp32 -> xT [n][1024][192] bf16
__global__ __launch_bounds__(256) void prep_xT(const float* __restrict__ x,
                                               ushort_t* __restrict__ xT)
{
    const int n = blockIdx.z, ci0 = blockIdx.y * 64, s0 = blockIdx.x * 64;
    const int tid = threadIdx.x;
    __shared__ float T[64 * 65];
#pragma unroll
    for (int i = 0; i < 16; i++) {
        int ch = tid + i * 256; int row = ch >> 6, cc = ch & 63;
        T[row * 65 + cc] = x[((size_t)n * 192 + ci0 + row) * SDIM + s0 + cc];
    }
    __syncthreads();
#pragma unroll
    for (int i = 0; i < 2; i++) {
        int ch = tid + i * 256; int srow = ch >> 3, c8 = ch & 7;
        ushort_t tmp[8];
#pragma unroll
        for (int j = 0; j < 8; j++) tmp[j] = f2bs(T[(c8 * 8 + j) * 65 + srow]);
        *(uint4*)(xT + ((size_t)n * SDIM + s0 + srow) * 192 + ci0 + c8 * 8) = *(uint4*)tmp;
    }
}

// ---------------- fused: x1 = conv1x1(x, wskip); xn = pix_norm(x1); sxT = silu(xn)
// block: M=256 (ALL co) x N=32 s; 4 waves stacked in M -> cross-channel norm in-block
__global__ __launch_bounds__(256, 2) void skip_fused(const ushort_t* __restrict__ Wp,   // [256][192]
                                                     const ushort_t* __restrict__ xT,   // [n][1024][192]
                                                     float* __restrict__ xn,
                                                     ushort_t* __restrict__ sxT)
{
    const int n = blockIdx.z, s0 = blockIdx.x * 32;
    const int tid = threadIdx.x, w = tid >> 6, lane = tid & 63;
    const int tx = lane & 15, quad = lane >> 4;

    __shared__ ushort_t As[256 * 72];
    __shared__ ushort_t Bs[32 * 72];
    __shared__ float csum[4][32];

    f32x4 acc[4][2];
#pragma unroll
    for (int a = 0; a < 4; a++)
#pragma unroll
        for (int b = 0; b < 2; b++) acc[a][b] = (f32x4){0.f, 0.f, 0.f, 0.f};

    for (int k0 = 0; k0 < 192; k0 += 64) {
        __syncthreads();
#pragma unroll
        for (int i = 0; i < 8; i++) {
            int ch = tid + i * 256; int row = ch >> 3, c8 = ch & 7;
            *(uint4*)&As[row * 72 + c8 * 8] = *(const uint4*)(Wp + (size_t)row * 192 + k0 + c8 * 8);
        }
        {
            int row = tid >> 3, c8 = tid & 7;
            *(uint4*)&Bs[row * 72 + c8 * 8] =
                *(const uint4*)(xT + ((size_t)n * SDIM + s0 + row) * 192 + k0 + c8 * 8);
        }
        __syncthreads();
#pragma unroll
        for (int kc = 0; kc < 2; kc++) {
            s16x8 af[4], bf_[2];
#pragma unroll
            for (int mt = 0; mt < 4; mt++) af[mt] = ldsA(&As[(w * 64 + mt * 16 + tx) * 72 + kc * 32 + quad * 8]);
#pragma unroll
            for (int nt = 0; nt < 2; nt++) bf_[nt] = ldsA(&Bs[(nt * 16 + tx) * 72 + kc * 32 + quad * 8]);
#pragma unroll
            for (int mt = 0; mt < 4; mt++)
#pragma unroll
                for (int nt = 0; nt < 2; nt++)
                    acc[mt][nt] = __builtin_amdgcn_mfma_f32_16x16x32_bf16(af[mt], bf_[nt], acc[mt][nt], 0, 0, 0);
        }
    }

    // per-column (pixel) sum of squares across all 256 co
#pragma unroll
    for (int nt = 0; nt < 2; nt++) {
        float s2 = 0.f;
#pragma unroll
        for (int mt = 0; mt < 4; mt++)
#pragma unroll
            for (int r = 0; r < 4; r++) s2 = fmaf(acc[mt][nt][r], acc[mt][nt][r], s2);
        s2 += __shfl_xor(s2, 16); s2 += __shfl_xor(s2, 32);
        if (quad == 0) csum[w][nt * 16 + tx] = s2;
    }
    __syncthreads();
    float f[2];
#pragma unroll
    for (int nt = 0; nt < 2; nt++) {
        int col = nt * 16 + tx;
        float tot = csum[0][col] + csum[1][col] + csum[2][col] + csum[3][col];
        f[nt] = 1.f / (EPSV + sqrtf(tot) * 0.0625f);
    }
    ushort_t* Ls = As;                      // [32 s][264 co]
    float* xb = xn + (size_t)n * COUT * SDIM;
#pragma unroll
    for (int mt = 0; mt < 4; mt++)
#pragma unroll
        for (int r = 0; r < 4; r++) {
            int co = w * 64 + mt * 16 + quad * 4 + r;
#pragma unroll
            for (int nt = 0; nt < 2; nt++) {
                int sp = s0 + nt * 16 + tx;
                float v = acc[mt][nt][r] * f[nt];
                xb[(size_t)co * SDIM + sp] = v;
                Ls[(nt * 16 + tx) * 264 + co] = f2bs(silu_mp(v));
            }
        }
    __syncthreads();
#pragma unroll
    for (int i = 0; i < 4; i++) {
        int ch = tid + i * 256; int row = ch >> 5, c32 = ch & 31;
        *(uint4*)(sxT + ((size_t)n * SDIM + s0 + row) * 256 + c32 * 8) = *(uint4*)&Ls[row * 264 + c32 * 8];
    }
}

// ---------------- bf16 MFMA conv GEMM, 128co x 64s tile, BK=64, reg-prefetch dbuf.
// waves 2x2: wave tile 64co x 32s. grid.x = 16 s-tiles (s0 = bx*64).
// MODE 0: qkv  -> OutT bf16 [n][768][1024]
// MODE 1: res0 -> *cvec, silu, OutT bf16 [n][1024][256] (transposed)
// MODE 2: res1 -> x2 = MPA*xn+MPB*acc; xn fp32 in place; OutT bf16 [n][1024][256]
// MODE 3: proj -> Outf = clip(MPA*RX+MPB*acc) fp32 [n][256][1024]
template<int KDIM, bool GATHER3, int MODE>
__global__ __launch_bounds__(256, 2) void gemm128(const ushort_t* __restrict__ Wp,
                                                  const ushort_t* __restrict__ Bsrc,
                                                  float* RX, float* Outf,
                                                  ushort_t* OutT,
                                                  const float* __restrict__ cvec)
{
    const int n = blockIdx.z, co0 = blockIdx.y * 128, s0 = blockIdx.x * 64;
    const int tid = threadIdx.x, w = tid >> 6, lane = tid & 63;
    const int tx = lane & 15, quad = lane >> 4;
    const int wm = w >> 1, ws = w & 1;

    __shared__ ushort_t SH[(128 + 64) * 72];
    ushort_t* As = SH;                      // [128 co][72]
    ushort_t* Bs = SH + 128 * 72;           // [64 s][72]
    const ushort_t* bn = Bsrc + (size_t)n * SDIM * 256;

    uint4 ra[4], rb[2];
    auto loadA = [&](int k0) {
#pragma unroll
        for (int i = 0; i < 4; i++) {
            int ch = tid + i * 256; int row = ch >> 3, c8 = ch & 7;
            ra[i] = *(const uint4*)(Wp + (size_t)(co0 + row) * KDIM + k0 + c8 * 8);
        }
    };
    auto loadB = [&](int k0) {
        int ci0 = k0, dy = 0, dx = 0;
        if (GATHER3) { int seg = k0 >> 8; ci0 = k0 & 255; int s3 = seg / 3; dy = s3 - 1; dx = seg - s3 * 3 - 1; }
#pragma unroll
        for (int i = 0; i < 2; i++) {
            int ch = tid + i * 256; int row = ch >> 3, c8 = ch & 7;
            int sImg = s0 + row;
            bool valid = true; int sSrc = sImg;
            if (GATHER3) {
                int h = (sImg >> 5) + dy, ww = (sImg & 31) + dx;
                valid = ((unsigned)h < 32u) && ((unsigned)ww < 32u);
                sSrc = (h << 5) | ww;
            }
            rb[i] = valid ? *(const uint4*)(bn + (size_t)sSrc * 256 + ci0 + c8 * 8)
                          : make_uint4(0u, 0u, 0u, 0u);
        }
    };

    f32x4 acc[4][2];
#pragma unroll
    for (int a = 0; a < 4; a++)
#pragma unroll
        for (int b = 0; b < 2; b++) acc[a][b] = (f32x4){0.f, 0.f, 0.f, 0.f};

    loadA(0); loadB(0);
    for (int k0 = 0; k0 < KDIM; k0 += 64) {
        __syncthreads();
#pragma unroll
        for (int i = 0; i < 4; i++) {
            int ch = tid + i * 256; int row = ch >> 3, c8 = ch & 7;
            *(uint4*)&As[row * 72 + c8 * 8] = ra[i];
        }
#pragma unroll
        for (int i = 0; i < 2; i++) {
            int ch = tid + i * 256; int row = ch >> 3, c8 = ch & 7;
            *(uint4*)&Bs[row * 72 + c8 * 8] = rb[i];
        }
        __syncthreads();
        if (k0 + 64 < KDIM) { loadA(k0 + 64); loadB(k0 + 64); }
#pragma unroll
        for (int kc = 0; kc < 2; kc++) {
            s16x8 af[4], bf_[2];
#pragma unroll
            for (int mt = 0; mt < 4; mt++) af[mt] = ldsA(&As[(wm * 64 + mt * 16 + tx) * 72 + kc * 32 + quad * 8]);
#pragma unroll
            for (int nt = 0; nt < 2; nt++) bf_[nt] = ldsA(&Bs[(ws * 32 + nt * 16 + tx) * 72 + kc * 32 + quad * 8]);
#pragma unroll
            for (int mt = 0; mt < 4; mt++)
#pragma unroll
                for (int nt = 0; nt < 2; nt++)
                    acc[mt][nt] = __builtin_amdgcn_mfma_f32_16x16x32_bf16(af[mt], bf_[nt], acc[mt][nt], 0, 0, 0);
        }
    }

    if (MODE == 0) {      // qkv: bf16 [co][s] out via LDS repack
        __syncthreads();
        ushort_t* Ls = SH;                  // [128 co][72 s]
#pragma unroll
        for (int mt = 0; mt < 4; mt++)
#pragma unroll
            for (int nt = 0; nt < 2; nt++)
#pragma unroll
                for (int r = 0; r < 4; r++)
                    Ls[(wm * 64 + mt * 16 + quad * 4 + r) * 72 + ws * 32 + nt * 16 + tx] = f2bs(acc[mt][nt][r]);
        __syncthreads();
        ushort_t* dst = OutT + (size_t)n * 768 * SDIM;
#pragma unroll
        for (int i = 0; i < 4; i++) {
            int ch = tid + i * 256; int row = ch >> 3, c8 = ch & 7;
            *(uint4*)(dst + (size_t)(co0 + row) * SDIM + s0 + c8 * 8) = *(uint4*)&Ls[row * 72 + c8 * 8];
        }
    }
    if (MODE == 1) {      // res0: *c, silu, transposed bf16 out
        float cm[4][4];
#pragma unroll
        for (int mt = 0; mt < 4; mt++)
#pragma unroll
            for (int r = 0; r < 4; r++)
                cm[mt][r] = cvec[n * COUT + co0 + wm * 64 + mt * 16 + quad * 4 + r];
        __syncthreads();
        ushort_t* Ls = SH;                  // [64 s][136 co]
#pragma unroll
        for (int mt = 0; mt < 4; mt++)
#pragma unroll
            for (int nt = 0; nt < 2; nt++)
#pragma unroll
                for (int r = 0; r < 4; r++) {
                    float v = silu_mp(acc[mt][nt][r] * cm[mt][r]);
                    Ls[(ws * 32 + nt * 16 + tx) * 136 + wm * 64 + mt * 16 + quad * 4 + r] = f2bs(v);
                }
        __syncthreads();
#pragma unroll
        for (int i = 0; i < 4; i++) {
            int ch = tid + i * 256; int row = ch >> 4, c16 = ch & 15;
            *(uint4*)(OutT + ((size_t)n * SDIM + s0 + row) * 256 + co0 + c16 * 8) = *(uint4*)&Ls[row * 136 + c16 * 8];
        }
    }
    if (MODE == 2) {      // res1: mp_sum in place on xn, + transposed bf16 out
        __syncthreads();
        ushort_t* Ls = SH;                  // [64 s][136 co]
#pragma unroll
        for (int mt = 0; mt < 4; mt++)
#pragma unroll
            for (int r = 0; r < 4; r++) {
                int col = wm * 64 + mt * 16 + quad * 4 + r;
                float* xp = RX + ((size_t)n * COUT + co0 + col) * SDIM + s0 + ws * 32;
#pragma unroll
                for (int nt = 0; nt < 2; nt++) {
                    float v = MPA * xp[nt * 16 + tx] + MPB * acc[mt][nt][r];
                    xp[nt * 16 + tx] = v;
                    Ls[(ws * 32 + nt * 16 + tx) * 136 + col] = f2bs(v);
                }
            }
        __syncthreads();
#pragma unroll
        for (int i = 0; i < 4; i++) {
            int ch = tid + i * 256; int row = ch >> 4, c16 = ch & 15;
            *(uint4*)(OutT + ((size_t)n * SDIM + s0 + row) * 256 + co0 + c16 * 8) = *(uint4*)&Ls[row * 136 + c16 * 8];
        }
    }
    if (MODE == 3) {      // proj: clip(mp_sum) fp32 out
#pragma unroll
        for (int mt = 0; mt < 4; mt++)
#pragma unroll
            for (int r = 0; r < 4; r++) {
                int co = co0 + wm * 64 + mt * 16 + quad * 4 + r;
                const float* xp = RX + ((size_t)n * COUT + co) * SDIM + s0 + ws * 32;
                float* op = Outf + ((size_t)n * COUT + co) * SDIM + s0 + ws * 32;
#pragma unroll
                for (int nt = 0; nt < 2; nt++) {
                    float v = MPA * xp[nt * 16 + tx] + MPB * acc[mt][nt][r];
                    op[nt * 16 + tx] = fminf(fmaxf(v, -256.f), 256.f);
                }
            }
    }
}

// ---------------- qkv norm over 64 channels per (n,head,t,s), bf16 in place (q * 1/8)
__global__ __launch_bounds__(256) void qkv_norm(ushort_t* qkv)
{
    int g = blockIdx.x * 256 + threadIdx.x;
    int s = g & 1023;
    int rem = g >> 10;
    int t = rem % 3;
    int rem2 = rem / 3;
    int head = rem2 & 3;
    int n = rem2 >> 2;
    ushort_t* base = qkv + (size_t)n * 768 * SDIM + (size_t)(head * 192 + t) * SDIM + s;
    float v[64]; float ss = 0.f;
#pragma unroll
    for (int c = 0; c < 64; c++) { v[c] = bs2f(base[(size_t)c * 3 * SDIM]); ss = fmaf(v[c], v[c], ss); }
    float sc = 1.f / (EPSV + sqrtf(ss) * 0.125f);
    if (t == 0) sc *= 0.125f;
#pragma unroll
    for (int c = 0; c < 64; c++) base[(size_t)c * 3 * SDIM] = f2bs(v[c] * sc);
}

// ---------------- MFMA flash attention (bf16 in, bf16 transposed out aT[n][s][256])
__global__ __launch_bounds__(256, 1) void attn_mfma(const ushort_t* __restrict__ qkv,
                                                    ushort_t* __restrict__ aT)
{
    const int n = blockIdx.z, head = blockIdx.y, q0 = blockIdx.x * 256;
    const int tid  = threadIdx.x;
    const int w    = tid >> 6, lane = tid & 63;
    const int tx   = lane & 15, quad = lane >> 4;

    __shared__ ushort_t Kl[64 * 72];      // [key][c]
    __shared__ ushort_t Vl[64 * 72];      // [c][key]
    __shared__ ushort_t Pl[4][64 * 72];   // per-wave [q][key] / Q stage / O stage

    const ushort_t* base = qkv + (size_t)n * 768 * SDIM + (size_t)head * 192 * SDIM;
    const int qw = q0 + w * 64;

#pragma unroll 8
    for (int c = 0; c < 64; c++)
        Pl[w][lane * 72 + c] = base[(size_t)(c * 3) * SDIM + qw + lane];
    __syncthreads();

    s16x8 qf[4][2];
#pragma unroll
    for (int mt = 0; mt < 4; mt++)
#pragma unroll
        for (int kc = 0; kc < 2; kc++)
            qf[mt][kc] = ldsA(&Pl[w][(mt * 16 + tx) * 72 + kc * 32 + quad * 8]);

    f32x4 acco[4][4];
    float lpart[4][4];
#pragma unroll
    for (int mt = 0; mt < 4; mt++)
#pragma unroll
        for (int nt = 0; nt < 4; nt++) {
            acco[mt][nt] = (f32x4){0.f, 0.f, 0.f, 0.f};
            lpart[mt][nt] = 0.f;
        }

    ushort_t kr[16], vr[16];
#pragma unroll
    for (int j = 0; j < 16; j++) {
        int i = tid + j * 256;
        int c = i >> 6, s = i & 63;
        kr[j] = base[(size_t)(c * 3 + 1) * SDIM + s];
        vr[j] = base[(size_t)(c * 3 + 2) * SDIM + s];
    }

    for (int kt = 0; kt < 16; kt++) {
        __syncthreads();
#pragma unroll
        for (int j = 0; j < 16; j++) {
            int i = tid + j * 256;
            int c = i >> 6, s = i & 63;
            Kl[s * 72 + c] = kr[j];
            Vl[c * 72 + s] = vr[j];
        }
        __syncthreads();
        if (kt < 15) {
            int k0 = (kt + 1) * 64;
#pragma unroll
            for (int j = 0; j < 16; j++) {
                int i = tid + j * 256;
                int c = i >> 6, s = i & 63;
                kr[j] = base[(size_t)(c * 3 + 1) * SDIM + k0 + s];
                vr[j] = base[(size_t)(c * 3 + 2) * SDIM + k0 + s];
            }
        }

        f32x4 accs[4][4];
#pragma unroll
        for (int mt = 0; mt < 4; mt++)
#pragma unroll
            for (int nt = 0; nt < 4; nt++) accs[mt][nt] = (f32x4){0.f, 0.f, 0.f, 0.f};
#pragma unroll
        for (int kc = 0; kc < 2; kc++)
#pragma unroll
            for (int nt = 0; nt < 4; nt++) {
                s16x8 kf = ldsA(&Kl[(nt * 16 + tx) * 72 + kc * 32 + quad * 8]);
#pragma unroll
                for (int mt = 0; mt < 4; mt++)
                    accs[mt][nt] = __builtin_amdgcn_mfma_f32_16x16x32_bf16(
                        qf[mt][kc], kf, accs[mt][nt], 0, 0, 0);
            }

#pragma unroll
        for (int mt = 0; mt < 4; mt++)
#pragma unroll
            for (int nt = 0; nt < 4; nt++)
#pragma unroll
                for (int r = 0; r < 4; r++) {
                    float p = __expf(accs[mt][nt][r]);
                    lpart[mt][r] += p;
                    Pl[w][(mt * 16 + quad * 4 + r) * 72 + nt * 16 + tx] = f2bs(p);
                }
        asm volatile("s_waitcnt lgkmcnt(0)" ::: "memory");

#pragma unroll
        for (int kc = 0; kc < 2; kc++) {
            s16x8 pf[4];
#pragma unroll
            for (int mt = 0; mt < 4; mt++)
                pf[mt] = ldsA(&Pl[w][(mt * 16 + tx) * 72 + kc * 32 + quad * 8]);
#pragma unroll
            for (int nt = 0; nt < 4; nt++) {
                s16x8 vf = ldsA(&Vl[(nt * 16 + tx) * 72 + kc * 32 + quad * 8]);
#pragma unroll
                for (int mt = 0; mt < 4; mt++)
                    acco[mt][nt] = __builtin_amdgcn_mfma_f32_16x16x32_bf16(
                        pf[mt], vf, acco[mt][nt], 0, 0, 0);
            }
        }
    }

    float inv[4][4];
#pragma unroll
    for (int mt = 0; mt < 4; mt++)
#pragma unroll
        for (int r = 0; r < 4; r++) {
            float l = lpart[mt][r];
            l += __shfl_xor(l, 1); l += __shfl_xor(l, 2);
            l += __shfl_xor(l, 4); l += __shfl_xor(l, 8);
            inv[mt][r] = 1.0f / l;
        }

    // O is already [q][c] in acc layout -> stage bf16 rows, write aT[n][qw+q][head*64 + c]
#pragma unroll
    for (int mt = 0; mt < 4; mt++)
#pragma unroll
        for (int nt = 0; nt < 4; nt++)
#pragma unroll
            for (int r = 0; r < 4; r++)
                Pl[w][(mt * 16 + quad * 4 + r) * 72 + nt * 16 + tx] = f2bs(acco[mt][nt][r] * inv[mt][r]);
    asm volatile("s_waitcnt lgkmcnt(0)" ::: "memory");
    ushort_t* dst = aT + ((size_t)n * SDIM + qw) * 256 + head * 64;
#pragma unroll
    for (int i = 0; i < 8; i++) {
        int ch = lane + i * 64; int row = ch >> 3, c8 = ch & 7;
        *(uint4*)(dst + (size_t)row * 256 + c8 * 8) = *(uint4*)&Pl[w][row * 72 + c8 * 8];
    }
}

extern "C" void kernel_launch(void* const* d_in, const int* in_sizes, int n_in,
                              void* d_out, int out_size, void* d_ws, size_t ws_size,
                              hipStream_t stream)
{
    const float* x      = (const float*)d_in[0];
    const float* emb    = (const float*)d_in[1];
    const float* w_skip = (const float*)d_in[2];
    const float* w_res0 = (const float*)d_in[3];
    const float* w_res1 = (const float*)d_in[4];
    const float* w_emb  = (const float*)d_in[5];
    const float* e_gain = (const float*)d_in[6];
    const float* w_qkv  = (const float*)d_in[7];
    const float* w_proj = (const float*)d_in[8];
    float* out = (float*)d_out;

    char* p = (char*)d_ws;
    auto alloc = [&](size_t bytes) { void* r = (void*)p; p += (bytes + 255) & ~(size_t)255; return r; };
    ushort_t* wskip_bf = (ushort_t*)alloc(256 * 192 * 2);
    ushort_t* wres0_bf = (ushort_t*)alloc(256 * 2304 * 2);
    ushort_t* wres1_bf = (ushort_t*)alloc(256 * 2304 * 2);
    ushort_t* wqkv_bf  = (ushort_t*)alloc(768 * 256 * 2);
    ushort_t* wproj_bf = (ushort_t*)alloc(256 * 256 * 2);
    float*    wemb_n   = (float*)alloc(256 * 768 * 4);
    float*    cvec     = (float*)alloc(16 * 256 * 4);
    ushort_t* xT   = (ushort_t*)alloc((size_t)16 * 1024 * 192 * 2);
    ushort_t* sxT  = (ushort_t*)alloc((size_t)16 * 1024 * 256 * 2);
    ushort_t* ysT  = (ushort_t*)alloc((size_t)16 * 1024 * 256 * 2);
    ushort_t* x2T  = (ushort_t*)alloc((size_t)16 * 1024 * 256 * 2);
    ushort_t* aT   = (ushort_t*)alloc((size_t)16 * 1024 * 256 * 2);
    float*    xn   = (float*)alloc((size_t)16 * 256 * 1024 * 4);
    ushort_t* qkvb = (ushort_t*)alloc((size_t)16 * 768 * 1024 * 2);

    wnorm_bf16<false><<<256, 256, 0, stream>>>(w_skip, wskip_bf, 192);
    wnorm_bf16<true ><<<256, 256, 0, stream>>>(w_res0, wres0_bf, 2304);
    wnorm_bf16<true ><<<256, 256, 0, stream>>>(w_res1, wres1_bf, 2304);
    wnorm_bf16<false><<<768, 256, 0, stream>>>(w_qkv,  wqkv_bf,  256);
    wnorm_bf16<false><<<256, 256, 0, stream>>>(w_proj, wproj_bf, 256);
    wnorm<<<256, 256, 0, stream>>>(w_emb, wemb_n, 768, e_gain);

    emb_mm<<<16, 256, 0, stream>>>(emb, wemb_n, cvec);
    prep_xT<<<dim3(16, 3, 16), 256, 0, stream>>>(x, xT);

    // fused skip conv + pix_norm + silu  (512 blocks)
    skip_fused<<<dim3(32, 1, 16), 256, 0, stream>>>(wskip_bf, xT, xn, sxT);
    // res0: y = conv3x3(sx) * c; ysT = silu(y)   (512 blocks)
    gemm128<2304, true, 1><<<dim3(16, 2, 16), 256, 0, stream>>>(wres0_bf, sxT, nullptr, nullptr, ysT, cvec);
    // res1: x2 = mp_sum(xn, conv3x3(ys)); xn <- x2 (in place) + x2T   (512 blocks)
    gemm128<2304, true, 2><<<dim3(16, 2, 16), 256, 0, stream>>>(wres1_bf, ysT, xn, nullptr, x2T, nullptr);
    // qkv = conv1x1(x2) -> bf16 [co][s]   (1536 blocks)
    gemm128<256, false, 0><<<dim3(16, 6, 16), 256, 0, stream>>>(wqkv_bf, x2T, nullptr, nullptr, qkvb, nullptr);
    // per-(n,h,t,s) norm over 64 ch (q pre-scaled by 1/8)
    qkv_norm<<<768, 256, 0, stream>>>(qkvb);
    // attention -> aT [n][s][256] bf16
    attn_mfma<<<dim3(4, 4, 16), 256, 0, stream>>>(qkvb, aT);
    // out = clip(mp_sum(x2, conv1x1(attn)))   (512 blocks)
    gemm128<256, false, 3><<<dim3(16, 2, 16), 256, 0, stream>>>(wproj_bf, aT, xn, out, nullptr, nullptr);
}

// Round 5
// 335.959 us; speedup vs baseline: 8.3247x; 1.3305x over previous
//
#include <hip/hip_runtime.h>
#include <math.h>

#define SDIM 1024
#define COUT 256

#define EPSV     1e-4f
#define SILU_INV 1.6778523489932886f   // 1/0.596
#define MPA      0.9191450300180579f   // 0.7/sqrt(0.58)
#define MPB      0.3939192985791677f   // 0.3/sqrt(0.58)

typedef short s16x8 __attribute__((ext_vector_type(8)));
typedef float f32x4 __attribute__((ext_vector_type(4)));
typedef unsigned short ushort_t;

__device__ inline ushort_t f2bs(float f) {
    unsigned u = __float_as_uint(f);
    u += 0x7fffu + ((u >> 16) & 1u);        // round-nearest-even
    return (ushort_t)(u >> 16);
}
__device__ inline float bs2f(ushort_t u) { return __uint_as_float(((unsigned)u) << 16); }
__device__ inline float silu_mp(float v) { return v * SILU_INV / (1.f + __expf(-v)); }

union F8 { s16x8 v; uint4 q; };
__device__ inline s16x8 ldsA(const ushort_t* p) {   // p is 16B-aligned by construction
    F8 r; r.q = *(const uint4*)p; return r.v;
}

// async global -> LDS, 16 B per lane. LDS dst = wave-uniform base + lane*16.
typedef const __attribute__((address_space(1))) unsigned int* gas_ptr;
typedef __attribute__((address_space(3))) unsigned int* las_ptr;
__device__ inline void gld16(const void* g, void* l) {
    __builtin_amdgcn_global_load_lds((gas_ptr)g, (las_ptr)l, 16, 0, 0);
}

// ---------------- zero-fill scratch line for OOB gather lanes
__global__ void zfill(uint4* z) { z[threadIdx.x] = make_uint4(0u, 0u, 0u, 0u); }

// ---------------- weight normalization (fp32 out, for w_emb)
__global__ __launch_bounds__(256) void wnorm(const float* __restrict__ w,
                                             float* __restrict__ wn,
                                             int fanin,
                                             const float* __restrict__ gain_ptr)
{
    int o = blockIdx.x;
    const float* row = w + (size_t)o * fanin;
    float ss = 0.f;
    for (int i = threadIdx.x; i < fanin; i += 256) { float v = row[i]; ss += v * v; }
    for (int off = 32; off >= 1; off >>= 1) ss += __shfl_down(ss, off);
    __shared__ float red[4];
    int lane = threadIdx.x & 63, wv = threadIdx.x >> 6;
    if (lane == 0) red[wv] = ss;
    __syncthreads();
    float tot = red[0] + red[1] + red[2] + red[3];
    float gain = gain_ptr ? *gain_ptr : 1.0f;
    float scale = gain / (EPSV * sqrtf((float)fanin) + sqrtf(tot));
    for (int i = threadIdx.x; i < fanin; i += 256)
        wn[(size_t)o * fanin + i] = row[i] * scale;
}

// ---------------- weight normalization -> bf16 (optional K reorder (ci,3,3)->(3x3,ci))
template<bool REORDER>
__global__ __launch_bounds__(256) void wnorm_bf16(const float* __restrict__ w,
                                                  ushort_t* __restrict__ wn,
                                                  int fanin)
{
    int o = blockIdx.x;
    const float* row = w + (size_t)o * fanin;
    float ss = 0.f;
    for (int i = threadIdx.x; i < fanin; i += 256) { float v = row[i]; ss += v * v; }
    for (int off = 32; off >= 1; off >>= 1) ss += __shfl_down(ss, off);
    __shared__ float red[4];
    int lane = threadIdx.x & 63, wv = threadIdx.x >> 6;
    if (lane == 0) red[wv] = ss;
    __syncthreads();
    float tot = red[0] + red[1] + red[2] + red[3];
    float scale = 1.0f / (EPSV * sqrtf((float)fanin) + sqrtf(tot));
    for (int i = threadIdx.x; i < fanin; i += 256) {
        int kd = i;
        if (REORDER) { int ci = i / 9; int r9 = i - ci * 9; kd = r9 * 256 + ci; }
        wn[(size_t)o * fanin + kd] = f2bs(row[i] * scale);
    }
}

// ---------------- c = emb @ wemb_n^T + 1
__global__ __launch_bounds__(256) void emb_mm(const float* __restrict__ emb,
                                              const float* __restrict__ wemb,
                                              float* __restrict__ cvec)
{
    int n = blockIdx.x;
    int co = threadIdx.x;
    const float* e  = emb  + (size_t)n * 768;
    const float* wr = wemb + (size_t)co * 768;
    float s = 0.f;
    for (int i = 0; i < 768; i++) s = fmaf(e[i], wr[i], s);
    cvec[n * COUT + co] = s + 1.0f;
}

// ---------------- transpose x [n][192][1024] fp32 -> xT [n][1024][192] bf16
__global__ __launch_bounds__(256) void prep_xT(const float* __restrict__ x,
                                               ushort_t* __restrict__ xT)
{
    const int n = blockIdx.z, ci0 = blockIdx.y * 64, s0 = blockIdx.x * 64;
    const int tid = threadIdx.x;
    __shared__ float T[64 * 65];
#pragma unroll
    for (int i = 0; i < 16; i++) {
        int ch = tid + i * 256; int row = ch >> 6, cc = ch & 63;
        T[row * 65 + cc] = x[((size_t)n * 192 + ci0 + row) * SDIM + s0 + cc];
    }
    __syncthreads();
#pragma unroll
    for (int i = 0; i < 2; i++) {
        int ch = tid + i * 256; int srow = ch >> 3, c8 = ch & 7;
        ushort_t tmp[8];
#pragma unroll
        for (int j = 0; j < 8; j++) tmp[j] = f2bs(T[(c8 * 8 + j) * 65 + srow]);
        *(uint4*)(xT + ((size_t)n * SDIM + s0 + srow) * 192 + ci0 + c8 * 8) = *(uint4*)tmp;
    }
}

// ---------------- fused: x1 = conv1x1(x, wskip); xn = pix_norm(x1); sxT = silu(xn)
__global__ __launch_bounds__(256, 2) void skip_fused(const ushort_t* __restrict__ Wp,   // [256][192]
                                                     const ushort_t* __restrict__ xT,   // [n][1024][192]
                                                     float* __restrict__ xn,
                                                     ushort_t* __restrict__ sxT)
{
    const int n = blockIdx.z, s0 = blockIdx.x * 32;
    const int tid = threadIdx.x, w = tid >> 6, lane = tid & 63;
    const int tx = lane & 15, quad = lane >> 4;

    __shared__ ushort_t As[256 * 72];
    __shared__ ushort_t Bs[32 * 72];
    __shared__ float csum[4][32];

    f32x4 acc[4][2];
#pragma unroll
    for (int a = 0; a < 4; a++)
#pragma unroll
        for (int b = 0; b < 2; b++) acc[a][b] = (f32x4){0.f, 0.f, 0.f, 0.f};

    for (int k0 = 0; k0 < 192; k0 += 64) {
        __syncthreads();
#pragma unroll
        for (int i = 0; i < 8; i++) {
            int ch = tid + i * 256; int row = ch >> 3, c8 = ch & 7;
            *(uint4*)&As[row * 72 + c8 * 8] = *(const uint4*)(Wp + (size_t)row * 192 + k0 + c8 * 8);
        }
        {
            int row = tid >> 3, c8 = tid & 7;
            *(uint4*)&Bs[row * 72 + c8 * 8] =
                *(const uint4*)(xT + ((size_t)n * SDIM + s0 + row) * 192 + k0 + c8 * 8);
        }
        __syncthreads();
#pragma unroll
        for (int kc = 0; kc < 2; kc++) {
            s16x8 af[4], bf_[2];
#pragma unroll
            for (int mt = 0; mt < 4; mt++) af[mt] = ldsA(&As[(w * 64 + mt * 16 + tx) * 72 + kc * 32 + quad * 8]);
#pragma unroll
            for (int nt = 0; nt < 2; nt++) bf_[nt] = ldsA(&Bs[(nt * 16 + tx) * 72 + kc * 32 + quad * 8]);
#pragma unroll
            for (int mt = 0; mt < 4; mt++)
#pragma unroll
                for (int nt = 0; nt < 2; nt++)
                    acc[mt][nt] = __builtin_amdgcn_mfma_f32_16x16x32_bf16(af[mt], bf_[nt], acc[mt][nt], 0, 0, 0);
        }
    }

#pragma unroll
    for (int nt = 0; nt < 2; nt++) {
        float s2 = 0.f;
#pragma unroll
        for (int mt = 0; mt < 4; mt++)
#pragma unroll
            for (int r = 0; r < 4; r++) s2 = fmaf(acc[mt][nt][r], acc[mt][nt][r], s2);
        s2 += __shfl_xor(s2, 16); s2 += __shfl_xor(s2, 32);
        if (quad == 0) csum[w][nt * 16 + tx] = s2;
    }
    __syncthreads();
    float f[2];
#pragma unroll
    for (int nt = 0; nt < 2; nt++) {
        int col = nt * 16 + tx;
        float tot = csum[0][col] + csum[1][col] + csum[2][col] + csum[3][col];
        f[nt] = 1.f / (EPSV + sqrtf(tot) * 0.0625f);
    }
    ushort_t* Ls = As;                      // [32 s][264 co]
    float* xb = xn + (size_t)n * COUT * SDIM;
#pragma unroll
    for (int mt = 0; mt < 4; mt++)
#pragma unroll
        for (int r = 0; r < 4; r++) {
            int co = w * 64 + mt * 16 + quad * 4 + r;
#pragma unroll
            for (int nt = 0; nt < 2; nt++) {
                int sp = s0 + nt * 16 + tx;
                float v = acc[mt][nt][r] * f[nt];
                xb[(size_t)co * SDIM + sp] = v;
                Ls[(nt * 16 + tx) * 264 + co] = f2bs(silu_mp(v));
            }
        }
    __syncthreads();
#pragma unroll
    for (int i = 0; i < 4; i++) {
        int ch = tid + i * 256; int row = ch >> 5, c32 = ch & 31;
        *(uint4*)(sxT + ((size_t)n * SDIM + s0 + row) * 256 + c32 * 8) = *(uint4*)&Ls[row * 264 + c32 * 8];
    }
}

// ---------------- bf16 MFMA conv GEMM, m97-style: global_load_lds staging,
// XOR-swizzled unpadded 128B LDS rows, double-buffered stages, 128co x 128s tile,
// 4 waves as 2x2 (wave tile 64x64), BK=64.
// LDS slot [row][c8] holds global k-chunk (c8 ^ (row&7)); frag read applies same XOR.
// MODE 0: qkv  -> OutT bf16 [n][768][1024]
// MODE 1: res0 -> *cvec, silu, OutT bf16 [n][1024][256] (transposed)
// MODE 2: res1 -> x2 = MPA*xn+MPB*acc; xn fp32 in place; OutT bf16 [n][1024][256]
// MODE 3: proj -> Outf = clip(MPA*RX+MPB*acc) fp32 [n][256][1024]
template<int KDIM, bool GATHER3, int MODE>
__global__ __launch_bounds__(256, 1) void gemm_glds(const ushort_t* __restrict__ Wp,
                                                    const ushort_t* __restrict__ Bsrc,
                                                    const ushort_t* __restrict__ zbuf,
                                                    float* RX, float* Outf,
                                                    ushort_t* OutT,
                                                    const float* __restrict__ cvec)
{
    const int n = blockIdx.z, co0 = blockIdx.y * 128, s0 = blockIdx.x * 128;
    const int tid = threadIdx.x, w = tid >> 6, lane = tid & 63;
    const int tx = lane & 15, quad = lane >> 4;
    const int wm = w >> 1, ws = w & 1;
    const int l8 = lane & 7, ld = lane >> 3;     // chunk slot, row-in-8
    const int swz = (l8 ^ ld) * 8;               // global k-offset (elements) for this lane

    // 2 stages x (A[128][64] + B[128][64]) bf16 = 64 KB
    __shared__ ushort_t SH[2 * 16384];

    const ushort_t* bn = Bsrc + (size_t)n * SDIM * 256;

    auto stageA = [&](int p, int k0) {
        ushort_t* Ab = SH + p * 16384;
#pragma unroll
        for (int j = 0; j < 4; j++) {
            int row0 = w * 32 + j * 8;
            const ushort_t* g = Wp + (size_t)(co0 + row0 + ld) * KDIM + k0 + swz;
            gld16(g, Ab + row0 * 64);
        }
    };
    auto stageB = [&](int p, int k0) {
        ushort_t* Bb = SH + p * 16384 + 8192;
        int ci0 = k0, dy = 0, dx = 0;
        if (GATHER3) { int seg = k0 >> 8; ci0 = k0 & 255; int s3 = seg / 3; dy = s3 - 1; dx = seg - s3 * 3 - 1; }
#pragma unroll
        for (int j = 0; j < 4; j++) {
            int row0 = w * 32 + j * 8;
            int srow = row0 + ld;
            const ushort_t* g;
            if (GATHER3) {
                int pix = s0 + srow;
                int h = (pix >> 5) + dy, wx = (pix & 31) + dx;
                bool valid = ((unsigned)h < 32u) && ((unsigned)wx < 32u);
                int sSrc = (h << 5) + wx;
                g = valid ? (bn + (size_t)sSrc * 256 + ci0 + swz) : zbuf;
            } else {
                g = bn + (size_t)(s0 + srow) * 256 + k0 + swz;
            }
            gld16(g, Bb + row0 * 64);
        }
    };

    f32x4 acc[4][4];
#pragma unroll
    for (int a = 0; a < 4; a++)
#pragma unroll
        for (int b = 0; b < 4; b++) acc[a][b] = (f32x4){0.f, 0.f, 0.f, 0.f};

    constexpr int NK = KDIM / 64;
    stageA(0, 0); stageB(0, 0);
    __syncthreads();

    for (int kt = 0; kt < NK; kt++) {
        int p = kt & 1;
        if (kt + 1 < NK) { stageA(p ^ 1, (kt + 1) * 64); stageB(p ^ 1, (kt + 1) * 64); }
        const ushort_t* Ab = SH + p * 16384;
        const ushort_t* Bb = Ab + 8192;
#pragma unroll
        for (int kc = 0; kc < 2; kc++) {
            int koff = ((kc * 4 + quad) ^ (tx & 7)) * 8;
            s16x8 af[4], bfv[4];
#pragma unroll
            for (int mt = 0; mt < 4; mt++) af[mt]  = ldsA(&Ab[(wm * 64 + mt * 16 + tx) * 64 + koff]);
#pragma unroll
            for (int nt = 0; nt < 4; nt++) bfv[nt] = ldsA(&Bb[(ws * 64 + nt * 16 + tx) * 64 + koff]);
#pragma unroll
            for (int mt = 0; mt < 4; mt++)
#pragma unroll
                for (int nt = 0; nt < 4; nt++)
                    acc[mt][nt] = __builtin_amdgcn_mfma_f32_16x16x32_bf16(af[mt], bfv[nt], acc[mt][nt], 0, 0, 0);
        }
        __syncthreads();     // drains this iteration's prefetch DMA (covered by compute above)
    }

    if (MODE == 0) {      // qkv: bf16 [co][s] out via LDS repack
        ushort_t* Ls = SH;                  // [128 co][136 s]
#pragma unroll
        for (int mt = 0; mt < 4; mt++)
#pragma unroll
            for (int nt = 0; nt < 4; nt++)
#pragma unroll
                for (int r = 0; r < 4; r++)
                    Ls[(wm * 64 + mt * 16 + quad * 4 + r) * 136 + ws * 64 + nt * 16 + tx] = f2bs(acc[mt][nt][r]);
        __syncthreads();
        ushort_t* dst = OutT + (size_t)n * 768 * SDIM;
#pragma unroll
        for (int i = 0; i < 8; i++) {
            int ch = tid + i * 256; int row = ch >> 4, c16 = ch & 15;
            *(uint4*)(dst + (size_t)(co0 + row) * SDIM + s0 + c16 * 8) = *(uint4*)&Ls[row * 136 + c16 * 8];
        }
    }
    if (MODE == 1) {      // res0: *c, silu, transposed bf16 out
        float cm[4][4];
#pragma unroll
        for (int mt = 0; mt < 4; mt++)
#pragma unroll
            for (int r = 0; r < 4; r++)
                cm[mt][r] = cvec[n * COUT + co0 + wm * 64 + mt * 16 + quad * 4 + r];
        ushort_t* Ls = SH;                  // [128 s][136 co]
#pragma unroll
        for (int mt = 0; mt < 4; mt++)
#pragma unroll
            for (int nt = 0; nt < 4; nt++)
#pragma unroll
                for (int r = 0; r < 4; r++) {
                    float v = silu_mp(acc[mt][nt][r] * cm[mt][r]);
                    Ls[(ws * 64 + nt * 16 + tx) * 136 + wm * 64 + mt * 16 + quad * 4 + r] = f2bs(v);
                }
        __syncthreads();
#pragma unroll
        for (int i = 0; i < 8; i++) {
            int ch = tid + i * 256; int row = ch >> 4, c16 = ch & 15;
            *(uint4*)(OutT + ((size_t)n * SDIM + s0 + row) * 256 + co0 + c16 * 8) = *(uint4*)&Ls[row * 136 + c16 * 8];
        }
    }
    if (MODE == 2) {      // res1: mp_sum in place on xn, + transposed bf16 out
        ushort_t* Ls = SH;                  // [128 s][136 co]
#pragma unroll
        for (int mt = 0; mt < 4; mt++)
#pragma unroll
            for (int r = 0; r < 4; r++) {
                int col = wm * 64 + mt * 16 + quad * 4 + r;
                float* xp = RX + ((size_t)n * COUT + co0 + col) * SDIM + s0 + ws * 64;
#pragma unroll
                for (int nt = 0; nt < 4; nt++) {
                    float v = MPA * xp[nt * 16 + tx] + MPB * acc[mt][nt][r];
                    xp[nt * 16 + tx] = v;
                    Ls[(ws * 64 + nt * 16 + tx) * 136 + col] = f2bs(v);
                }
            }
        __syncthreads();
#pragma unroll
        for (int i = 0; i < 8; i++) {
            int ch = tid + i * 256; int row = ch >> 4, c16 = ch & 15;
            *(uint4*)(OutT + ((size_t)n * SDIM + s0 + row) * 256 + co0 + c16 * 8) = *(uint4*)&Ls[row * 136 + c16 * 8];
        }
    }
    if (MODE == 3) {      // proj: clip(mp_sum) fp32 out
#pragma unroll
        for (int mt = 0; mt < 4; mt++)
#pragma unroll
            for (int r = 0; r < 4; r++) {
                int co = co0 + wm * 64 + mt * 16 + quad * 4 + r;
                const float* xp = RX + ((size_t)n * COUT + co) * SDIM + s0 + ws * 64;
                float* op = Outf + ((size_t)n * COUT + co) * SDIM + s0 + ws * 64;
#pragma unroll
                for (int nt = 0; nt < 4; nt++) {
                    float v = MPA * xp[nt * 16 + tx] + MPB * acc[mt][nt][r];
                    op[nt * 16 + tx] = fminf(fmaxf(v, -256.f), 256.f);
                }
            }
    }
}

// ---------------- qkv norm over 64 channels per (n,head,t,s), bf16 in place (q * 1/8)
__global__ __launch_bounds__(256) void qkv_norm(ushort_t* qkv)
{
    int g = blockIdx.x * 256 + threadIdx.x;
    int s = g & 1023;
    int rem = g >> 10;
    int t = rem % 3;
    int rem2 = rem / 3;
    int head = rem2 & 3;
    int n = rem2 >> 2;
    ushort_t* base = qkv + (size_t)n * 768 * SDIM + (size_t)(head * 192 + t) * SDIM + s;
    float v[64]; float ss = 0.f;
#pragma unroll
    for (int c = 0; c < 64; c++) { v[c] = bs2f(base[(size_t)c * 3 * SDIM]); ss = fmaf(v[c], v[c], ss); }
    float sc = 1.f / (EPSV + sqrtf(ss) * 0.125f);
    if (t == 0) sc *= 0.125f;
#pragma unroll
    for (int c = 0; c < 64; c++) base[(size_t)c * 3 * SDIM] = f2bs(v[c] * sc);
}

// ---------------- MFMA flash attention (bf16 in, bf16 transposed out aT[n][s][256])
__global__ __launch_bounds__(256, 1) void attn_mfma(const ushort_t* __restrict__ qkv,
                                                    ushort_t* __restrict__ aT)
{
    const int n = blockIdx.z, head = blockIdx.y, q0 = blockIdx.x * 256;
    const int tid  = threadIdx.x;
    const int w    = tid >> 6, lane = tid & 63;
    const int tx   = lane & 15, quad = lane >> 4;

    __shared__ ushort_t Kl[64 * 72];      // [key][c]
    __shared__ ushort_t Vl[64 * 72];      // [c][key]
    __shared__ ushort_t Pl[4][64 * 72];   // per-wave [q][key] / Q stage / O stage

    const ushort_t* base = qkv + (size_t)n * 768 * SDIM + (size_t)head * 192 * SDIM;
    const int qw = q0 + w * 64;

#pragma unroll 8
    for (int c = 0; c < 64; c++)
        Pl[w][lane * 72 + c] = base[(size_t)(c * 3) * SDIM + qw + lane];
    __syncthreads();

    s16x8 qf[4][2];
#pragma unroll
    for (int mt = 0; mt < 4; mt++)
#pragma unroll
        for (int kc = 0; kc < 2; kc++)
            qf[mt][kc] = ldsA(&Pl[w][(mt * 16 + tx) * 72 + kc * 32 + quad * 8]);

    f32x4 acco[4][4];
    float lpart[4][4];
#pragma unroll
    for (int mt = 0; mt < 4; mt++)
#pragma unroll
        for (int nt = 0; nt < 4; nt++) {
            acco[mt][nt] = (f32x4){0.f, 0.f, 0.f, 0.f};
            lpart[mt][nt] = 0.f;
        }

    ushort_t kr[16], vr[16];
#pragma unroll
    for (int j = 0; j < 16; j++) {
        int i = tid + j * 256;
        int c = i >> 6, s = i & 63;
        kr[j] = base[(size_t)(c * 3 + 1) * SDIM + s];
        vr[j] = base[(size_t)(c * 3 + 2) * SDIM + s];
    }

    for (int kt = 0; kt < 16; kt++) {
        __syncthreads();
#pragma unroll
        for (int j = 0; j < 16; j++) {
            int i = tid + j * 256;
            int c = i >> 6, s = i & 63;
            Kl[s * 72 + c] = kr[j];
            Vl[c * 72 + s] = vr[j];
        }
        __syncthreads();
        if (kt < 15) {
            int k0 = (kt + 1) * 64;
#pragma unroll
            for (int j = 0; j < 16; j++) {
                int i = tid + j * 256;
                int c = i >> 6, s = i & 63;
                kr[j] = base[(size_t)(c * 3 + 1) * SDIM + k0 + s];
                vr[j] = base[(size_t)(c * 3 + 2) * SDIM + k0 + s];
            }
        }

        f32x4 accs[4][4];
#pragma unroll
        for (int mt = 0; mt < 4; mt++)
#pragma unroll
            for (int nt = 0; nt < 4; nt++) accs[mt][nt] = (f32x4){0.f, 0.f, 0.f, 0.f};
#pragma unroll
        for (int kc = 0; kc < 2; kc++)
#pragma unroll
            for (int nt = 0; nt < 4; nt++) {
                s16x8 kf = ldsA(&Kl[(nt * 16 + tx) * 72 + kc * 32 + quad * 8]);
#pragma unroll
                for (int mt = 0; mt < 4; mt++)
                    accs[mt][nt] = __builtin_amdgcn_mfma_f32_16x16x32_bf16(
                        qf[mt][kc], kf, accs[mt][nt], 0, 0, 0);
            }

#pragma unroll
        for (int mt = 0; mt < 4; mt++)
#pragma unroll
            for (int nt = 0; nt < 4; nt++)
#pragma unroll
                for (int r = 0; r < 4; r++) {
                    float p = __expf(accs[mt][nt][r]);
                    lpart[mt][r] += p;
                    Pl[w][(mt * 16 + quad * 4 + r) * 72 + nt * 16 + tx] = f2bs(p);
                }
        asm volatile("s_waitcnt lgkmcnt(0)" ::: "memory");

#pragma unroll
        for (int kc = 0; kc < 2; kc++) {
            s16x8 pf[4];
#pragma unroll
            for (int mt = 0; mt < 4; mt++)
                pf[mt] = ldsA(&Pl[w][(mt * 16 + tx) * 72 + kc * 32 + quad * 8]);
#pragma unroll
            for (int nt = 0; nt < 4; nt++) {
                s16x8 vf = ldsA(&Vl[(nt * 16 + tx) * 72 + kc * 32 + quad * 8]);
#pragma unroll
                for (int mt = 0; mt < 4; mt++)
                    acco[mt][nt] = __builtin_amdgcn_mfma_f32_16x16x32_bf16(
                        pf[mt], vf, acco[mt][nt], 0, 0, 0);
            }
        }
    }

    float inv[4][4];
#pragma unroll
    for (int mt = 0; mt < 4; mt++)
#pragma unroll
        for (int r = 0; r < 4; r++) {
            float l = lpart[mt][r];
            l += __shfl_xor(l, 1); l += __shfl_xor(l, 2);
            l += __shfl_xor(l, 4); l += __shfl_xor(l, 8);
            inv[mt][r] = 1.0f / l;
        }

#pragma unroll
    for (int mt = 0; mt < 4; mt++)
#pragma unroll
        for (int nt = 0; nt < 4; nt++)
#pragma unroll
            for (int r = 0; r < 4; r++)
                Pl[w][(mt * 16 + quad * 4 + r) * 72 + nt * 16 + tx] = f2bs(acco[mt][nt][r] * inv[mt][r]);
    asm volatile("s_waitcnt lgkmcnt(0)" ::: "memory");
    ushort_t* dst = aT + ((size_t)n * SDIM + qw) * 256 + head * 64;
#pragma unroll
    for (int i = 0; i < 8; i++) {
        int ch = lane + i * 64; int row = ch >> 3, c8 = ch & 7;
        *(uint4*)(dst + (size_t)row * 256 + c8 * 8) = *(uint4*)&Pl[w][row * 72 + c8 * 8];
    }
}

extern "C" void kernel_launch(void* const* d_in, const int* in_sizes, int n_in,
                              void* d_out, int out_size, void* d_ws, size_t ws_size,
                              hipStream_t stream)
{
    const float* x      = (const float*)d_in[0];
    const float* emb    = (const float*)d_in[1];
    const float* w_skip = (const float*)d_in[2];
    const float* w_res0 = (const float*)d_in[3];
    const float* w_res1 = (const float*)d_in[4];
    const float* w_emb  = (const float*)d_in[5];
    const float* e_gain = (const float*)d_in[6];
    const float* w_qkv  = (const float*)d_in[7];
    const float* w_proj = (const float*)d_in[8];
    float* out = (float*)d_out;

    char* p = (char*)d_ws;
    auto alloc = [&](size_t bytes) { void* r = (void*)p; p += (bytes + 255) & ~(size_t)255; return r; };
    ushort_t* wskip_bf = (ushort_t*)alloc(256 * 192 * 2);
    ushort_t* wres0_bf = (ushort_t*)alloc(256 * 2304 * 2);
    ushort_t* wres1_bf = (ushort_t*)alloc(256 * 2304 * 2);
    ushort_t* wqkv_bf  = (ushort_t*)alloc(768 * 256 * 2);
    ushort_t* wproj_bf = (ushort_t*)alloc(256 * 256 * 2);
    float*    wemb_n   = (float*)alloc(256 * 768 * 4);
    float*    cvec     = (float*)alloc(16 * 256 * 4);
    ushort_t* zbuf     = (ushort_t*)alloc(1024);
    ushort_t* xT   = (ushort_t*)alloc((size_t)16 * 1024 * 192 * 2);
    ushort_t* sxT  = (ushort_t*)alloc((size_t)16 * 1024 * 256 * 2);
    ushort_t* ysT  = (ushort_t*)alloc((size_t)16 * 1024 * 256 * 2);
    ushort_t* x2T  = (ushort_t*)alloc((size_t)16 * 1024 * 256 * 2);
    ushort_t* aT   = (ushort_t*)alloc((size_t)16 * 1024 * 256 * 2);
    float*    xn   = (float*)alloc((size_t)16 * 256 * 1024 * 4);
    ushort_t* qkvb = (ushort_t*)alloc((size_t)16 * 768 * 1024 * 2);

    zfill<<<1, 64, 0, stream>>>((uint4*)zbuf);
    wnorm_bf16<false><<<256, 256, 0, stream>>>(w_skip, wskip_bf, 192);
    wnorm_bf16<true ><<<256, 256, 0, stream>>>(w_res0, wres0_bf, 2304);
    wnorm_bf16<true ><<<256, 256, 0, stream>>>(w_res1, wres1_bf, 2304);
    wnorm_bf16<false><<<768, 256, 0, stream>>>(w_qkv,  wqkv_bf,  256);
    wnorm_bf16<false><<<256, 256, 0, stream>>>(w_proj, wproj_bf, 256);
    wnorm<<<256, 256, 0, stream>>>(w_emb, wemb_n, 768, e_gain);

    emb_mm<<<16, 256, 0, stream>>>(emb, wemb_n, cvec);
    prep_xT<<<dim3(16, 3, 16), 256, 0, stream>>>(x, xT);

    // fused skip conv + pix_norm + silu
    skip_fused<<<dim3(32, 1, 16), 256, 0, stream>>>(wskip_bf, xT, xn, sxT);
    // res0: y = conv3x3(sx) * c; ysT = silu(y)
    gemm_glds<2304, true, 1><<<dim3(8, 2, 16), 256, 0, stream>>>(wres0_bf, sxT, zbuf, nullptr, nullptr, ysT, cvec);
    // res1: x2 = mp_sum(xn, conv3x3(ys)); xn <- x2 (in place) + x2T
    gemm_glds<2304, true, 2><<<dim3(8, 2, 16), 256, 0, stream>>>(wres1_bf, ysT, zbuf, xn, nullptr, x2T, nullptr);
    // qkv = conv1x1(x2) -> bf16 [co][s]
    gemm_glds<256, false, 0><<<dim3(8, 6, 16), 256, 0, stream>>>(wqkv_bf, x2T, zbuf, nullptr, nullptr, qkvb, nullptr);
    // per-(n,h,t,s) norm over 64 ch (q pre-scaled by 1/8)
    qkv_norm<<<768, 256, 0, stream>>>(qkvb);
    // attention -> aT [n][s][256] bf16
    attn_mfma<<<dim3(4, 4, 16), 256, 0, stream>>>(qkvb, aT);
    // out = clip(mp_sum(x2, conv1x1(attn)))
    gemm_glds<256, false, 3><<<dim3(8, 2, 16), 256, 0, stream>>>(wproj_bf, aT, zbuf, xn, out, nullptr, nullptr);
}

// Round 6
// 301.243 us; speedup vs baseline: 9.2840x; 1.1152x over previous
//
#include <hip/hip_runtime.h>
#include <math.h>

#define SDIM 1024
#define COUT 256

#define EPSV     1e-4f
#define SILU_INV 1.6778523489932886f   // 1/0.596
#define MPA      0.9191450300180579f   // 0.7/sqrt(0.58)
#define MPB      0.3939192985791677f   // 0.3/sqrt(0.58)
#define LOG2E    1.4426950408889634f

typedef short s16x8 __attribute__((ext_vector_type(8)));
typedef float f32x4 __attribute__((ext_vector_type(4)));
typedef unsigned short ushort_t;

#if __has_builtin(__builtin_amdgcn_exp2f)
#define EXP2F __builtin_amdgcn_exp2f
#else
#define EXP2F exp2f
#endif

__device__ inline ushort_t f2bs(float f) {
    unsigned u = __float_as_uint(f);
    u += 0x7fffu + ((u >> 16) & 1u);        // round-nearest-even
    return (ushort_t)(u >> 16);
}
__device__ inline float silu_mp(float v) { return v * SILU_INV / (1.f + __expf(-v)); }

union F8 { s16x8 v; uint4 q; };
__device__ inline s16x8 ld16(const ushort_t* p) {   // 16B-aligned (global or LDS)
    F8 r; r.q = *(const uint4*)p; return r.v;
}

// async global -> LDS, 16 B per lane. LDS dst = wave-uniform base + lane*16.
typedef const __attribute__((address_space(1))) unsigned int* gas_ptr;
typedef __attribute__((address_space(3))) unsigned int* las_ptr;
__device__ inline void gld16(const void* g, void* l) {
    __builtin_amdgcn_global_load_lds((gas_ptr)g, (las_ptr)l, 16, 0, 0);
}

__global__ void zfill(uint4* z) { z[threadIdx.x] = make_uint4(0u, 0u, 0u, 0u); }

// ---------------- weight normalization (fp32 out, for w_emb)
__global__ __launch_bounds__(256) void wnorm(const float* __restrict__ w,
                                             float* __restrict__ wn,
                                             int fanin,
                                             const float* __restrict__ gain_ptr)
{
    int o = blockIdx.x;
    const float* row = w + (size_t)o * fanin;
    float ss = 0.f;
    for (int i = threadIdx.x; i < fanin; i += 256) { float v = row[i]; ss += v * v; }
    for (int off = 32; off >= 1; off >>= 1) ss += __shfl_down(ss, off);
    __shared__ float red[4];
    int lane = threadIdx.x & 63, wv = threadIdx.x >> 6;
    if (lane == 0) red[wv] = ss;
    __syncthreads();
    float tot = red[0] + red[1] + red[2] + red[3];
    float gain = gain_ptr ? *gain_ptr : 1.0f;
    float scale = gain / (EPSV * sqrtf((float)fanin) + sqrtf(tot));
    for (int i = threadIdx.x; i < fanin; i += 256)
        wn[(size_t)o * fanin + i] = row[i] * scale;
}

// ---------------- weight normalization -> bf16.
// REORDER: K (ci,3,3)->(3x3,ci). QPERM: out row = t*256 + h*64 + c for o = h*192+c*3+t.
template<bool REORDER, bool QPERM>
__global__ __launch_bounds__(256) void wnorm_bf16(const float* __restrict__ w,
                                                  ushort_t* __restrict__ wn,
                                                  int fanin)
{
    int o = blockIdx.x;
    const float* row = w + (size_t)o * fanin;
    float ss = 0.f;
    for (int i = threadIdx.x; i < fanin; i += 256) { float v = row[i]; ss += v * v; }
    for (int off = 32; off >= 1; off >>= 1) ss += __shfl_down(ss, off);
    __shared__ float red[4];
    int lane = threadIdx.x & 63, wv = threadIdx.x >> 6;
    if (lane == 0) red[wv] = ss;
    __syncthreads();
    float tot = red[0] + red[1] + red[2] + red[3];
    float scale = 1.0f / (EPSV * sqrtf((float)fanin) + sqrtf(tot));
    int orow = o;
    if (QPERM) { int h = o / 192, rem = o % 192; orow = (rem % 3) * 256 + h * 64 + rem / 3; }
    for (int i = threadIdx.x; i < fanin; i += 256) {
        int kd = i;
        if (REORDER) { int ci = i / 9; int r9 = i - ci * 9; kd = r9 * 256 + ci; }
        wn[(size_t)orow * fanin + kd] = f2bs(row[i] * scale);
    }
}

// ---------------- c = emb @ wemb_n^T + 1
__global__ __launch_bounds__(256) void emb_mm(const float* __restrict__ emb,
                                              const float* __restrict__ wemb,
                                              float* __restrict__ cvec)
{
    int n = blockIdx.x;
    int co = threadIdx.x;
    const float* e  = emb  + (size_t)n * 768;
    const float* wr = wemb + (size_t)co * 768;
    float s = 0.f;
    for (int i = 0; i < 768; i++) s = fmaf(e[i], wr[i], s);
    cvec[n * COUT + co] = s + 1.0f;
}

// ---------------- transpose x [n][192][1024] fp32 -> xT [n][1024][192] bf16
__global__ __launch_bounds__(256) void prep_xT(const float* __restrict__ x,
                                               ushort_t* __restrict__ xT)
{
    const int n = blockIdx.z, ci0 = blockIdx.y * 64, s0 = blockIdx.x * 64;
    const int tid = threadIdx.x;
    __shared__ float T[64 * 65];
#pragma unroll
    for (int i = 0; i < 16; i++) {
        int ch = tid + i * 256; int row = ch >> 6, cc = ch & 63;
        T[row * 65 + cc] = x[((size_t)n * 192 + ci0 + row) * SDIM + s0 + cc];
    }
    __syncthreads();
#pragma unroll
    for (int i = 0; i < 2; i++) {
        int ch = tid + i * 256; int srow = ch >> 3, c8 = ch & 7;
        ushort_t tmp[8];
#pragma unroll
        for (int j = 0; j < 8; j++) tmp[j] = f2bs(T[(c8 * 8 + j) * 65 + srow]);
        *(uint4*)(xT + ((size_t)n * SDIM + s0 + srow) * 192 + ci0 + c8 * 8) = *(uint4*)tmp;
    }
}

// ---------------- fused: x1 = conv1x1(x, wskip); xn = pix_norm(x1); sxT = silu(xn)
__global__ __launch_bounds__(256, 2) void skip_fused(const ushort_t* __restrict__ Wp,
                                                     const ushort_t* __restrict__ xT,
                                                     float* __restrict__ xn,
                                                     ushort_t* __restrict__ sxT)
{
    const int n = blockIdx.z, s0 = blockIdx.x * 32;
    const int tid = threadIdx.x, w = tid >> 6, lane = tid & 63;
    const int tx = lane & 15, quad = lane >> 4;

    __shared__ ushort_t As[256 * 72];
    __shared__ ushort_t Bs[32 * 72];
    __shared__ float csum[4][32];

    f32x4 acc[4][2];
#pragma unroll
    for (int a = 0; a < 4; a++)
#pragma unroll
        for (int b = 0; b < 2; b++) acc[a][b] = (f32x4){0.f, 0.f, 0.f, 0.f};

    for (int k0 = 0; k0 < 192; k0 += 64) {
        __syncthreads();
#pragma unroll
        for (int i = 0; i < 8; i++) {
            int ch = tid + i * 256; int row = ch >> 3, c8 = ch & 7;
            *(uint4*)&As[row * 72 + c8 * 8] = *(const uint4*)(Wp + (size_t)row * 192 + k0 + c8 * 8);
        }
        {
            int row = tid >> 3, c8 = tid & 7;
            *(uint4*)&Bs[row * 72 + c8 * 8] =
                *(const uint4*)(xT + ((size_t)n * SDIM + s0 + row) * 192 + k0 + c8 * 8);
        }
        __syncthreads();
#pragma unroll
        for (int kc = 0; kc < 2; kc++) {
            s16x8 af[4], bf_[2];
#pragma unroll
            for (int mt = 0; mt < 4; mt++) af[mt] = ld16(&As[(w * 64 + mt * 16 + tx) * 72 + kc * 32 + quad * 8]);
#pragma unroll
            for (int nt = 0; nt < 2; nt++) bf_[nt] = ld16(&Bs[(nt * 16 + tx) * 72 + kc * 32 + quad * 8]);
#pragma unroll
            for (int mt = 0; mt < 4; mt++)
#pragma unroll
                for (int nt = 0; nt < 2; nt++)
                    acc[mt][nt] = __builtin_amdgcn_mfma_f32_16x16x32_bf16(af[mt], bf_[nt], acc[mt][nt], 0, 0, 0);
        }
    }

#pragma unroll
    for (int nt = 0; nt < 2; nt++) {
        float s2 = 0.f;
#pragma unroll
        for (int mt = 0; mt < 4; mt++)
#pragma unroll
            for (int r = 0; r < 4; r++) s2 = fmaf(acc[mt][nt][r], acc[mt][nt][r], s2);
        s2 += __shfl_xor(s2, 16); s2 += __shfl_xor(s2, 32);
        if (quad == 0) csum[w][nt * 16 + tx] = s2;
    }
    __syncthreads();
    float f[2];
#pragma unroll
    for (int nt = 0; nt < 2; nt++) {
        int col = nt * 16 + tx;
        float tot = csum[0][col] + csum[1][col] + csum[2][col] + csum[3][col];
        f[nt] = 1.f / (EPSV + sqrtf(tot) * 0.0625f);
    }
    ushort_t* Ls = As;                      // [32 s][264 co]
    float* xb = xn + (size_t)n * COUT * SDIM;
#pragma unroll
    for (int mt = 0; mt < 4; mt++)
#pragma unroll
        for (int r = 0; r < 4; r++) {
            int co = w * 64 + mt * 16 + quad * 4 + r;
#pragma unroll
            for (int nt = 0; nt < 2; nt++) {
                int sp = s0 + nt * 16 + tx;
                float v = acc[mt][nt][r] * f[nt];
                xb[(size_t)co * SDIM + sp] = v;
                Ls[(nt * 16 + tx) * 264 + co] = f2bs(silu_mp(v));
            }
        }
    __syncthreads();
#pragma unroll
    for (int i = 0; i < 4; i++) {
        int ch = tid + i * 256; int row = ch >> 5, c32 = ch & 31;
        *(uint4*)(sxT + ((size_t)n * SDIM + s0 + row) * 256 + c32 * 8) = *(uint4*)&Ls[row * 264 + c32 * 8];
    }
}

// ---------------- bf16 MFMA conv GEMM: glds staging, XOR-swizzled LDS, dbuf,
// 128co x 64s tile, waves 2x2 (wave 64co x 32s), BK=64.
// MODE 1: res0 -> *cvec, silu, OutT bf16 [n][1024][256] (transposed)
// MODE 2: res1 -> x2 = MPA*xn+MPB*acc; xn fp32 in place; OutT bf16 [n][1024][256]
// MODE 3: proj -> Outf = clip(MPA*RX+MPB*acc) fp32 [n][256][1024]
// MODE 4: qkv  -> fused 64-ch norm; q,k (co0<512) -> OutT = qkT[n][1024][512]
//                 (q scaled 0.125*log2e); v (co0>=512) -> Vout = vbuf[n][256][1024]
template<int KDIM, bool GATHER3, int MODE>
__global__ __launch_bounds__(256, 2) void gemm_glds(const ushort_t* __restrict__ Wp,
                                                    const ushort_t* __restrict__ Bsrc,
                                                    const ushort_t* __restrict__ zbuf,
                                                    float* RX, float* Outf,
                                                    ushort_t* OutT, ushort_t* Vout,
                                                    const float* __restrict__ cvec)
{
    const int n = blockIdx.z, co0 = blockIdx.y * 128, s0 = blockIdx.x * 64;
    const int tid = threadIdx.x, w = tid >> 6, lane = tid & 63;
    const int tx = lane & 15, quad = lane >> 4;
    const int wm = w >> 1, ws = w & 1;
    const int l8 = lane & 7, ld = lane >> 3;
    const int swz = (l8 ^ ld) * 8;

    __shared__ ushort_t SH[2 * 12288];      // stage: A[128][64] + B[64][64] = 24 KB

    const ushort_t* bn = Bsrc + (size_t)n * SDIM * 256;

    auto stageA = [&](int p, int k0) {
        ushort_t* Ab = SH + p * 12288;
#pragma unroll
        for (int j = 0; j < 4; j++) {
            int row0 = w * 32 + j * 8;
            gld16(Wp + (size_t)(co0 + row0 + ld) * KDIM + k0 + swz, Ab + row0 * 64);
        }
    };
    auto stageB = [&](int p, int k0) {
        ushort_t* Bb = SH + p * 12288 + 8192;
        int ci0 = k0, dy = 0, dx = 0;
        if (GATHER3) { int seg = k0 >> 8; ci0 = k0 & 255; int s3 = seg / 3; dy = s3 - 1; dx = seg - s3 * 3 - 1; }
#pragma unroll
        for (int j = 0; j < 2; j++) {
            int row0 = w * 16 + j * 8;
            const ushort_t* g;
            if (GATHER3) {
                int pix = s0 + row0 + ld;
                int h = (pix >> 5) + dy, wx = (pix & 31) + dx;
                bool valid = ((unsigned)h < 32u) && ((unsigned)wx < 32u);
                g = valid ? (bn + (size_t)((h << 5) + wx) * 256 + ci0 + swz) : zbuf;
            } else {
                g = bn + (size_t)(s0 + row0 + ld) * 256 + k0 + swz;
            }
            gld16(g, Bb + row0 * 64);
        }
    };

    f32x4 acc[4][2];
#pragma unroll
    for (int a = 0; a < 4; a++)
#pragma unroll
        for (int b = 0; b < 2; b++) acc[a][b] = (f32x4){0.f, 0.f, 0.f, 0.f};

    constexpr int NK = KDIM / 64;
    stageA(0, 0); stageB(0, 0);
    __syncthreads();

    for (int kt = 0; kt < NK; kt++) {
        int p = kt & 1;
        if (kt + 1 < NK) { stageA(p ^ 1, (kt + 1) * 64); stageB(p ^ 1, (kt + 1) * 64); }
        const ushort_t* Ab = SH + p * 12288;
        const ushort_t* Bb = Ab + 8192;
#pragma unroll
        for (int kc = 0; kc < 2; kc++) {
            int koff = ((kc * 4 + quad) ^ (tx & 7)) * 8;
            s16x8 af[4], bfv[2];
#pragma unroll
            for (int mt = 0; mt < 4; mt++) af[mt]  = ld16(&Ab[(wm * 64 + mt * 16 + tx) * 64 + koff]);
#pragma unroll
            for (int nt = 0; nt < 2; nt++) bfv[nt] = ld16(&Bb[(ws * 32 + nt * 16 + tx) * 64 + koff]);
#pragma unroll
            for (int mt = 0; mt < 4; mt++)
#pragma unroll
                for (int nt = 0; nt < 2; nt++)
                    acc[mt][nt] = __builtin_amdgcn_mfma_f32_16x16x32_bf16(af[mt], bfv[nt], acc[mt][nt], 0, 0, 0);
        }
        __syncthreads();
    }

    if (MODE == 4) {
        float scl[2];
#pragma unroll
        for (int nt = 0; nt < 2; nt++) {
            float s2 = 0.f;
#pragma unroll
            for (int mt = 0; mt < 4; mt++)
#pragma unroll
                for (int r = 0; r < 4; r++) s2 = fmaf(acc[mt][nt][r], acc[mt][nt][r], s2);
            s2 += __shfl_xor(s2, 16); s2 += __shfl_xor(s2, 32);
            float fac = (co0 < 256) ? (0.125f * LOG2E) : 1.0f;
            scl[nt] = fac / (EPSV + sqrtf(s2) * 0.125f);
        }
#pragma unroll
        for (int mt = 0; mt < 4; mt++)
#pragma unroll
            for (int nt = 0; nt < 2; nt++)
#pragma unroll
                for (int r = 0; r < 4; r++) acc[mt][nt][r] *= scl[nt];

        if (co0 < 512) {      // q,k: transposed -> qkT[n][s][512]
            ushort_t* Ls = SH;                  // [64 s][136 co]
#pragma unroll
            for (int mt = 0; mt < 4; mt++)
#pragma unroll
                for (int nt = 0; nt < 2; nt++)
#pragma unroll
                    for (int r = 0; r < 4; r++)
                        Ls[(ws * 32 + nt * 16 + tx) * 136 + wm * 64 + mt * 16 + quad * 4 + r] = f2bs(acc[mt][nt][r]);
            __syncthreads();
#pragma unroll
            for (int i = 0; i < 4; i++) {
                int ch = tid + i * 256; int row = ch >> 4, c16 = ch & 15;
                *(uint4*)(OutT + ((size_t)n * SDIM + s0 + row) * 512 + co0 + c16 * 8) = *(uint4*)&Ls[row * 136 + c16 * 8];
            }
        } else {              // v: [co][s] -> vbuf[n][256][1024]
            ushort_t* Ls = SH;                  // [128 co][72 s]
#pragma unroll
            for (int mt = 0; mt < 4; mt++)
#pragma unroll
                for (int nt = 0; nt < 2; nt++)
#pragma unroll
                    for (int r = 0; r < 4; r++)
                        Ls[(wm * 64 + mt * 16 + quad * 4 + r) * 72 + ws * 32 + nt * 16 + tx] = f2bs(acc[mt][nt][r]);
            __syncthreads();
#pragma unroll
            for (int i = 0; i < 4; i++) {
                int ch = tid + i * 256; int row = ch >> 3, c8 = ch & 7;
                *(uint4*)(Vout + ((size_t)n * 256 + (co0 - 512) + row) * SDIM + s0 + c8 * 8) = *(uint4*)&Ls[row * 72 + c8 * 8];
            }
        }
    }
    if (MODE == 1) {
        float cm[4][4];
#pragma unroll
        for (int mt = 0; mt < 4; mt++)
#pragma unroll
            for (int r = 0; r < 4; r++)
                cm[mt][r] = cvec[n * COUT + co0 + wm * 64 + mt * 16 + quad * 4 + r];
        ushort_t* Ls = SH;                  // [64 s][136 co]
#pragma unroll
        for (int mt = 0; mt < 4; mt++)
#pragma unroll
            for (int nt = 0; nt < 2; nt++)
#pragma unroll
                for (int r = 0; r < 4; r++) {
                    float v = silu_mp(acc[mt][nt][r] * cm[mt][r]);
                    Ls[(ws * 32 + nt * 16 + tx) * 136 + wm * 64 + mt * 16 + quad * 4 + r] = f2bs(v);
                }
        __syncthreads();
#pragma unroll
        for (int i = 0; i < 4; i++) {
            int ch = tid + i * 256; int row = ch >> 4, c16 = ch & 15;
            *(uint4*)(OutT + ((size_t)n * SDIM + s0 + row) * 256 + co0 + c16 * 8) = *(uint4*)&Ls[row * 136 + c16 * 8];
        }
    }
    if (MODE == 2) {
        ushort_t* Ls = SH;                  // [64 s][136 co]
#pragma unroll
        for (int mt = 0; mt < 4; mt++)
#pragma unroll
            for (int r = 0; r < 4; r++) {
                int col = wm * 64 + mt * 16 + quad * 4 + r;
                float* xp = RX + ((size_t)n * COUT + co0 + col) * SDIM + s0 + ws * 32;
#pragma unroll
                for (int nt = 0; nt < 2; nt++) {
                    float v = MPA * xp[nt * 16 + tx] + MPB * acc[mt][nt][r];
                    xp[nt * 16 + tx] = v;
                    Ls[(ws * 32 + nt * 16 + tx) * 136 + col] = f2bs(v);
                }
            }
        __syncthreads();
#pragma unroll
        for (int i = 0; i < 4; i++) {
            int ch = tid + i * 256; int row = ch >> 4, c16 = ch & 15;
            *(uint4*)(OutT + ((size_t)n * SDIM + s0 + row) * 256 + co0 + c16 * 8) = *(uint4*)&Ls[row * 136 + c16 * 8];
        }
    }
    if (MODE == 3) {
#pragma unroll
        for (int mt = 0; mt < 4; mt++)
#pragma unroll
            for (int r = 0; r < 4; r++) {
                int co = co0 + wm * 64 + mt * 16 + quad * 4 + r;
                const float* xp = RX + ((size_t)n * COUT + co) * SDIM + s0 + ws * 32;
                float* op = Outf + ((size_t)n * COUT + co) * SDIM + s0 + ws * 32;
#pragma unroll
                for (int nt = 0; nt < 2; nt++) {
                    float v = MPA * xp[nt * 16 + tx] + MPB * acc[mt][nt][r];
                    op[nt * 16 + tx] = fminf(fmaxf(v, -256.f), 256.f);
                }
            }
    }
}

// ---------------- MFMA flash attention: Q/K/V frags direct from global; P via LDS.
// Block = 128 q x (head, n); wave = 32 q. Grid 512 -> 2 blocks/CU.
__global__ __launch_bounds__(256, 2) void attn_mfma(const ushort_t* __restrict__ qkT,
                                                    const ushort_t* __restrict__ vbuf,
                                                    ushort_t* __restrict__ aT)
{
    const int n = blockIdx.z, head = blockIdx.y, q0 = blockIdx.x * 128;
    const int tid = threadIdx.x, w = tid >> 6, lane = tid & 63;
    const int tx = lane & 15, quad = lane >> 4;

    __shared__ ushort_t Pl[4][32 * 72];

    const size_t nb = (size_t)n * SDIM;
    const int qw = q0 + w * 32;

    s16x8 qf[2][2];
#pragma unroll
    for (int mt = 0; mt < 2; mt++)
#pragma unroll
        for (int kc = 0; kc < 2; kc++)
            qf[mt][kc] = ld16(qkT + (nb + qw + mt * 16 + tx) * 512 + head * 64 + kc * 32 + quad * 8);

    f32x4 acco[2][4];
    float lpart[2][4];
#pragma unroll
    for (int mt = 0; mt < 2; mt++)
#pragma unroll
        for (int nt = 0; nt < 4; nt++) acco[mt][nt] = (f32x4){0.f, 0.f, 0.f, 0.f};
#pragma unroll
    for (int mt = 0; mt < 2; mt++)
#pragma unroll
        for (int r = 0; r < 4; r++) lpart[mt][r] = 0.f;

    const ushort_t* kbase = qkT + nb * 512 + 256 + head * 64;
    const ushort_t* vbase = vbuf + ((size_t)n * 256 + head * 64) * SDIM;

    for (int kt = 0; kt < 16; kt++) {
        int k0 = kt * 64;
        s16x8 kf[4][2];
#pragma unroll
        for (int nt = 0; nt < 4; nt++)
#pragma unroll
            for (int kc = 0; kc < 2; kc++)
                kf[nt][kc] = ld16(kbase + (size_t)(k0 + nt * 16 + tx) * 512 + kc * 32 + quad * 8);

        f32x4 accs[2][4];
#pragma unroll
        for (int mt = 0; mt < 2; mt++)
#pragma unroll
            for (int nt = 0; nt < 4; nt++) accs[mt][nt] = (f32x4){0.f, 0.f, 0.f, 0.f};
#pragma unroll
        for (int kc = 0; kc < 2; kc++)
#pragma unroll
            for (int nt = 0; nt < 4; nt++)
#pragma unroll
                for (int mt = 0; mt < 2; mt++)
                    accs[mt][nt] = __builtin_amdgcn_mfma_f32_16x16x32_bf16(
                        qf[mt][kc], kf[nt][kc], accs[mt][nt], 0, 0, 0);

#pragma unroll
        for (int mt = 0; mt < 2; mt++)
#pragma unroll
            for (int nt = 0; nt < 4; nt++)
#pragma unroll
                for (int r = 0; r < 4; r++) {
                    float p = EXP2F(accs[mt][nt][r]);
                    lpart[mt][r] += p;
                    Pl[w][(mt * 16 + quad * 4 + r) * 72 + nt * 16 + tx] = f2bs(p);
                }
        asm volatile("s_waitcnt lgkmcnt(0)" ::: "memory");

        s16x8 vf[4][2], pf[2][2];
#pragma unroll
        for (int nt = 0; nt < 4; nt++)
#pragma unroll
            for (int kc = 0; kc < 2; kc++)
                vf[nt][kc] = ld16(vbase + (size_t)(nt * 16 + tx) * SDIM + k0 + kc * 32 + quad * 8);
#pragma unroll
        for (int mt = 0; mt < 2; mt++)
#pragma unroll
            for (int kc = 0; kc < 2; kc++)
                pf[mt][kc] = ld16(&Pl[w][(mt * 16 + tx) * 72 + kc * 32 + quad * 8]);
#pragma unroll
        for (int kc = 0; kc < 2; kc++)
#pragma unroll
            for (int nt = 0; nt < 4; nt++)
#pragma unroll
                for (int mt = 0; mt < 2; mt++)
                    acco[mt][nt] = __builtin_amdgcn_mfma_f32_16x16x32_bf16(
                        pf[mt][kc], vf[nt][kc], acco[mt][nt], 0, 0, 0);
    }

    float inv[2][4];
#pragma unroll
    for (int mt = 0; mt < 2; mt++)
#pragma unroll
        for (int r = 0; r < 4; r++) {
            float l = lpart[mt][r];
            l += __shfl_xor(l, 1); l += __shfl_xor(l, 2);
            l += __shfl_xor(l, 4); l += __shfl_xor(l, 8);
            inv[mt][r] = 1.0f / l;
        }

#pragma unroll
    for (int mt = 0; mt < 2; mt++)
#pragma unroll
        for (int nt = 0; nt < 4; nt++)
#pragma unroll
            for (int r = 0; r < 4; r++)
                Pl[w][(mt * 16 + quad * 4 + r) * 72 + nt * 16 + tx] = f2bs(acco[mt][nt][r] * inv[mt][r]);
    asm volatile("s_waitcnt lgkmcnt(0)" ::: "memory");
    ushort_t* dst = aT + (nb + qw) * 256 + head * 64;
#pragma unroll
    for (int i = 0; i < 4; i++) {
        int ch = lane + i * 64; int row = ch >> 3, c8 = ch & 7;
        *(uint4*)(dst + (size_t)row * 256 + c8 * 8) = *(uint4*)&Pl[w][row * 72 + c8 * 8];
    }
}

extern "C" void kernel_launch(void* const* d_in, const int* in_sizes, int n_in,
                              void* d_out, int out_size, void* d_ws, size_t ws_size,
                              hipStream_t stream)
{
    const float* x      = (const float*)d_in[0];
    const float* emb    = (const float*)d_in[1];
    const float* w_skip = (const float*)d_in[2];
    const float* w_res0 = (const float*)d_in[3];
    const float* w_res1 = (const float*)d_in[4];
    const float* w_emb  = (const float*)d_in[5];
    const float* e_gain = (const float*)d_in[6];
    const float* w_qkv  = (const float*)d_in[7];
    const float* w_proj = (const float*)d_in[8];
    float* out = (float*)d_out;

    char* p = (char*)d_ws;
    auto alloc = [&](size_t bytes) { void* r = (void*)p; p += (bytes + 255) & ~(size_t)255; return r; };
    ushort_t* wskip_bf = (ushort_t*)alloc(256 * 192 * 2);
    ushort_t* wres0_bf = (ushort_t*)alloc(256 * 2304 * 2);
    ushort_t* wres1_bf = (ushort_t*)alloc(256 * 2304 * 2);
    ushort_t* wqkv_bf  = (ushort_t*)alloc(768 * 256 * 2);
    ushort_t* wproj_bf = (ushort_t*)alloc(256 * 256 * 2);
    float*    wemb_n   = (float*)alloc(256 * 768 * 4);
    float*    cvec     = (float*)alloc(16 * 256 * 4);
    ushort_t* zbuf     = (ushort_t*)alloc(1024);
    ushort_t* xT   = (ushort_t*)alloc((size_t)16 * 1024 * 192 * 2);
    ushort_t* sxT  = (ushort_t*)alloc((size_t)16 * 1024 * 256 * 2);
    ushort_t* ysT  = (ushort_t*)alloc((size_t)16 * 1024 * 256 * 2);
    ushort_t* x2T  = (ushort_t*)alloc((size_t)16 * 1024 * 256 * 2);
    ushort_t* aT   = (ushort_t*)alloc((size_t)16 * 1024 * 256 * 2);
    float*    xn   = (float*)alloc((size_t)16 * 256 * 1024 * 4);
    ushort_t* qkT  = (ushort_t*)alloc((size_t)16 * 1024 * 512 * 2);
    ushort_t* vbuf = (ushort_t*)alloc((size_t)16 * 256 * 1024 * 2);

    zfill<<<1, 64, 0, stream>>>((uint4*)zbuf);
    wnorm_bf16<false, false><<<256, 256, 0, stream>>>(w_skip, wskip_bf, 192);
    wnorm_bf16<true,  false><<<256, 256, 0, stream>>>(w_res0, wres0_bf, 2304);
    wnorm_bf16<true,  false><<<256, 256, 0, stream>>>(w_res1, wres1_bf, 2304);
    wnorm_bf16<false, true ><<<768, 256, 0, stream>>>(w_qkv,  wqkv_bf,  256);
    wnorm_bf16<false, false><<<256, 256, 0, stream>>>(w_proj, wproj_bf, 256);
    wnorm<<<256, 256, 0, stream>>>(w_emb, wemb_n, 768, e_gain);

    emb_mm<<<16, 256, 0, stream>>>(emb, wemb_n, cvec);
    prep_xT<<<dim3(16, 3, 16), 256, 0, stream>>>(x, xT);

    skip_fused<<<dim3(32, 1, 16), 256, 0, stream>>>(wskip_bf, xT, xn, sxT);
    gemm_glds<2304, true, 1><<<dim3(16, 2, 16), 256, 0, stream>>>(wres0_bf, sxT, zbuf, nullptr, nullptr, ysT, nullptr, cvec);
    gemm_glds<2304, true, 2><<<dim3(16, 2, 16), 256, 0, stream>>>(wres1_bf, ysT, zbuf, xn, nullptr, x2T, nullptr, nullptr);
    // qkv + fused norm: q,k -> qkT (q pre-scaled by 0.125*log2e); v -> vbuf
    gemm_glds<256, false, 4><<<dim3(16, 6, 16), 256, 0, stream>>>(wqkv_bf, x2T, zbuf, nullptr, nullptr, qkT, vbuf, nullptr);
    // attention -> aT [n][s][256]
    attn_mfma<<<dim3(8, 4, 16), 256, 0, stream>>>(qkT, vbuf, aT);
    gemm_glds<256, false, 3><<<dim3(16, 2, 16), 256, 0, stream>>>(wproj_bf, aT, zbuf, xn, out, nullptr, nullptr, nullptr);
}

// Round 7
// 261.547 us; speedup vs baseline: 10.6931x; 1.1518x over previous
//
#include <hip/hip_runtime.h>
#include <math.h>

#define SDIM 1024
#define COUT 256

#define EPSV     1e-4f
#define SILU_INV 1.6778523489932886f   // 1/0.596
#define MPA      0.9191450300180579f   // 0.7/sqrt(0.58)
#define MPB      0.3939192985791677f   // 0.3/sqrt(0.58)
#define LOG2E    1.4426950408889634f

typedef short s16x8 __attribute__((ext_vector_type(8)));
typedef float f32x4 __attribute__((ext_vector_type(4)));
typedef unsigned short ushort_t;

#if __has_builtin(__builtin_amdgcn_exp2f)
#define EXP2F __builtin_amdgcn_exp2f
#else
#define EXP2F exp2f
#endif

__device__ inline ushort_t f2bs(float f) {
    unsigned u = __float_as_uint(f);
    u += 0x7fffu + ((u >> 16) & 1u);        // round-nearest-even
    return (ushort_t)(u >> 16);
}
__device__ inline float silu_mp(float v) { return v * SILU_INV / (1.f + __expf(-v)); }

union F8 { s16x8 v; uint4 q; };
__device__ inline s16x8 ld16(const ushort_t* p) {   // 16B-aligned (global or LDS)
    F8 r; r.q = *(const uint4*)p; return r.v;
}

// async global -> LDS, 16 B per lane. LDS dst = wave-uniform base + lane*16.
typedef const __attribute__((address_space(1))) unsigned int* gas_ptr;
typedef __attribute__((address_space(3))) unsigned int* las_ptr;
__device__ inline void gld16(const void* g, void* l) {
    __builtin_amdgcn_global_load_lds((gas_ptr)g, (las_ptr)l, 16, 0, 0);
}

// ---------------- fused prologue: all weight norms + x transpose + zbuf fill.
// blocks: [0,256) wskip | [256,512) res0 | [512,768) res1 | [768,1536) qkv |
//         [1536,1792) proj | [1792,2560) prep_xT | 2560 zfill
__global__ __launch_bounds__(256) void prep_all(
    const float* __restrict__ w_skip, const float* __restrict__ w_res0,
    const float* __restrict__ w_res1, const float* __restrict__ w_qkv,
    const float* __restrict__ w_proj, const float* __restrict__ x,
    ushort_t* wskip_bf, ushort_t* wres0_bf, ushort_t* wres1_bf,
    ushort_t* wqkv_bf, ushort_t* wproj_bf, ushort_t* xT, uint4* zbuf)
{
    __shared__ float T[64 * 65];
    const int b = blockIdx.x, tid = threadIdx.x;

    if (b >= 2560) {                     // zfill
        if (tid < 64) zbuf[tid] = make_uint4(0u, 0u, 0u, 0u);
        return;
    }
    if (b >= 1792) {                     // prep_xT: [n][192][1024] f32 -> [n][1024][192] bf16
        int b2 = b - 1792;
        int n = b2 / 48, rem = b2 % 48;
        int ci0 = (rem / 16) * 64, s0 = (rem & 15) * 64;
#pragma unroll
        for (int i = 0; i < 16; i++) {
            int ch = tid + i * 256; int row = ch >> 6, cc = ch & 63;
            T[row * 65 + cc] = x[((size_t)n * 192 + ci0 + row) * SDIM + s0 + cc];
        }
        __syncthreads();
#pragma unroll
        for (int i = 0; i < 2; i++) {
            int ch = tid + i * 256; int srow = ch >> 3, c8 = ch & 7;
            ushort_t tmp[8];
#pragma unroll
            for (int j = 0; j < 8; j++) tmp[j] = f2bs(T[(c8 * 8 + j) * 65 + srow]);
            *(uint4*)(xT + ((size_t)n * SDIM + s0 + srow) * 192 + ci0 + c8 * 8) = *(uint4*)tmp;
        }
        return;
    }
    // weight-norm branches
    const float* src; ushort_t* dst; int fanin, mode, o;
    if      (b < 256)  { src = w_skip; dst = wskip_bf; fanin = 192;  mode = 0; o = b; }
    else if (b < 512)  { src = w_res0; dst = wres0_bf; fanin = 2304; mode = 1; o = b - 256; }
    else if (b < 768)  { src = w_res1; dst = wres1_bf; fanin = 2304; mode = 1; o = b - 512; }
    else if (b < 1536) { src = w_qkv;  dst = wqkv_bf;  fanin = 256;  mode = 2; o = b - 768; }
    else               { src = w_proj; dst = wproj_bf; fanin = 256;  mode = 0; o = b - 1536; }

    const float* row = src + (size_t)o * fanin;
    float ss = 0.f;
    for (int i = tid; i < fanin; i += 256) { float v = row[i]; ss += v * v; }
    for (int off = 32; off >= 1; off >>= 1) ss += __shfl_down(ss, off);
    int lane = tid & 63, wv = tid >> 6;
    if (lane == 0) T[wv] = ss;
    __syncthreads();
    float tot = T[0] + T[1] + T[2] + T[3];
    float scale = 1.0f / (EPSV * sqrtf((float)fanin) + sqrtf(tot));
    int orow = o;
    if (mode == 2) { int h = o / 192, rem = o % 192; orow = (rem % 3) * 256 + h * 64 + rem / 3; }
    for (int i = tid; i < fanin; i += 256) {
        int kd = i;
        if (mode == 1) { int ci = i / 9; int r9 = i - ci * 9; kd = r9 * 256 + ci; }
        dst[(size_t)orow * fanin + kd] = f2bs(row[i] * scale);
    }
}

// ---------------- c = emb @ mp_weight(w_emb, gain)^T + 1  (norm fused per thread)
__global__ __launch_bounds__(256) void emb_mm(const float* __restrict__ emb,
                                              const float* __restrict__ w_emb,
                                              const float* __restrict__ gain_ptr,
                                              float* __restrict__ cvec)
{
    int n = blockIdx.x;
    int co = threadIdx.x;
    const float* e  = emb   + (size_t)n * 768;
    const float* wr = w_emb + (size_t)co * 768;
    float ss = 0.f, dot = 0.f;
    for (int i = 0; i < 768; i++) {
        float wv = wr[i];
        ss  = fmaf(wv, wv, ss);
        dot = fmaf(e[i], wv, dot);
    }
    float scale = gain_ptr[0] / (EPSV * sqrtf(768.0f) + sqrtf(ss));
    cvec[n * COUT + co] = dot * scale + 1.0f;
}

// ---------------- fused: x1 = conv1x1(x, wskip); xn = pix_norm(x1); sxT = silu(xn)
__global__ __launch_bounds__(256, 2) void skip_fused(const ushort_t* __restrict__ Wp,
                                                     const ushort_t* __restrict__ xT,
                                                     float* __restrict__ xn,
                                                     ushort_t* __restrict__ sxT)
{
    const int n = blockIdx.z, s0 = blockIdx.x * 32;
    const int tid = threadIdx.x, w = tid >> 6, lane = tid & 63;
    const int tx = lane & 15, quad = lane >> 4;

    __shared__ ushort_t As[256 * 72];
    __shared__ ushort_t Bs[32 * 72];
    __shared__ float csum[4][32];

    f32x4 acc[4][2];
#pragma unroll
    for (int a = 0; a < 4; a++)
#pragma unroll
        for (int b = 0; b < 2; b++) acc[a][b] = (f32x4){0.f, 0.f, 0.f, 0.f};

    for (int k0 = 0; k0 < 192; k0 += 64) {
        __syncthreads();
#pragma unroll
        for (int i = 0; i < 8; i++) {
            int ch = tid + i * 256; int row = ch >> 3, c8 = ch & 7;
            *(uint4*)&As[row * 72 + c8 * 8] = *(const uint4*)(Wp + (size_t)row * 192 + k0 + c8 * 8);
        }
        {
            int row = tid >> 3, c8 = tid & 7;
            *(uint4*)&Bs[row * 72 + c8 * 8] =
                *(const uint4*)(xT + ((size_t)n * SDIM + s0 + row) * 192 + k0 + c8 * 8);
        }
        __syncthreads();
#pragma unroll
        for (int kc = 0; kc < 2; kc++) {
            s16x8 af[4], bf_[2];
#pragma unroll
            for (int mt = 0; mt < 4; mt++) af[mt] = ld16(&As[(w * 64 + mt * 16 + tx) * 72 + kc * 32 + quad * 8]);
#pragma unroll
            for (int nt = 0; nt < 2; nt++) bf_[nt] = ld16(&Bs[(nt * 16 + tx) * 72 + kc * 32 + quad * 8]);
#pragma unroll
            for (int mt = 0; mt < 4; mt++)
#pragma unroll
                for (int nt = 0; nt < 2; nt++)
                    acc[mt][nt] = __builtin_amdgcn_mfma_f32_16x16x32_bf16(af[mt], bf_[nt], acc[mt][nt], 0, 0, 0);
        }
    }

#pragma unroll
    for (int nt = 0; nt < 2; nt++) {
        float s2 = 0.f;
#pragma unroll
        for (int mt = 0; mt < 4; mt++)
#pragma unroll
            for (int r = 0; r < 4; r++) s2 = fmaf(acc[mt][nt][r], acc[mt][nt][r], s2);
        s2 += __shfl_xor(s2, 16); s2 += __shfl_xor(s2, 32);
        if (quad == 0) csum[w][nt * 16 + tx] = s2;
    }
    __syncthreads();
    float f[2];
#pragma unroll
    for (int nt = 0; nt < 2; nt++) {
        int col = nt * 16 + tx;
        float tot = csum[0][col] + csum[1][col] + csum[2][col] + csum[3][col];
        f[nt] = 1.f / (EPSV + sqrtf(tot) * 0.0625f);
    }
    ushort_t* Ls = As;                      // [32 s][264 co]
    float* xb = xn + (size_t)n * COUT * SDIM;
#pragma unroll
    for (int mt = 0; mt < 4; mt++)
#pragma unroll
        for (int r = 0; r < 4; r++) {
            int co = w * 64 + mt * 16 + quad * 4 + r;
#pragma unroll
            for (int nt = 0; nt < 2; nt++) {
                int sp = s0 + nt * 16 + tx;
                float v = acc[mt][nt][r] * f[nt];
                xb[(size_t)co * SDIM + sp] = v;
                Ls[(nt * 16 + tx) * 264 + co] = f2bs(silu_mp(v));
            }
        }
    __syncthreads();
#pragma unroll
    for (int i = 0; i < 4; i++) {
        int ch = tid + i * 256; int row = ch >> 5, c32 = ch & 31;
        *(uint4*)(sxT + ((size_t)n * SDIM + s0 + row) * 256 + c32 * 8) = *(uint4*)&Ls[row * 264 + c32 * 8];
    }
}

// ---------------- bf16 MFMA conv GEMM: glds staging, XOR-swizzled LDS, dbuf,
// 128co x 64s tile, waves 2x2 (wave 64co x 32s), BK=64.
// MODE 1: res0 -> *cvec, silu, OutT bf16 [n][1024][256] (transposed)
// MODE 2: res1 -> x2 = MPA*xn+MPB*acc; xn fp32 in place; OutT bf16 [n][1024][256]
// MODE 3: proj -> Outf = clip(MPA*RX+MPB*acc) fp32 [n][256][1024]
// MODE 4: qkv  -> fused 64-ch norm; q,k (co0<512) -> OutT = qkT[n][1024][512]
//                 (q scaled 0.125*log2e); v (co0>=512) -> Vout = vbuf[n][256][1024]
template<int KDIM, bool GATHER3, int MODE>
__global__ __launch_bounds__(256, 2) void gemm_glds(const ushort_t* __restrict__ Wp,
                                                    const ushort_t* __restrict__ Bsrc,
                                                    const ushort_t* __restrict__ zbuf,
                                                    float* RX, float* Outf,
                                                    ushort_t* OutT, ushort_t* Vout,
                                                    const float* __restrict__ cvec)
{
    const int n = blockIdx.z, co0 = blockIdx.y * 128, s0 = blockIdx.x * 64;
    const int tid = threadIdx.x, w = tid >> 6, lane = tid & 63;
    const int tx = lane & 15, quad = lane >> 4;
    const int wm = w >> 1, ws = w & 1;
    const int l8 = lane & 7, ld = lane >> 3;
    const int swz = (l8 ^ ld) * 8;

    __shared__ ushort_t SH[2 * 12288];      // stage: A[128][64] + B[64][64] = 24 KB

    const ushort_t* bn = Bsrc + (size_t)n * SDIM * 256;

    auto stageA = [&](int p, int k0) {
        ushort_t* Ab = SH + p * 12288;
#pragma unroll
        for (int j = 0; j < 4; j++) {
            int row0 = w * 32 + j * 8;
            gld16(Wp + (size_t)(co0 + row0 + ld) * KDIM + k0 + swz, Ab + row0 * 64);
        }
    };
    auto stageB = [&](int p, int k0) {
        ushort_t* Bb = SH + p * 12288 + 8192;
        int ci0 = k0, dy = 0, dx = 0;
        if (GATHER3) { int seg = k0 >> 8; ci0 = k0 & 255; int s3 = seg / 3; dy = s3 - 1; dx = seg - s3 * 3 - 1; }
#pragma unroll
        for (int j = 0; j < 2; j++) {
            int row0 = w * 16 + j * 8;
            const ushort_t* g;
            if (GATHER3) {
                int pix = s0 + row0 + ld;
                int h = (pix >> 5) + dy, wx = (pix & 31) + dx;
                bool valid = ((unsigned)h < 32u) && ((unsigned)wx < 32u);
                g = valid ? (bn + (size_t)((h << 5) + wx) * 256 + ci0 + swz) : zbuf;
            } else {
                g = bn + (size_t)(s0 + row0 + ld) * 256 + k0 + swz;
            }
            gld16(g, Bb + row0 * 64);
        }
    };

    f32x4 acc[4][2];
#pragma unroll
    for (int a = 0; a < 4; a++)
#pragma unroll
        for (int b = 0; b < 2; b++) acc[a][b] = (f32x4){0.f, 0.f, 0.f, 0.f};

    constexpr int NK = KDIM / 64;
    stageA(0, 0); stageB(0, 0);
    __syncthreads();

    for (int kt = 0; kt < NK; kt++) {
        int p = kt & 1;
        if (kt + 1 < NK) { stageA(p ^ 1, (kt + 1) * 64); stageB(p ^ 1, (kt + 1) * 64); }
        const ushort_t* Ab = SH + p * 12288;
        const ushort_t* Bb = Ab + 8192;
#pragma unroll
        for (int kc = 0; kc < 2; kc++) {
            int koff = ((kc * 4 + quad) ^ (tx & 7)) * 8;
            s16x8 af[4], bfv[2];
#pragma unroll
            for (int mt = 0; mt < 4; mt++) af[mt]  = ld16(&Ab[(wm * 64 + mt * 16 + tx) * 64 + koff]);
#pragma unroll
            for (int nt = 0; nt < 2; nt++) bfv[nt] = ld16(&Bb[(ws * 32 + nt * 16 + tx) * 64 + koff]);
#pragma unroll
            for (int mt = 0; mt < 4; mt++)
#pragma unroll
                for (int nt = 0; nt < 2; nt++)
                    acc[mt][nt] = __builtin_amdgcn_mfma_f32_16x16x32_bf16(af[mt], bfv[nt], acc[mt][nt], 0, 0, 0);
        }
        __syncthreads();
    }

    if (MODE == 4) {
        float scl[2];
#pragma unroll
        for (int nt = 0; nt < 2; nt++) {
            float s2 = 0.f;
#pragma unroll
            for (int mt = 0; mt < 4; mt++)
#pragma unroll
                for (int r = 0; r < 4; r++) s2 = fmaf(acc[mt][nt][r], acc[mt][nt][r], s2);
            s2 += __shfl_xor(s2, 16); s2 += __shfl_xor(s2, 32);
            float fac = (co0 < 256) ? (0.125f * LOG2E) : 1.0f;
            scl[nt] = fac / (EPSV + sqrtf(s2) * 0.125f);
        }
#pragma unroll
        for (int mt = 0; mt < 4; mt++)
#pragma unroll
            for (int nt = 0; nt < 2; nt++)
#pragma unroll
                for (int r = 0; r < 4; r++) acc[mt][nt][r] *= scl[nt];

        if (co0 < 512) {      // q,k: transposed -> qkT[n][s][512]
            ushort_t* Ls = SH;                  // [64 s][136 co]
#pragma unroll
            for (int mt = 0; mt < 4; mt++)
#pragma unroll
                for (int nt = 0; nt < 2; nt++)
#pragma unroll
                    for (int r = 0; r < 4; r++)
                        Ls[(ws * 32 + nt * 16 + tx) * 136 + wm * 64 + mt * 16 + quad * 4 + r] = f2bs(acc[mt][nt][r]);
            __syncthreads();
#pragma unroll
            for (int i = 0; i < 4; i++) {
                int ch = tid + i * 256; int row = ch >> 4, c16 = ch & 15;
                *(uint4*)(OutT + ((size_t)n * SDIM + s0 + row) * 512 + co0 + c16 * 8) = *(uint4*)&Ls[row * 136 + c16 * 8];
            }
        } else {              // v: [co][s] -> vbuf[n][256][1024]
            ushort_t* Ls = SH;                  // [128 co][72 s]
#pragma unroll
            for (int mt = 0; mt < 4; mt++)
#pragma unroll
                for (int nt = 0; nt < 2; nt++)
#pragma unroll
                    for (int r = 0; r < 4; r++)
                        Ls[(wm * 64 + mt * 16 + quad * 4 + r) * 72 + ws * 32 + nt * 16 + tx] = f2bs(acc[mt][nt][r]);
            __syncthreads();
#pragma unroll
            for (int i = 0; i < 4; i++) {
                int ch = tid + i * 256; int row = ch >> 3, c8 = ch & 7;
                *(uint4*)(Vout + ((size_t)n * 256 + (co0 - 512) + row) * SDIM + s0 + c8 * 8) = *(uint4*)&Ls[row * 72 + c8 * 8];
            }
        }
    }
    if (MODE == 1) {
        float cm[4][4];
#pragma unroll
        for (int mt = 0; mt < 4; mt++)
#pragma unroll
            for (int r = 0; r < 4; r++)
                cm[mt][r] = cvec[n * COUT + co0 + wm * 64 + mt * 16 + quad * 4 + r];
        ushort_t* Ls = SH;                  // [64 s][136 co]
#pragma unroll
        for (int mt = 0; mt < 4; mt++)
#pragma unroll
            for (int nt = 0; nt < 2; nt++)
#pragma unroll
                for (int r = 0; r < 4; r++) {
                    float v = silu_mp(acc[mt][nt][r] * cm[mt][r]);
                    Ls[(ws * 32 + nt * 16 + tx) * 136 + wm * 64 + mt * 16 + quad * 4 + r] = f2bs(v);
                }
        __syncthreads();
#pragma unroll
        for (int i = 0; i < 4; i++) {
            int ch = tid + i * 256; int row = ch >> 4, c16 = ch & 15;
            *(uint4*)(OutT + ((size_t)n * SDIM + s0 + row) * 256 + co0 + c16 * 8) = *(uint4*)&Ls[row * 136 + c16 * 8];
        }
    }
    if (MODE == 2) {
        ushort_t* Ls = SH;                  // [64 s][136 co]
#pragma unroll
        for (int mt = 0; mt < 4; mt++)
#pragma unroll
            for (int r = 0; r < 4; r++) {
                int col = wm * 64 + mt * 16 + quad * 4 + r;
                float* xp = RX + ((size_t)n * COUT + co0 + col) * SDIM + s0 + ws * 32;
#pragma unroll
                for (int nt = 0; nt < 2; nt++) {
                    float v = MPA * xp[nt * 16 + tx] + MPB * acc[mt][nt][r];
                    xp[nt * 16 + tx] = v;
                    Ls[(ws * 32 + nt * 16 + tx) * 136 + col] = f2bs(v);
                }
            }
        __syncthreads();
#pragma unroll
        for (int i = 0; i < 4; i++) {
            int ch = tid + i * 256; int row = ch >> 4, c16 = ch & 15;
            *(uint4*)(OutT + ((size_t)n * SDIM + s0 + row) * 256 + co0 + c16 * 8) = *(uint4*)&Ls[row * 136 + c16 * 8];
        }
    }
    if (MODE == 3) {
#pragma unroll
        for (int mt = 0; mt < 4; mt++)
#pragma unroll
            for (int r = 0; r < 4; r++) {
                int co = co0 + wm * 64 + mt * 16 + quad * 4 + r;
                const float* xp = RX + ((size_t)n * COUT + co) * SDIM + s0 + ws * 32;
                float* op = Outf + ((size_t)n * COUT + co) * SDIM + s0 + ws * 32;
#pragma unroll
                for (int nt = 0; nt < 2; nt++) {
                    float v = MPA * xp[nt * 16 + tx] + MPB * acc[mt][nt][r];
                    op[nt * 16 + tx] = fminf(fmaxf(v, -256.f), 256.f);
                }
            }
    }
}

// ---------------- MFMA flash attention, glds-dbuf K/V staging (conv recipe).
// Block = 256 q (4 waves x 64 q), grid (4, head, n) = 256 blocks.
// K tile [64key][64c] from qkT; V tile [64c][64key] from vbuf; both glds, XOR-swizzled.
// Q in registers; P per-wave LDS (XOR-swizzled, 64-stride). LDS = exactly 64 KB.
__global__ __launch_bounds__(256, 1) void attn_mfma(const ushort_t* __restrict__ qkT,
                                                    const ushort_t* __restrict__ vbuf,
                                                    ushort_t* __restrict__ aT)
{
    const int n = blockIdx.z, head = blockIdx.y, q0 = blockIdx.x * 256;
    const int tid = threadIdx.x, w = tid >> 6, lane = tid & 63;
    const int tx = lane & 15, quad = lane >> 4;
    const int l8 = lane & 7, ld = lane >> 3;
    const int swz = (l8 ^ ld) * 8;

    __shared__ ushort_t Kst[2][4096];   // [stage][64 key][64 c]
    __shared__ ushort_t Vst[2][4096];   // [stage][64 c][64 key]
    __shared__ ushort_t Pl[4][4096];    // per-wave [64 q][64 k] swizzled / O stage

    const size_t nb = (size_t)n * SDIM;
    const int qw = q0 + w * 64;
    const ushort_t* kg = qkT + nb * 512 + 256 + head * 64;              // row=key, stride 512
    const ushort_t* vg = vbuf + ((size_t)n * 256 + head * 64) * SDIM;   // row=c, stride 1024

    auto stage = [&](int p, int k0) {
#pragma unroll
        for (int j = 0; j < 2; j++) {
            int row0 = w * 16 + j * 8;
            gld16(kg + (size_t)(k0 + row0 + ld) * 512 + swz, &Kst[p][row0 * 64]);
            gld16(vg + (size_t)(row0 + ld) * SDIM + k0 + swz, &Vst[p][row0 * 64]);
        }
    };

    // Q frags direct from global (q pre-scaled by 0.125*log2e)
    s16x8 qf[4][2];
#pragma unroll
    for (int mt = 0; mt < 4; mt++)
#pragma unroll
        for (int kc = 0; kc < 2; kc++)
            qf[mt][kc] = ld16(qkT + (nb + qw + mt * 16 + tx) * 512 + head * 64 + kc * 32 + quad * 8);

    f32x4 acco[4][4];
    float lpart[4][4];
#pragma unroll
    for (int mt = 0; mt < 4; mt++)
#pragma unroll
        for (int nt = 0; nt < 4; nt++) acco[mt][nt] = (f32x4){0.f, 0.f, 0.f, 0.f};
#pragma unroll
    for (int mt = 0; mt < 4; mt++)
#pragma unroll
        for (int r = 0; r < 4; r++) lpart[mt][r] = 0.f;

    stage(0, 0);
    __syncthreads();

    for (int kt = 0; kt < 16; kt++) {
        int p = kt & 1;
        if (kt < 15) stage(p ^ 1, (kt + 1) * 64);

        // S = Q K^T (64q x 64key per wave)
        f32x4 accs[4][4];
#pragma unroll
        for (int mt = 0; mt < 4; mt++)
#pragma unroll
            for (int nt = 0; nt < 4; nt++) accs[mt][nt] = (f32x4){0.f, 0.f, 0.f, 0.f};
#pragma unroll
        for (int kc = 0; kc < 2; kc++) {
            int koff = ((kc * 4 + quad) ^ (tx & 7)) * 8;
#pragma unroll
            for (int nt = 0; nt < 4; nt++) {
                s16x8 kf = ld16(&Kst[p][(nt * 16 + tx) * 64 + koff]);
#pragma unroll
                for (int mt = 0; mt < 4; mt++)
                    accs[mt][nt] = __builtin_amdgcn_mfma_f32_16x16x32_bf16(
                        qf[mt][kc], kf, accs[mt][nt], 0, 0, 0);
            }
        }

        // P = 2^S; row sums; P -> per-wave LDS (chunk-XOR swizzle)
#pragma unroll
        for (int mt = 0; mt < 4; mt++)
#pragma unroll
            for (int r = 0; r < 4; r++) {
                int row = mt * 16 + quad * 4 + r;
                int rx = row & 7;
#pragma unroll
                for (int nt = 0; nt < 4; nt++) {
                    float pv = EXP2F(accs[mt][nt][r]);
                    lpart[mt][r] += pv;
                    int slot = (nt * 2 + (tx >> 3)) ^ rx;
                    Pl[w][row * 64 + slot * 8 + (tx & 7)] = f2bs(pv);
                }
            }
        asm volatile("s_waitcnt lgkmcnt(0)" ::: "memory");

        // O += P V
#pragma unroll
        for (int kc = 0; kc < 2; kc++) {
            int koff = ((kc * 4 + quad) ^ (tx & 7)) * 8;
            s16x8 pf[4];
#pragma unroll
            for (int mt = 0; mt < 4; mt++)
                pf[mt] = ld16(&Pl[w][(mt * 16 + tx) * 64 + koff]);
#pragma unroll
            for (int nt = 0; nt < 4; nt++) {
                s16x8 vf = ld16(&Vst[p][(nt * 16 + tx) * 64 + koff]);
#pragma unroll
                for (int mt = 0; mt < 4; mt++)
                    acco[mt][nt] = __builtin_amdgcn_mfma_f32_16x16x32_bf16(
                        pf[mt], vf, acco[mt][nt], 0, 0, 0);
            }
        }
        __syncthreads();     // all waves done with stage p; prefetch DMA drained here
    }

    float inv[4][4];
#pragma unroll
    for (int mt = 0; mt < 4; mt++)
#pragma unroll
        for (int r = 0; r < 4; r++) {
            float l = lpart[mt][r];
            l += __shfl_xor(l, 1); l += __shfl_xor(l, 2);
            l += __shfl_xor(l, 4); l += __shfl_xor(l, 8);
            inv[mt][r] = 1.0f / l;
        }

    // O stage (swizzled) -> vectorized global write aT[n][s][256]
#pragma unroll
    for (int mt = 0; mt < 4; mt++)
#pragma unroll
        for (int r = 0; r < 4; r++) {
            int row = mt * 16 + quad * 4 + r;
            int rx = row & 7;
#pragma unroll
            for (int nt = 0; nt < 4; nt++) {
                int slot = (nt * 2 + (tx >> 3)) ^ rx;
                Pl[w][row * 64 + slot * 8 + (tx & 7)] = f2bs(acco[mt][nt][r] * inv[mt][r]);
            }
        }
    asm volatile("s_waitcnt lgkmcnt(0)" ::: "memory");
    ushort_t* dst = aT + (nb + qw) * 256 + head * 64;
#pragma unroll
    for (int i = 0; i < 8; i++) {
        int ch = lane + i * 64; int row = ch >> 3, c8 = ch & 7;
        *(uint4*)(dst + (size_t)row * 256 + c8 * 8) = *(uint4*)&Pl[w][row * 64 + (c8 ^ (row & 7)) * 8];
    }
}

extern "C" void kernel_launch(void* const* d_in, const int* in_sizes, int n_in,
                              void* d_out, int out_size, void* d_ws, size_t ws_size,
                              hipStream_t stream)
{
    const float* x      = (const float*)d_in[0];
    const float* emb    = (const float*)d_in[1];
    const float* w_skip = (const float*)d_in[2];
    const float* w_res0 = (const float*)d_in[3];
    const float* w_res1 = (const float*)d_in[4];
    const float* w_emb  = (const float*)d_in[5];
    const float* e_gain = (const float*)d_in[6];
    const float* w_qkv  = (const float*)d_in[7];
    const float* w_proj = (const float*)d_in[8];
    float* out = (float*)d_out;

    char* p = (char*)d_ws;
    auto alloc = [&](size_t bytes) { void* r = (void*)p; p += (bytes + 255) & ~(size_t)255; return r; };
    ushort_t* wskip_bf = (ushort_t*)alloc(256 * 192 * 2);
    ushort_t* wres0_bf = (ushort_t*)alloc(256 * 2304 * 2);
    ushort_t* wres1_bf = (ushort_t*)alloc(256 * 2304 * 2);
    ushort_t* wqkv_bf  = (ushort_t*)alloc(768 * 256 * 2);
    ushort_t* wproj_bf = (ushort_t*)alloc(256 * 256 * 2);
    float*    cvec     = (float*)alloc(16 * 256 * 4);
    ushort_t* zbuf     = (ushort_t*)alloc(1024);
    ushort_t* xT   = (ushort_t*)alloc((size_t)16 * 1024 * 192 * 2);
    ushort_t* sxT  = (ushort_t*)alloc((size_t)16 * 1024 * 256 * 2);
    ushort_t* ysT  = (ushort_t*)alloc((size_t)16 * 1024 * 256 * 2);
    ushort_t* x2T  = (ushort_t*)alloc((size_t)16 * 1024 * 256 * 2);
    ushort_t* aT   = (ushort_t*)alloc((size_t)16 * 1024 * 256 * 2);
    float*    xn   = (float*)alloc((size_t)16 * 256 * 1024 * 4);
    ushort_t* qkT  = (ushort_t*)alloc((size_t)16 * 1024 * 512 * 2);
    ushort_t* vbuf = (ushort_t*)alloc((size_t)16 * 256 * 1024 * 2);

    // fused prologue: all weight norms + x transpose + zbuf
    prep_all<<<2561, 256, 0, stream>>>(w_skip, w_res0, w_res1, w_qkv, w_proj, x,
                                       wskip_bf, wres0_bf, wres1_bf, wqkv_bf, wproj_bf,
                                       xT, (uint4*)zbuf);
    emb_mm<<<16, 256, 0, stream>>>(emb, w_emb, e_gain, cvec);

    skip_fused<<<dim3(32, 1, 16), 256, 0, stream>>>(wskip_bf, xT, xn, sxT);
    gemm_glds<2304, true, 1><<<dim3(16, 2, 16), 256, 0, stream>>>(wres0_bf, sxT, zbuf, nullptr, nullptr, ysT, nullptr, cvec);
    gemm_glds<2304, true, 2><<<dim3(16, 2, 16), 256, 0, stream>>>(wres1_bf, ysT, zbuf, xn, nullptr, x2T, nullptr, nullptr);
    gemm_glds<256, false, 4><<<dim3(16, 6, 16), 256, 0, stream>>>(wqkv_bf, x2T, zbuf, nullptr, nullptr, qkT, vbuf, nullptr);
    attn_mfma<<<dim3(4, 4, 16), 256, 0, stream>>>(qkT, vbuf, aT);
    gemm_glds<256, false, 3><<<dim3(16, 2, 16), 256, 0, stream>>>(wproj_bf, aT, zbuf, xn, out, nullptr, nullptr, nullptr);
}

// Round 8
// 255.928 us; speedup vs baseline: 10.9279x; 1.0220x over previous
//
#include <hip/hip_runtime.h>
#include <math.h>

#define SDIM 1024
#define COUT 256

#define EPSV     1e-4f
#define SILU_INV 1.6778523489932886f   // 1/0.596
#define MPA      0.9191450300180579f   // 0.7/sqrt(0.58)
#define MPB      0.3939192985791677f   // 0.3/sqrt(0.58)
#define LOG2E    1.4426950408889634f

typedef short s16x8 __attribute__((ext_vector_type(8)));
typedef float f32x4 __attribute__((ext_vector_type(4)));
typedef unsigned short ushort_t;

#if __has_builtin(__builtin_amdgcn_exp2f)
#define EXP2F __builtin_amdgcn_exp2f
#else
#define EXP2F exp2f
#endif

__device__ inline ushort_t f2bs(float f) {
    unsigned u = __float_as_uint(f);
    u += 0x7fffu + ((u >> 16) & 1u);        // round-nearest-even
    return (ushort_t)(u >> 16);
}
__device__ inline float silu_mp(float v) { return v * SILU_INV / (1.f + __expf(-v)); }

union F8 { s16x8 v; uint4 q; };
__device__ inline s16x8 ld16(const ushort_t* p) {   // 16B-aligned (global or LDS)
    F8 r; r.q = *(const uint4*)p; return r.v;
}

// async global -> LDS, 16 B per lane. LDS dst = wave-uniform base + lane*16.
typedef const __attribute__((address_space(1))) unsigned int* gas_ptr;
typedef __attribute__((address_space(3))) unsigned int* las_ptr;
__device__ inline void gld16(const void* g, void* l) {
    __builtin_amdgcn_global_load_lds((gas_ptr)g, (las_ptr)l, 16, 0, 0);
}

// ---------------- fused prologue: all weight norms + x transpose + zbuf fill.
// blocks: [0,256) wskip | [256,512) res0 | [512,768) res1 | [768,1536) qkv |
//         [1536,1792) proj | [1792,2560) prep_xT | 2560 zfill
__global__ __launch_bounds__(256) void prep_all(
    const float* __restrict__ w_skip, const float* __restrict__ w_res0,
    const float* __restrict__ w_res1, const float* __restrict__ w_qkv,
    const float* __restrict__ w_proj, const float* __restrict__ x,
    ushort_t* wskip_bf, ushort_t* wres0_bf, ushort_t* wres1_bf,
    ushort_t* wqkv_bf, ushort_t* wproj_bf, ushort_t* xT, uint4* zbuf)
{
    __shared__ float T[64 * 65];
    const int b = blockIdx.x, tid = threadIdx.x;

    if (b >= 2560) {                     // zfill
        if (tid < 64) zbuf[tid] = make_uint4(0u, 0u, 0u, 0u);
        return;
    }
    if (b >= 1792) {                     // prep_xT: [n][192][1024] f32 -> [n][1024][192] bf16
        int b2 = b - 1792;
        int n = b2 / 48, rem = b2 % 48;
        int ci0 = (rem / 16) * 64, s0 = (rem & 15) * 64;
#pragma unroll
        for (int i = 0; i < 16; i++) {
            int ch = tid + i * 256; int row = ch >> 6, cc = ch & 63;
            T[row * 65 + cc] = x[((size_t)n * 192 + ci0 + row) * SDIM + s0 + cc];
        }
        __syncthreads();
#pragma unroll
        for (int i = 0; i < 2; i++) {
            int ch = tid + i * 256; int srow = ch >> 3, c8 = ch & 7;
            ushort_t tmp[8];
#pragma unroll
            for (int j = 0; j < 8; j++) tmp[j] = f2bs(T[(c8 * 8 + j) * 65 + srow]);
            *(uint4*)(xT + ((size_t)n * SDIM + s0 + srow) * 192 + ci0 + c8 * 8) = *(uint4*)tmp;
        }
        return;
    }
    // weight-norm branches
    const float* src; ushort_t* dst; int fanin, mode, o;
    if      (b < 256)  { src = w_skip; dst = wskip_bf; fanin = 192;  mode = 0; o = b; }
    else if (b < 512)  { src = w_res0; dst = wres0_bf; fanin = 2304; mode = 1; o = b - 256; }
    else if (b < 768)  { src = w_res1; dst = wres1_bf; fanin = 2304; mode = 1; o = b - 512; }
    else if (b < 1536) { src = w_qkv;  dst = wqkv_bf;  fanin = 256;  mode = 2; o = b - 768; }
    else               { src = w_proj; dst = wproj_bf; fanin = 256;  mode = 0; o = b - 1536; }

    const float* row = src + (size_t)o * fanin;
    float ss = 0.f;
    for (int i = tid; i < fanin; i += 256) { float v = row[i]; ss += v * v; }
    for (int off = 32; off >= 1; off >>= 1) ss += __shfl_down(ss, off);
    int lane = tid & 63, wv = tid >> 6;
    if (lane == 0) T[wv] = ss;
    __syncthreads();
    float tot = T[0] + T[1] + T[2] + T[3];
    float scale = 1.0f / (EPSV * sqrtf((float)fanin) + sqrtf(tot));
    int orow = o;
    if (mode == 2) { int h = o / 192, rem = o % 192; orow = (rem % 3) * 256 + h * 64 + rem / 3; }
    for (int i = tid; i < fanin; i += 256) {
        int kd = i;
        if (mode == 1) { int ci = i / 9; int r9 = i - ci * 9; kd = r9 * 256 + ci; }
        dst[(size_t)orow * fanin + kd] = f2bs(row[i] * scale);
    }
}

// ---------------- c = emb @ mp_weight(w_emb, gain)^T + 1  (norm fused per thread)
__global__ __launch_bounds__(256) void emb_mm(const float* __restrict__ emb,
                                              const float* __restrict__ w_emb,
                                              const float* __restrict__ gain_ptr,
                                              float* __restrict__ cvec)
{
    int n = blockIdx.x;
    int co = threadIdx.x;
    const float* e  = emb   + (size_t)n * 768;
    const float* wr = w_emb + (size_t)co * 768;
    float ss = 0.f, dot = 0.f;
    for (int i = 0; i < 768; i++) {
        float wv = wr[i];
        ss  = fmaf(wv, wv, ss);
        dot = fmaf(e[i], wv, dot);
    }
    float scale = gain_ptr[0] / (EPSV * sqrtf(768.0f) + sqrtf(ss));
    cvec[n * COUT + co] = dot * scale + 1.0f;
}

// ---------------- fused: x1 = conv1x1(x, wskip); xn = pix_norm(x1); sxT = silu(xn)
__global__ __launch_bounds__(256, 2) void skip_fused(const ushort_t* __restrict__ Wp,
                                                     const ushort_t* __restrict__ xT,
                                                     float* __restrict__ xn,
                                                     ushort_t* __restrict__ sxT)
{
    const int n = blockIdx.z, s0 = blockIdx.x * 32;
    const int tid = threadIdx.x, w = tid >> 6, lane = tid & 63;
    const int tx = lane & 15, quad = lane >> 4;

    __shared__ ushort_t As[256 * 72];
    __shared__ ushort_t Bs[32 * 72];
    __shared__ float csum[4][32];

    f32x4 acc[4][2];
#pragma unroll
    for (int a = 0; a < 4; a++)
#pragma unroll
        for (int b = 0; b < 2; b++) acc[a][b] = (f32x4){0.f, 0.f, 0.f, 0.f};

    for (int k0 = 0; k0 < 192; k0 += 64) {
        __syncthreads();
#pragma unroll
        for (int i = 0; i < 8; i++) {
            int ch = tid + i * 256; int row = ch >> 3, c8 = ch & 7;
            *(uint4*)&As[row * 72 + c8 * 8] = *(const uint4*)(Wp + (size_t)row * 192 + k0 + c8 * 8);
        }
        {
            int row = tid >> 3, c8 = tid & 7;
            *(uint4*)&Bs[row * 72 + c8 * 8] =
                *(const uint4*)(xT + ((size_t)n * SDIM + s0 + row) * 192 + k0 + c8 * 8);
        }
        __syncthreads();
#pragma unroll
        for (int kc = 0; kc < 2; kc++) {
            s16x8 af[4], bf_[2];
#pragma unroll
            for (int mt = 0; mt < 4; mt++) af[mt] = ld16(&As[(w * 64 + mt * 16 + tx) * 72 + kc * 32 + quad * 8]);
#pragma unroll
            for (int nt = 0; nt < 2; nt++) bf_[nt] = ld16(&Bs[(nt * 16 + tx) * 72 + kc * 32 + quad * 8]);
#pragma unroll
            for (int mt = 0; mt < 4; mt++)
#pragma unroll
                for (int nt = 0; nt < 2; nt++)
                    acc[mt][nt] = __builtin_amdgcn_mfma_f32_16x16x32_bf16(af[mt], bf_[nt], acc[mt][nt], 0, 0, 0);
        }
    }

#pragma unroll
    for (int nt = 0; nt < 2; nt++) {
        float s2 = 0.f;
#pragma unroll
        for (int mt = 0; mt < 4; mt++)
#pragma unroll
            for (int r = 0; r < 4; r++) s2 = fmaf(acc[mt][nt][r], acc[mt][nt][r], s2);
        s2 += __shfl_xor(s2, 16); s2 += __shfl_xor(s2, 32);
        if (quad == 0) csum[w][nt * 16 + tx] = s2;
    }
    __syncthreads();
    float f[2];
#pragma unroll
    for (int nt = 0; nt < 2; nt++) {
        int col = nt * 16 + tx;
        float tot = csum[0][col] + csum[1][col] + csum[2][col] + csum[3][col];
        f[nt] = 1.f / (EPSV + sqrtf(tot) * 0.0625f);
    }
    ushort_t* Ls = As;                      // [32 s][264 co]
    float* xb = xn + (size_t)n * COUT * SDIM;
#pragma unroll
    for (int mt = 0; mt < 4; mt++)
#pragma unroll
        for (int r = 0; r < 4; r++) {
            int co = w * 64 + mt * 16 + quad * 4 + r;
#pragma unroll
            for (int nt = 0; nt < 2; nt++) {
                int sp = s0 + nt * 16 + tx;
                float v = acc[mt][nt][r] * f[nt];
                xb[(size_t)co * SDIM + sp] = v;
                Ls[(nt * 16 + tx) * 264 + co] = f2bs(silu_mp(v));
            }
        }
    __syncthreads();
#pragma unroll
    for (int i = 0; i < 4; i++) {
        int ch = tid + i * 256; int row = ch >> 5, c32 = ch & 31;
        *(uint4*)(sxT + ((size_t)n * SDIM + s0 + row) * 256 + c32 * 8) = *(uint4*)&Ls[row * 264 + c32 * 8];
    }
}

// ---------------- bf16 MFMA conv GEMM: glds staging, XOR-swizzled LDS, dbuf,
// 128co x 64s tile, waves 2x2 (wave 64co x 32s), BK=64.
// MODE 1: res0 -> *cvec, silu, OutT bf16 [n][1024][256] (transposed)
// MODE 2: res1 -> x2 = MPA*xn+MPB*acc; xn fp32 in place; OutT bf16 [n][1024][256]
// MODE 3: proj -> Outf = clip(MPA*RX+MPB*acc) fp32 [n][256][1024]
// MODE 4: qkv  -> fused 64-ch norm; q,k (co0<512) -> OutT = qkT[n][1024][512]
//                 (q scaled 0.125*log2e); v (co0>=512) -> Vout = vbuf[n][256][1024]
template<int KDIM, bool GATHER3, int MODE>
__global__ __launch_bounds__(256, 2) void gemm_glds(const ushort_t* __restrict__ Wp,
                                                    const ushort_t* __restrict__ Bsrc,
                                                    const ushort_t* __restrict__ zbuf,
                                                    float* RX, float* Outf,
                                                    ushort_t* OutT, ushort_t* Vout,
                                                    const float* __restrict__ cvec)
{
    const int n = blockIdx.z, co0 = blockIdx.y * 128, s0 = blockIdx.x * 64;
    const int tid = threadIdx.x, w = tid >> 6, lane = tid & 63;
    const int tx = lane & 15, quad = lane >> 4;
    const int wm = w >> 1, ws = w & 1;
    const int l8 = lane & 7, ld = lane >> 3;
    const int swz = (l8 ^ ld) * 8;

    __shared__ ushort_t SH[2 * 12288];      // stage: A[128][64] + B[64][64] = 24 KB

    const ushort_t* bn = Bsrc + (size_t)n * SDIM * 256;

    auto stageA = [&](int p, int k0) {
        ushort_t* Ab = SH + p * 12288;
#pragma unroll
        for (int j = 0; j < 4; j++) {
            int row0 = w * 32 + j * 8;
            gld16(Wp + (size_t)(co0 + row0 + ld) * KDIM + k0 + swz, Ab + row0 * 64);
        }
    };
    auto stageB = [&](int p, int k0) {
        ushort_t* Bb = SH + p * 12288 + 8192;
        int ci0 = k0, dy = 0, dx = 0;
        if (GATHER3) { int seg = k0 >> 8; ci0 = k0 & 255; int s3 = seg / 3; dy = s3 - 1; dx = seg - s3 * 3 - 1; }
#pragma unroll
        for (int j = 0; j < 2; j++) {
            int row0 = w * 16 + j * 8;
            const ushort_t* g;
            if (GATHER3) {
                int pix = s0 + row0 + ld;
                int h = (pix >> 5) + dy, wx = (pix & 31) + dx;
                bool valid = ((unsigned)h < 32u) && ((unsigned)wx < 32u);
                g = valid ? (bn + (size_t)((h << 5) + wx) * 256 + ci0 + swz) : zbuf;
            } else {
                g = bn + (size_t)(s0 + row0 + ld) * 256 + k0 + swz;
            }
            gld16(g, Bb + row0 * 64);
        }
    };

    f32x4 acc[4][2];
#pragma unroll
    for (int a = 0; a < 4; a++)
#pragma unroll
        for (int b = 0; b < 2; b++) acc[a][b] = (f32x4){0.f, 0.f, 0.f, 0.f};

    constexpr int NK = KDIM / 64;
    stageA(0, 0); stageB(0, 0);
    __syncthreads();

    for (int kt = 0; kt < NK; kt++) {
        int p = kt & 1;
        if (kt + 1 < NK) { stageA(p ^ 1, (kt + 1) * 64); stageB(p ^ 1, (kt + 1) * 64); }
        const ushort_t* Ab = SH + p * 12288;
        const ushort_t* Bb = Ab + 8192;
#pragma unroll
        for (int kc = 0; kc < 2; kc++) {
            int koff = ((kc * 4 + quad) ^ (tx & 7)) * 8;
            s16x8 af[4], bfv[2];
#pragma unroll
            for (int mt = 0; mt < 4; mt++) af[mt]  = ld16(&Ab[(wm * 64 + mt * 16 + tx) * 64 + koff]);
#pragma unroll
            for (int nt = 0; nt < 2; nt++) bfv[nt] = ld16(&Bb[(ws * 32 + nt * 16 + tx) * 64 + koff]);
#pragma unroll
            for (int mt = 0; mt < 4; mt++)
#pragma unroll
                for (int nt = 0; nt < 2; nt++)
                    acc[mt][nt] = __builtin_amdgcn_mfma_f32_16x16x32_bf16(af[mt], bfv[nt], acc[mt][nt], 0, 0, 0);
        }
        __syncthreads();
    }

    if (MODE == 4) {
        float scl[2];
#pragma unroll
        for (int nt = 0; nt < 2; nt++) {
            float s2 = 0.f;
#pragma unroll
            for (int mt = 0; mt < 4; mt++)
#pragma unroll
                for (int r = 0; r < 4; r++) s2 = fmaf(acc[mt][nt][r], acc[mt][nt][r], s2);
            s2 += __shfl_xor(s2, 16); s2 += __shfl_xor(s2, 32);
            float fac = (co0 < 256) ? (0.125f * LOG2E) : 1.0f;
            scl[nt] = fac / (EPSV + sqrtf(s2) * 0.125f);
        }
#pragma unroll
        for (int mt = 0; mt < 4; mt++)
#pragma unroll
            for (int nt = 0; nt < 2; nt++)
#pragma unroll
                for (int r = 0; r < 4; r++) acc[mt][nt][r] *= scl[nt];

        if (co0 < 512) {      // q,k: transposed -> qkT[n][s][512]
            ushort_t* Ls = SH;                  // [64 s][136 co]
#pragma unroll
            for (int mt = 0; mt < 4; mt++)
#pragma unroll
                for (int nt = 0; nt < 2; nt++)
#pragma unroll
                    for (int r = 0; r < 4; r++)
                        Ls[(ws * 32 + nt * 16 + tx) * 136 + wm * 64 + mt * 16 + quad * 4 + r] = f2bs(acc[mt][nt][r]);
            __syncthreads();
#pragma unroll
            for (int i = 0; i < 4; i++) {
                int ch = tid + i * 256; int row = ch >> 4, c16 = ch & 15;
                *(uint4*)(OutT + ((size_t)n * SDIM + s0 + row) * 512 + co0 + c16 * 8) = *(uint4*)&Ls[row * 136 + c16 * 8];
            }
        } else {              // v: [co][s] -> vbuf[n][256][1024]
            ushort_t* Ls = SH;                  // [128 co][72 s]
#pragma unroll
            for (int mt = 0; mt < 4; mt++)
#pragma unroll
                for (int nt = 0; nt < 2; nt++)
#pragma unroll
                    for (int r = 0; r < 4; r++)
                        Ls[(wm * 64 + mt * 16 + quad * 4 + r) * 72 + ws * 32 + nt * 16 + tx] = f2bs(acc[mt][nt][r]);
            __syncthreads();
#pragma unroll
            for (int i = 0; i < 4; i++) {
                int ch = tid + i * 256; int row = ch >> 3, c8 = ch & 7;
                *(uint4*)(Vout + ((size_t)n * 256 + (co0 - 512) + row) * SDIM + s0 + c8 * 8) = *(uint4*)&Ls[row * 72 + c8 * 8];
            }
        }
    }
    if (MODE == 1) {
        float cm[4][4];
#pragma unroll
        for (int mt = 0; mt < 4; mt++)
#pragma unroll
            for (int r = 0; r < 4; r++)
                cm[mt][r] = cvec[n * COUT + co0 + wm * 64 + mt * 16 + quad * 4 + r];
        ushort_t* Ls = SH;                  // [64 s][136 co]
#pragma unroll
        for (int mt = 0; mt < 4; mt++)
#pragma unroll
            for (int nt = 0; nt < 2; nt++)
#pragma unroll
                for (int r = 0; r < 4; r++) {
                    float v = silu_mp(acc[mt][nt][r] * cm[mt][r]);
                    Ls[(ws * 32 + nt * 16 + tx) * 136 + wm * 64 + mt * 16 + quad * 4 + r] = f2bs(v);
                }
        __syncthreads();
#pragma unroll
        for (int i = 0; i < 4; i++) {
            int ch = tid + i * 256; int row = ch >> 4, c16 = ch & 15;
            *(uint4*)(OutT + ((size_t)n * SDIM + s0 + row) * 256 + co0 + c16 * 8) = *(uint4*)&Ls[row * 136 + c16 * 8];
        }
    }
    if (MODE == 2) {
        ushort_t* Ls = SH;                  // [64 s][136 co]
#pragma unroll
        for (int mt = 0; mt < 4; mt++)
#pragma unroll
            for (int r = 0; r < 4; r++) {
                int col = wm * 64 + mt * 16 + quad * 4 + r;
                float* xp = RX + ((size_t)n * COUT + co0 + col) * SDIM + s0 + ws * 32;
#pragma unroll
                for (int nt = 0; nt < 2; nt++) {
                    float v = MPA * xp[nt * 16 + tx] + MPB * acc[mt][nt][r];
                    xp[nt * 16 + tx] = v;
                    Ls[(ws * 32 + nt * 16 + tx) * 136 + col] = f2bs(v);
                }
            }
        __syncthreads();
#pragma unroll
        for (int i = 0; i < 4; i++) {
            int ch = tid + i * 256; int row = ch >> 4, c16 = ch & 15;
            *(uint4*)(OutT + ((size_t)n * SDIM + s0 + row) * 256 + co0 + c16 * 8) = *(uint4*)&Ls[row * 136 + c16 * 8];
        }
    }
    if (MODE == 3) {
#pragma unroll
        for (int mt = 0; mt < 4; mt++)
#pragma unroll
            for (int r = 0; r < 4; r++) {
                int co = co0 + wm * 64 + mt * 16 + quad * 4 + r;
                const float* xp = RX + ((size_t)n * COUT + co) * SDIM + s0 + ws * 32;
                float* op = Outf + ((size_t)n * COUT + co) * SDIM + s0 + ws * 32;
#pragma unroll
                for (int nt = 0; nt < 2; nt++) {
                    float v = MPA * xp[nt * 16 + tx] + MPB * acc[mt][nt][r];
                    op[nt * 16 + tx] = fminf(fmaxf(v, -256.f), 256.f);
                }
            }
    }
}

// ---------------- MFMA flash attention, glds-dbuf K/V staging.
// Block = 128 q (4 waves x 32 q), grid (8, head, n) = 512 blocks -> 2 blocks/CU.
// K tile [64key][64c] from qkT; V tile [64c][64key] from vbuf; both glds, XOR-swizzled.
// Q in registers; P per-wave LDS (XOR-swizzled, 64-stride). LDS = 48 KB.
__global__ __launch_bounds__(256, 2) void attn_mfma(const ushort_t* __restrict__ qkT,
                                                    const ushort_t* __restrict__ vbuf,
                                                    ushort_t* __restrict__ aT)
{
    const int n = blockIdx.z, head = blockIdx.y, q0 = blockIdx.x * 128;
    const int tid = threadIdx.x, w = tid >> 6, lane = tid & 63;
    const int tx = lane & 15, quad = lane >> 4;
    const int l8 = lane & 7, ld = lane >> 3;
    const int swz = (l8 ^ ld) * 8;

    __shared__ ushort_t Kst[2][4096];   // [stage][64 key][64 c]
    __shared__ ushort_t Vst[2][4096];   // [stage][64 c][64 key]
    __shared__ ushort_t Pl[4][2048];    // per-wave [32 q][64 k] swizzled / O stage

    const size_t nb = (size_t)n * SDIM;
    const int qw = q0 + w * 32;
    const ushort_t* kg = qkT + nb * 512 + 256 + head * 64;              // row=key, stride 512
    const ushort_t* vg = vbuf + ((size_t)n * 256 + head * 64) * SDIM;   // row=c, stride 1024

    auto stage = [&](int p, int k0) {
#pragma unroll
        for (int j = 0; j < 2; j++) {
            int row0 = w * 16 + j * 8;
            gld16(kg + (size_t)(k0 + row0 + ld) * 512 + swz, &Kst[p][row0 * 64]);
            gld16(vg + (size_t)(row0 + ld) * SDIM + k0 + swz, &Vst[p][row0 * 64]);
        }
    };

    // Q frags direct from global (q pre-scaled by 0.125*log2e)
    s16x8 qf[2][2];
#pragma unroll
    for (int mt = 0; mt < 2; mt++)
#pragma unroll
        for (int kc = 0; kc < 2; kc++)
            qf[mt][kc] = ld16(qkT + (nb + qw + mt * 16 + tx) * 512 + head * 64 + kc * 32 + quad * 8);

    f32x4 acco[2][4];
    float lpart[2][4];
#pragma unroll
    for (int mt = 0; mt < 2; mt++)
#pragma unroll
        for (int nt = 0; nt < 4; nt++) acco[mt][nt] = (f32x4){0.f, 0.f, 0.f, 0.f};
#pragma unroll
    for (int mt = 0; mt < 2; mt++)
#pragma unroll
        for (int r = 0; r < 4; r++) lpart[mt][r] = 0.f;

    stage(0, 0);
    __syncthreads();

    for (int kt = 0; kt < 16; kt++) {
        int p = kt & 1;
        if (kt < 15) stage(p ^ 1, (kt + 1) * 64);

        // S = Q K^T (32q x 64key per wave)
        f32x4 accs[2][4];
#pragma unroll
        for (int mt = 0; mt < 2; mt++)
#pragma unroll
            for (int nt = 0; nt < 4; nt++) accs[mt][nt] = (f32x4){0.f, 0.f, 0.f, 0.f};
#pragma unroll
        for (int kc = 0; kc < 2; kc++) {
            int koff = ((kc * 4 + quad) ^ (tx & 7)) * 8;
#pragma unroll
            for (int nt = 0; nt < 4; nt++) {
                s16x8 kf = ld16(&Kst[p][(nt * 16 + tx) * 64 + koff]);
#pragma unroll
                for (int mt = 0; mt < 2; mt++)
                    accs[mt][nt] = __builtin_amdgcn_mfma_f32_16x16x32_bf16(
                        qf[mt][kc], kf, accs[mt][nt], 0, 0, 0);
            }
        }

        // P = 2^S; row sums; P -> per-wave LDS (chunk-XOR swizzle)
#pragma unroll
        for (int mt = 0; mt < 2; mt++)
#pragma unroll
            for (int r = 0; r < 4; r++) {
                int row = mt * 16 + quad * 4 + r;
                int rx = row & 7;
#pragma unroll
                for (int nt = 0; nt < 4; nt++) {
                    float pv = EXP2F(accs[mt][nt][r]);
                    lpart[mt][r] += pv;
                    int slot = (nt * 2 + (tx >> 3)) ^ rx;
                    Pl[w][row * 64 + slot * 8 + (tx & 7)] = f2bs(pv);
                }
            }
        asm volatile("s_waitcnt lgkmcnt(0)" ::: "memory");

        // O += P V
#pragma unroll
        for (int kc = 0; kc < 2; kc++) {
            int koff = ((kc * 4 + quad) ^ (tx & 7)) * 8;
            s16x8 pf[2];
#pragma unroll
            for (int mt = 0; mt < 2; mt++)
                pf[mt] = ld16(&Pl[w][(mt * 16 + tx) * 64 + koff]);
#pragma unroll
            for (int nt = 0; nt < 4; nt++) {
                s16x8 vf = ld16(&Vst[p][(nt * 16 + tx) * 64 + koff]);
#pragma unroll
                for (int mt = 0; mt < 2; mt++)
                    acco[mt][nt] = __builtin_amdgcn_mfma_f32_16x16x32_bf16(
                        pf[mt], vf, acco[mt][nt], 0, 0, 0);
            }
        }
        __syncthreads();     // all waves done with stage p; prefetch DMA drained here
    }

    float inv[2][4];
#pragma unroll
    for (int mt = 0; mt < 2; mt++)
#pragma unroll
        for (int r = 0; r < 4; r++) {
            float l = lpart[mt][r];
            l += __shfl_xor(l, 1); l += __shfl_xor(l, 2);
            l += __shfl_xor(l, 4); l += __shfl_xor(l, 8);
            inv[mt][r] = 1.0f / l;
        }

    // O stage (swizzled) -> vectorized global write aT[n][s][256]
#pragma unroll
    for (int mt = 0; mt < 2; mt++)
#pragma unroll
        for (int r = 0; r < 4; r++) {
            int row = mt * 16 + quad * 4 + r;
            int rx = row & 7;
#pragma unroll
            for (int nt = 0; nt < 4; nt++) {
                int slot = (nt * 2 + (tx >> 3)) ^ rx;
                Pl[w][row * 64 + slot * 8 + (tx & 7)] = f2bs(acco[mt][nt][r] * inv[mt][r]);
            }
        }
    asm volatile("s_waitcnt lgkmcnt(0)" ::: "memory");
    ushort_t* dst = aT + (nb + qw) * 256 + head * 64;
#pragma unroll
    for (int i = 0; i < 4; i++) {
        int ch = lane + i * 64; int row = ch >> 3, c8 = ch & 7;
        *(uint4*)(dst + (size_t)row * 256 + c8 * 8) = *(uint4*)&Pl[w][row * 64 + (c8 ^ (row & 7)) * 8];
    }
}

extern "C" void kernel_launch(void* const* d_in, const int* in_sizes, int n_in,
                              void* d_out, int out_size, void* d_ws, size_t ws_size,
                              hipStream_t stream)
{
    const float* x      = (const float*)d_in[0];
    const float* emb    = (const float*)d_in[1];
    const float* w_skip = (const float*)d_in[2];
    const float* w_res0 = (const float*)d_in[3];
    const float* w_res1 = (const float*)d_in[4];
    const float* w_emb  = (const float*)d_in[5];
    const float* e_gain = (const float*)d_in[6];
    const float* w_qkv  = (const float*)d_in[7];
    const float* w_proj = (const float*)d_in[8];
    float* out = (float*)d_out;

    char* p = (char*)d_ws;
    auto alloc = [&](size_t bytes) { void* r = (void*)p; p += (bytes + 255) & ~(size_t)255; return r; };
    ushort_t* wskip_bf = (ushort_t*)alloc(256 * 192 * 2);
    ushort_t* wres0_bf = (ushort_t*)alloc(256 * 2304 * 2);
    ushort_t* wres1_bf = (ushort_t*)alloc(256 * 2304 * 2);
    ushort_t* wqkv_bf  = (ushort_t*)alloc(768 * 256 * 2);
    ushort_t* wproj_bf = (ushort_t*)alloc(256 * 256 * 2);
    float*    cvec     = (float*)alloc(16 * 256 * 4);
    ushort_t* zbuf     = (ushort_t*)alloc(1024);
    ushort_t* xT   = (ushort_t*)alloc((size_t)16 * 1024 * 192 * 2);
    ushort_t* sxT  = (ushort_t*)alloc((size_t)16 * 1024 * 256 * 2);
    ushort_t* ysT  = (ushort_t*)alloc((size_t)16 * 1024 * 256 * 2);
    ushort_t* x2T  = (ushort_t*)alloc((size_t)16 * 1024 * 256 * 2);
    ushort_t* aT   = (ushort_t*)alloc((size_t)16 * 1024 * 256 * 2);
    float*    xn   = (float*)alloc((size_t)16 * 256 * 1024 * 4);
    ushort_t* qkT  = (ushort_t*)alloc((size_t)16 * 1024 * 512 * 2);
    ushort_t* vbuf = (ushort_t*)alloc((size_t)16 * 256 * 1024 * 2);

    // fused prologue: all weight norms + x transpose + zbuf
    prep_all<<<2561, 256, 0, stream>>>(w_skip, w_res0, w_res1, w_qkv, w_proj, x,
                                       wskip_bf, wres0_bf, wres1_bf, wqkv_bf, wproj_bf,
                                       xT, (uint4*)zbuf);
    emb_mm<<<16, 256, 0, stream>>>(emb, w_emb, e_gain, cvec);

    skip_fused<<<dim3(32, 1, 16), 256, 0, stream>>>(wskip_bf, xT, xn, sxT);
    gemm_glds<2304, true, 1><<<dim3(16, 2, 16), 256, 0, stream>>>(wres0_bf, sxT, zbuf, nullptr, nullptr, ysT, nullptr, cvec);
    gemm_glds<2304, true, 2><<<dim3(16, 2, 16), 256, 0, stream>>>(wres1_bf, ysT, zbuf, xn, nullptr, x2T, nullptr, nullptr);
    gemm_glds<256, false, 4><<<dim3(16, 6, 16), 256, 0, stream>>>(wqkv_bf, x2T, zbuf, nullptr, nullptr, qkT, vbuf, nullptr);
    attn_mfma<<<dim3(8, 4, 16), 256, 0, stream>>>(qkT, vbuf, aT);
    gemm_glds<256, false, 3><<<dim3(16, 2, 16), 256, 0, stream>>>(wproj_bf, aT, zbuf, xn, out, nullptr, nullptr, nullptr);
}

// Round 9
// 254.597 us; speedup vs baseline: 10.9850x; 1.0052x over previous
//
#include <hip/hip_runtime.h>
#include <math.h>

#define SDIM 1024
#define COUT 256

#define EPSV     1e-4f
#define SILU_INV 1.6778523489932886f   // 1/0.596
#define MPA      0.9191450300180579f   // 0.7/sqrt(0.58)
#define MPB      0.3939192985791677f   // 0.3/sqrt(0.58)
#define LOG2E    1.4426950408889634f

typedef short s16x8 __attribute__((ext_vector_type(8)));
typedef float f32x4 __attribute__((ext_vector_type(4)));
typedef unsigned short ushort_t;

#if __has_builtin(__builtin_amdgcn_exp2f)
#define EXP2F __builtin_amdgcn_exp2f
#else
#define EXP2F exp2f
#endif

__device__ inline ushort_t f2bs(float f) {
    unsigned u = __float_as_uint(f);
    u += 0x7fffu + ((u >> 16) & 1u);        // round-nearest-even
    return (ushort_t)(u >> 16);
}
__device__ inline float silu_mp(float v) { return v * SILU_INV / (1.f + __expf(-v)); }

union F8 { s16x8 v; uint4 q; };
__device__ inline s16x8 ld16(const ushort_t* p) {   // 16B-aligned (global or LDS)
    F8 r; r.q = *(const uint4*)p; return r.v;
}

// async global -> LDS, 16 B per lane. LDS dst = wave-uniform base + lane*16.
typedef const __attribute__((address_space(1))) unsigned int* gas_ptr;
typedef __attribute__((address_space(3))) unsigned int* las_ptr;
__device__ inline void gld16(const void* g, void* l) {
    __builtin_amdgcn_global_load_lds((gas_ptr)g, (las_ptr)l, 16, 0, 0);
}

// ---------------- fused prologue: all weight norms + x transpose + zbuf fill.
// blocks: [0,256) wskip | [256,512) res0 | [512,768) res1 | [768,1536) qkv |
//         [1536,1792) proj | [1792,2560) prep_xT | 2560 zfill
__global__ __launch_bounds__(256) void prep_all(
    const float* __restrict__ w_skip, const float* __restrict__ w_res0,
    const float* __restrict__ w_res1, const float* __restrict__ w_qkv,
    const float* __restrict__ w_proj, const float* __restrict__ x,
    ushort_t* wskip_bf, ushort_t* wres0_bf, ushort_t* wres1_bf,
    ushort_t* wqkv_bf, ushort_t* wproj_bf, ushort_t* xT, uint4* zbuf)
{
    __shared__ float T[64 * 65];
    const int b = blockIdx.x, tid = threadIdx.x;

    if (b >= 2560) {                     // zfill
        if (tid < 64) zbuf[tid] = make_uint4(0u, 0u, 0u, 0u);
        return;
    }
    if (b >= 1792) {                     // prep_xT: [n][192][1024] f32 -> [n][1024][192] bf16
        int b2 = b - 1792;
        int n = b2 / 48, rem = b2 % 48;
        int ci0 = (rem / 16) * 64, s0 = (rem & 15) * 64;
#pragma unroll
        for (int i = 0; i < 16; i++) {
            int ch = tid + i * 256; int row = ch >> 6, cc = ch & 63;
            T[row * 65 + cc] = x[((size_t)n * 192 + ci0 + row) * SDIM + s0 + cc];
        }
        __syncthreads();
#pragma unroll
        for (int i = 0; i < 2; i++) {
            int ch = tid + i * 256; int srow = ch >> 3, c8 = ch & 7;
            ushort_t tmp[8];
#pragma unroll
            for (int j = 0; j < 8; j++) tmp[j] = f2bs(T[(c8 * 8 + j) * 65 + srow]);
            *(uint4*)(xT + ((size_t)n * SDIM + s0 + srow) * 192 + ci0 + c8 * 8) = *(uint4*)tmp;
        }
        return;
    }
    // weight-norm branches
    const float* src; ushort_t* dst; int fanin, mode, o;
    if      (b < 256)  { src = w_skip; dst = wskip_bf; fanin = 192;  mode = 0; o = b; }
    else if (b < 512)  { src = w_res0; dst = wres0_bf; fanin = 2304; mode = 1; o = b - 256; }
    else if (b < 768)  { src = w_res1; dst = wres1_bf; fanin = 2304; mode = 1; o = b - 512; }
    else if (b < 1536) { src = w_qkv;  dst = wqkv_bf;  fanin = 256;  mode = 2; o = b - 768; }
    else               { src = w_proj; dst = wproj_bf; fanin = 256;  mode = 0; o = b - 1536; }

    const float* row = src + (size_t)o * fanin;
    float ss = 0.f;
    for (int i = tid; i < fanin; i += 256) { float v = row[i]; ss += v * v; }
    for (int off = 32; off >= 1; off >>= 1) ss += __shfl_down(ss, off);
    int lane = tid & 63, wv = tid >> 6;
    if (lane == 0) T[wv] = ss;
    __syncthreads();
    float tot = T[0] + T[1] + T[2] + T[3];
    float scale = 1.0f / (EPSV * sqrtf((float)fanin) + sqrtf(tot));
    int orow = o;
    if (mode == 2) { int h = o / 192, rem = o % 192; orow = (rem % 3) * 256 + h * 64 + rem / 3; }
    for (int i = tid; i < fanin; i += 256) {
        int kd = i;
        if (mode == 1) { int ci = i / 9; int r9 = i - ci * 9; kd = r9 * 256 + ci; }
        dst[(size_t)orow * fanin + kd] = f2bs(row[i] * scale);
    }
}

// ---------------- c = emb @ mp_weight(w_emb, gain)^T + 1  (norm fused per thread)
__global__ __launch_bounds__(256) void emb_mm(const float* __restrict__ emb,
                                              const float* __restrict__ w_emb,
                                              const float* __restrict__ gain_ptr,
                                              float* __restrict__ cvec)
{
    int n = blockIdx.x;
    int co = threadIdx.x;
    const float* e  = emb   + (size_t)n * 768;
    const float* wr = w_emb + (size_t)co * 768;
    float ss = 0.f, dot = 0.f;
    for (int i = 0; i < 768; i++) {
        float wv = wr[i];
        ss  = fmaf(wv, wv, ss);
        dot = fmaf(e[i], wv, dot);
    }
    float scale = gain_ptr[0] / (EPSV * sqrtf(768.0f) + sqrtf(ss));
    cvec[n * COUT + co] = dot * scale + 1.0f;
}

// ---------------- fused: x1 = conv1x1(x, wskip); xn = pix_norm(x1); sxT = silu(xn)
__global__ __launch_bounds__(256, 2) void skip_fused(const ushort_t* __restrict__ Wp,
                                                     const ushort_t* __restrict__ xT,
                                                     float* __restrict__ xn,
                                                     ushort_t* __restrict__ sxT)
{
    const int n = blockIdx.z, s0 = blockIdx.x * 32;
    const int tid = threadIdx.x, w = tid >> 6, lane = tid & 63;
    const int tx = lane & 15, quad = lane >> 4;

    __shared__ ushort_t As[256 * 72];
    __shared__ ushort_t Bs[32 * 72];
    __shared__ float csum[4][32];

    f32x4 acc[4][2];
#pragma unroll
    for (int a = 0; a < 4; a++)
#pragma unroll
        for (int b = 0; b < 2; b++) acc[a][b] = (f32x4){0.f, 0.f, 0.f, 0.f};

    for (int k0 = 0; k0 < 192; k0 += 64) {
        __syncthreads();
#pragma unroll
        for (int i = 0; i < 8; i++) {
            int ch = tid + i * 256; int row = ch >> 3, c8 = ch & 7;
            *(uint4*)&As[row * 72 + c8 * 8] = *(const uint4*)(Wp + (size_t)row * 192 + k0 + c8 * 8);
        }
        {
            int row = tid >> 3, c8 = tid & 7;
            *(uint4*)&Bs[row * 72 + c8 * 8] =
                *(const uint4*)(xT + ((size_t)n * SDIM + s0 + row) * 192 + k0 + c8 * 8);
        }
        __syncthreads();
#pragma unroll
        for (int kc = 0; kc < 2; kc++) {
            s16x8 af[4], bf_[2];
#pragma unroll
            for (int mt = 0; mt < 4; mt++) af[mt] = ld16(&As[(w * 64 + mt * 16 + tx) * 72 + kc * 32 + quad * 8]);
#pragma unroll
            for (int nt = 0; nt < 2; nt++) bf_[nt] = ld16(&Bs[(nt * 16 + tx) * 72 + kc * 32 + quad * 8]);
#pragma unroll
            for (int mt = 0; mt < 4; mt++)
#pragma unroll
                for (int nt = 0; nt < 2; nt++)
                    acc[mt][nt] = __builtin_amdgcn_mfma_f32_16x16x32_bf16(af[mt], bf_[nt], acc[mt][nt], 0, 0, 0);
        }
    }

#pragma unroll
    for (int nt = 0; nt < 2; nt++) {
        float s2 = 0.f;
#pragma unroll
        for (int mt = 0; mt < 4; mt++)
#pragma unroll
            for (int r = 0; r < 4; r++) s2 = fmaf(acc[mt][nt][r], acc[mt][nt][r], s2);
        s2 += __shfl_xor(s2, 16); s2 += __shfl_xor(s2, 32);
        if (quad == 0) csum[w][nt * 16 + tx] = s2;
    }
    __syncthreads();
    float f[2];
#pragma unroll
    for (int nt = 0; nt < 2; nt++) {
        int col = nt * 16 + tx;
        float tot = csum[0][col] + csum[1][col] + csum[2][col] + csum[3][col];
        f[nt] = 1.f / (EPSV + sqrtf(tot) * 0.0625f);
    }
    ushort_t* Ls = As;                      // [32 s][264 co]
    float* xb = xn + (size_t)n * COUT * SDIM;
#pragma unroll
    for (int mt = 0; mt < 4; mt++)
#pragma unroll
        for (int r = 0; r < 4; r++) {
            int co = w * 64 + mt * 16 + quad * 4 + r;
#pragma unroll
            for (int nt = 0; nt < 2; nt++) {
                int sp = s0 + nt * 16 + tx;
                float v = acc[mt][nt][r] * f[nt];
                xb[(size_t)co * SDIM + sp] = v;
                Ls[(nt * 16 + tx) * 264 + co] = f2bs(silu_mp(v));
            }
        }
    __syncthreads();
#pragma unroll
    for (int i = 0; i < 4; i++) {
        int ch = tid + i * 256; int row = ch >> 5, c32 = ch & 31;
        *(uint4*)(sxT + ((size_t)n * SDIM + s0 + row) * 256 + c32 * 8) = *(uint4*)&Ls[row * 264 + c32 * 8];
    }
}

// ---------------- bf16 MFMA conv GEMM: glds staging, XOR-swizzled LDS, dbuf,
// 128co x 64s tile, waves 2x2 (wave 64co x 32s), BK=64.
// MODE 1: res0 -> *cvec, silu, OutT bf16 [n][1024][256] (transposed)
// MODE 2: res1 -> x2 = MPA*xn+MPB*acc; xn fp32 in place; OutT bf16 [n][1024][256]
// MODE 3: proj -> Outf = clip(MPA*RX+MPB*acc) fp32 [n][256][1024]
// MODE 4: qkv  -> fused 64-ch norm; q,k (co0<512) -> OutT = qkT[n][1024][512]
//                 (q scaled 0.125*log2e); v (co0>=512) -> Vout = vbuf[n][256][1024]
template<int KDIM, bool GATHER3, int MODE>
__global__ __launch_bounds__(256, 2) void gemm_glds(const ushort_t* __restrict__ Wp,
                                                    const ushort_t* __restrict__ Bsrc,
                                                    const ushort_t* __restrict__ zbuf,
                                                    float* RX, float* Outf,
                                                    ushort_t* OutT, ushort_t* Vout,
                                                    const float* __restrict__ cvec)
{
    const int n = blockIdx.z, co0 = blockIdx.y * 128, s0 = blockIdx.x * 64;
    const int tid = threadIdx.x, w = tid >> 6, lane = tid & 63;
    const int tx = lane & 15, quad = lane >> 4;
    const int wm = w >> 1, ws = w & 1;
    const int l8 = lane & 7, ld = lane >> 3;
    const int swz = (l8 ^ ld) * 8;

    __shared__ ushort_t SH[2 * 12288];      // stage: A[128][64] + B[64][64] = 24 KB

    const ushort_t* bn = Bsrc + (size_t)n * SDIM * 256;

    auto stageA = [&](int p, int k0) {
        ushort_t* Ab = SH + p * 12288;
#pragma unroll
        for (int j = 0; j < 4; j++) {
            int row0 = w * 32 + j * 8;
            gld16(Wp + (size_t)(co0 + row0 + ld) * KDIM + k0 + swz, Ab + row0 * 64);
        }
    };
    auto stageB = [&](int p, int k0) {
        ushort_t* Bb = SH + p * 12288 + 8192;
        int ci0 = k0, dy = 0, dx = 0;
        if (GATHER3) { int seg = k0 >> 8; ci0 = k0 & 255; int s3 = seg / 3; dy = s3 - 1; dx = seg - s3 * 3 - 1; }
#pragma unroll
        for (int j = 0; j < 2; j++) {
            int row0 = w * 16 + j * 8;
            const ushort_t* g;
            if (GATHER3) {
                int pix = s0 + row0 + ld;
                int h = (pix >> 5) + dy, wx = (pix & 31) + dx;
                bool valid = ((unsigned)h < 32u) && ((unsigned)wx < 32u);
                g = valid ? (bn + (size_t)((h << 5) + wx) * 256 + ci0 + swz) : zbuf;
            } else {
                g = bn + (size_t)(s0 + row0 + ld) * 256 + k0 + swz;
            }
            gld16(g, Bb + row0 * 64);
        }
    };

    f32x4 acc[4][2];
#pragma unroll
    for (int a = 0; a < 4; a++)
#pragma unroll
        for (int b = 0; b < 2; b++) acc[a][b] = (f32x4){0.f, 0.f, 0.f, 0.f};

    constexpr int NK = KDIM / 64;
    stageA(0, 0); stageB(0, 0);
    __syncthreads();

    for (int kt = 0; kt < NK; kt++) {
        int p = kt & 1;
        if (kt + 1 < NK) { stageA(p ^ 1, (kt + 1) * 64); stageB(p ^ 1, (kt + 1) * 64); }
        const ushort_t* Ab = SH + p * 12288;
        const ushort_t* Bb = Ab + 8192;
#pragma unroll
        for (int kc = 0; kc < 2; kc++) {
            int koff = ((kc * 4 + quad) ^ (tx & 7)) * 8;
            s16x8 af[4], bfv[2];
#pragma unroll
            for (int mt = 0; mt < 4; mt++) af[mt]  = ld16(&Ab[(wm * 64 + mt * 16 + tx) * 64 + koff]);
#pragma unroll
            for (int nt = 0; nt < 2; nt++) bfv[nt] = ld16(&Bb[(ws * 32 + nt * 16 + tx) * 64 + koff]);
#pragma unroll
            for (int mt = 0; mt < 4; mt++)
#pragma unroll
                for (int nt = 0; nt < 2; nt++)
                    acc[mt][nt] = __builtin_amdgcn_mfma_f32_16x16x32_bf16(af[mt], bfv[nt], acc[mt][nt], 0, 0, 0);
        }
        __syncthreads();
    }

    if (MODE == 4) {
        float scl[2];
#pragma unroll
        for (int nt = 0; nt < 2; nt++) {
            float s2 = 0.f;
#pragma unroll
            for (int mt = 0; mt < 4; mt++)
#pragma unroll
                for (int r = 0; r < 4; r++) s2 = fmaf(acc[mt][nt][r], acc[mt][nt][r], s2);
            s2 += __shfl_xor(s2, 16); s2 += __shfl_xor(s2, 32);
            float fac = (co0 < 256) ? (0.125f * LOG2E) : 1.0f;
            scl[nt] = fac / (EPSV + sqrtf(s2) * 0.125f);
        }
#pragma unroll
        for (int mt = 0; mt < 4; mt++)
#pragma unroll
            for (int nt = 0; nt < 2; nt++)
#pragma unroll
                for (int r = 0; r < 4; r++) acc[mt][nt][r] *= scl[nt];

        if (co0 < 512) {      // q,k: transposed -> qkT[n][s][512]
            ushort_t* Ls = SH;                  // [64 s][136 co]
#pragma unroll
            for (int mt = 0; mt < 4; mt++)
#pragma unroll
                for (int nt = 0; nt < 2; nt++)
#pragma unroll
                    for (int r = 0; r < 4; r++)
                        Ls[(ws * 32 + nt * 16 + tx) * 136 + wm * 64 + mt * 16 + quad * 4 + r] = f2bs(acc[mt][nt][r]);
            __syncthreads();
#pragma unroll
            for (int i = 0; i < 4; i++) {
                int ch = tid + i * 256; int row = ch >> 4, c16 = ch & 15;
                *(uint4*)(OutT + ((size_t)n * SDIM + s0 + row) * 512 + co0 + c16 * 8) = *(uint4*)&Ls[row * 136 + c16 * 8];
            }
        } else {              // v: [co][s] -> vbuf[n][256][1024]
            ushort_t* Ls = SH;                  // [128 co][72 s]
#pragma unroll
            for (int mt = 0; mt < 4; mt++)
#pragma unroll
                for (int nt = 0; nt < 2; nt++)
#pragma unroll
                    for (int r = 0; r < 4; r++)
                        Ls[(wm * 64 + mt * 16 + quad * 4 + r) * 72 + ws * 32 + nt * 16 + tx] = f2bs(acc[mt][nt][r]);
            __syncthreads();
#pragma unroll
            for (int i = 0; i < 4; i++) {
                int ch = tid + i * 256; int row = ch >> 3, c8 = ch & 7;
                *(uint4*)(Vout + ((size_t)n * 256 + (co0 - 512) + row) * SDIM + s0 + c8 * 8) = *(uint4*)&Ls[row * 72 + c8 * 8];
            }
        }
    }
    if (MODE == 1) {
        float cm[4][4];
#pragma unroll
        for (int mt = 0; mt < 4; mt++)
#pragma unroll
            for (int r = 0; r < 4; r++)
                cm[mt][r] = cvec[n * COUT + co0 + wm * 64 + mt * 16 + quad * 4 + r];
        ushort_t* Ls = SH;                  // [64 s][136 co]
#pragma unroll
        for (int mt = 0; mt < 4; mt++)
#pragma unroll
            for (int nt = 0; nt < 2; nt++)
#pragma unroll
                for (int r = 0; r < 4; r++) {
                    float v = silu_mp(acc[mt][nt][r] * cm[mt][r]);
                    Ls[(ws * 32 + nt * 16 + tx) * 136 + wm * 64 + mt * 16 + quad * 4 + r] = f2bs(v);
                }
        __syncthreads();
#pragma unroll
        for (int i = 0; i < 4; i++) {
            int ch = tid + i * 256; int row = ch >> 4, c16 = ch & 15;
            *(uint4*)(OutT + ((size_t)n * SDIM + s0 + row) * 256 + co0 + c16 * 8) = *(uint4*)&Ls[row * 136 + c16 * 8];
        }
    }
    if (MODE == 2) {
        ushort_t* Ls = SH;                  // [64 s][136 co]
#pragma unroll
        for (int mt = 0; mt < 4; mt++)
#pragma unroll
            for (int r = 0; r < 4; r++) {
                int col = wm * 64 + mt * 16 + quad * 4 + r;
                float* xp = RX + ((size_t)n * COUT + co0 + col) * SDIM + s0 + ws * 32;
#pragma unroll
                for (int nt = 0; nt < 2; nt++) {
                    float v = MPA * xp[nt * 16 + tx] + MPB * acc[mt][nt][r];
                    xp[nt * 16 + tx] = v;
                    Ls[(ws * 32 + nt * 16 + tx) * 136 + col] = f2bs(v);
                }
            }
        __syncthreads();
#pragma unroll
        for (int i = 0; i < 4; i++) {
            int ch = tid + i * 256; int row = ch >> 4, c16 = ch & 15;
            *(uint4*)(OutT + ((size_t)n * SDIM + s0 + row) * 256 + co0 + c16 * 8) = *(uint4*)&Ls[row * 136 + c16 * 8];
        }
    }
    if (MODE == 3) {
#pragma unroll
        for (int mt = 0; mt < 4; mt++)
#pragma unroll
            for (int r = 0; r < 4; r++) {
                int co = co0 + wm * 64 + mt * 16 + quad * 4 + r;
                const float* xp = RX + ((size_t)n * COUT + co) * SDIM + s0 + ws * 32;
                float* op = Outf + ((size_t)n * COUT + co) * SDIM + s0 + ws * 32;
#pragma unroll
                for (int nt = 0; nt < 2; nt++) {
                    float v = MPA * xp[nt * 16 + tx] + MPB * acc[mt][nt][r];
                    op[nt * 16 + tx] = fminf(fmaxf(v, -256.f), 256.f);
                }
            }
    }
}

// ---------------- MFMA flash attention, glds-dbuf K/V staging + pipelined P.
// Block = 128 q (4 waves x 32 q), grid (8, head, n) = 512 blocks -> 2 blocks/CU.
// Per iter: PV(kt-1) | barrier | stage(kt+1) | QK(kt), exp, P->Pw[p].
// P write->read spans one iteration (dbuf per-wave P): no in-iteration LDS drain;
// PV MFMAs overlap next tile's exp VALU chain. LDS = 64 KB -> 2 blocks/CU.
__global__ __launch_bounds__(256, 2) void attn_mfma(const ushort_t* __restrict__ qkT,
                                                    const ushort_t* __restrict__ vbuf,
                                                    ushort_t* __restrict__ aT)
{
    const int n = blockIdx.z, head = blockIdx.y, q0 = blockIdx.x * 128;
    const int tid = threadIdx.x, w = tid >> 6, lane = tid & 63;
    const int tx = lane & 15, quad = lane >> 4;
    const int l8 = lane & 7, ld = lane >> 3;
    const int swz = (l8 ^ ld) * 8;

    __shared__ ushort_t Kst[2][4096];   // [stage][64 key][64 c]
    __shared__ ushort_t Vst[2][4096];   // [stage][64 c][64 key]
    __shared__ ushort_t Pw[8][2048];    // [wave*2+stage][32 q][64 k] swizzled / O stage

    const size_t nb = (size_t)n * SDIM;
    const int qw = q0 + w * 32;
    const ushort_t* kg = qkT + nb * 512 + 256 + head * 64;              // row=key, stride 512
    const ushort_t* vg = vbuf + ((size_t)n * 256 + head * 64) * SDIM;   // row=c, stride 1024

    auto stage = [&](int p, int k0) {
#pragma unroll
        for (int j = 0; j < 2; j++) {
            int row0 = w * 16 + j * 8;
            gld16(kg + (size_t)(k0 + row0 + ld) * 512 + swz, &Kst[p][row0 * 64]);
            gld16(vg + (size_t)(row0 + ld) * SDIM + k0 + swz, &Vst[p][row0 * 64]);
        }
    };
    auto pv_step = [&](int pb, f32x4 (&acco)[2][4]) {
        const ushort_t* Pp = Pw[w * 2 + pb];
#pragma unroll
        for (int kc = 0; kc < 2; kc++) {
            int koff = ((kc * 4 + quad) ^ (tx & 7)) * 8;
            s16x8 pf[2];
#pragma unroll
            for (int mt = 0; mt < 2; mt++)
                pf[mt] = ld16(&Pp[(mt * 16 + tx) * 64 + koff]);
#pragma unroll
            for (int nt = 0; nt < 4; nt++) {
                s16x8 vf = ld16(&Vst[pb][(nt * 16 + tx) * 64 + koff]);
#pragma unroll
                for (int mt = 0; mt < 2; mt++)
                    acco[mt][nt] = __builtin_amdgcn_mfma_f32_16x16x32_bf16(
                        pf[mt], vf, acco[mt][nt], 0, 0, 0);
            }
        }
    };

    // Q frags direct from global (q pre-scaled by 0.125*log2e)
    s16x8 qf[2][2];
#pragma unroll
    for (int mt = 0; mt < 2; mt++)
#pragma unroll
        for (int kc = 0; kc < 2; kc++)
            qf[mt][kc] = ld16(qkT + (nb + qw + mt * 16 + tx) * 512 + head * 64 + kc * 32 + quad * 8);

    f32x4 acco[2][4];
    float lpart[2][4];
#pragma unroll
    for (int mt = 0; mt < 2; mt++)
#pragma unroll
        for (int nt = 0; nt < 4; nt++) acco[mt][nt] = (f32x4){0.f, 0.f, 0.f, 0.f};
#pragma unroll
    for (int mt = 0; mt < 2; mt++)
#pragma unroll
        for (int r = 0; r < 4; r++) lpart[mt][r] = 0.f;

    stage(0, 0);

    for (int kt = 0; kt < 16; kt++) {
        int p = kt & 1;
        // (a) PV for previous tile (reads Pw[p^1], Vst[p^1]; both written last iter)
        if (kt > 0) pv_step(p ^ 1, acco);
        __syncthreads();            // waves done with p^1; drains DMA for Kst/Vst[p]
        // (b) prefetch next tile into p^1
        if (kt < 15) stage(p ^ 1, (kt + 1) * 64);

        // (c) S = Q K^T (32q x 64key per wave) from Kst[p]
        f32x4 accs[2][4];
#pragma unroll
        for (int mt = 0; mt < 2; mt++)
#pragma unroll
            for (int nt = 0; nt < 4; nt++) accs[mt][nt] = (f32x4){0.f, 0.f, 0.f, 0.f};
#pragma unroll
        for (int kc = 0; kc < 2; kc++) {
            int koff = ((kc * 4 + quad) ^ (tx & 7)) * 8;
#pragma unroll
            for (int nt = 0; nt < 4; nt++) {
                s16x8 kf = ld16(&Kst[p][(nt * 16 + tx) * 64 + koff]);
#pragma unroll
                for (int mt = 0; mt < 2; mt++)
                    accs[mt][nt] = __builtin_amdgcn_mfma_f32_16x16x32_bf16(
                        qf[mt][kc], kf, accs[mt][nt], 0, 0, 0);
            }
        }
        // P = 2^S; row sums; P -> Pw[p] (chunk-XOR swizzle); consumed next iter
#pragma unroll
        for (int mt = 0; mt < 2; mt++)
#pragma unroll
            for (int r = 0; r < 4; r++) {
                int row = mt * 16 + quad * 4 + r;
                int rx = row & 7;
#pragma unroll
                for (int nt = 0; nt < 4; nt++) {
                    float pv = EXP2F(accs[mt][nt][r]);
                    lpart[mt][r] += pv;
                    int slot = (nt * 2 + (tx >> 3)) ^ rx;
                    Pw[w * 2 + p][row * 64 + slot * 8 + (tx & 7)] = f2bs(pv);
                }
            }
    }
    // final PV for tile 15 (p=1); its P writes are this wave's own, lgkm-ordered
    asm volatile("s_waitcnt lgkmcnt(0)" ::: "memory");
    pv_step(1, acco);

    float inv[2][4];
#pragma unroll
    for (int mt = 0; mt < 2; mt++)
#pragma unroll
        for (int r = 0; r < 4; r++) {
            float l = lpart[mt][r];
            l += __shfl_xor(l, 1); l += __shfl_xor(l, 2);
            l += __shfl_xor(l, 4); l += __shfl_xor(l, 8);
            inv[mt][r] = 1.0f / l;
        }

    // O stage (swizzled) -> vectorized global write aT[n][s][256]
#pragma unroll
    for (int mt = 0; mt < 2; mt++)
#pragma unroll
        for (int r = 0; r < 4; r++) {
            int row = mt * 16 + quad * 4 + r;
            int rx = row & 7;
#pragma unroll
            for (int nt = 0; nt < 4; nt++) {
                int slot = (nt * 2 + (tx >> 3)) ^ rx;
                Pw[w * 2][row * 64 + slot * 8 + (tx & 7)] = f2bs(acco[mt][nt][r] * inv[mt][r]);
            }
        }
    asm volatile("s_waitcnt lgkmcnt(0)" ::: "memory");
    ushort_t* dst = aT + (nb + qw) * 256 + head * 64;
#pragma unroll
    for (int i = 0; i < 4; i++) {
        int ch = lane + i * 64; int row = ch >> 3, c8 = ch & 7;
        *(uint4*)(dst + (size_t)row * 256 + c8 * 8) = *(uint4*)&Pw[w * 2][row * 64 + (c8 ^ (row & 7)) * 8];
    }
}

extern "C" void kernel_launch(void* const* d_in, const int* in_sizes, int n_in,
                              void* d_out, int out_size, void* d_ws, size_t ws_size,
                              hipStream_t stream)
{
    const float* x      = (const float*)d_in[0];
    const float* emb    = (const float*)d_in[1];
    const float* w_skip = (const float*)d_in[2];
    const float* w_res0 = (const float*)d_in[3];
    const float* w_res1 = (const float*)d_in[4];
    const float* w_emb  = (const float*)d_in[5];
    const float* e_gain = (const float*)d_in[6];
    const float* w_qkv  = (const float*)d_in[7];
    const float* w_proj = (const float*)d_in[8];
    float* out = (float*)d_out;

    char* p = (char*)d_ws;
    auto alloc = [&](size_t bytes) { void* r = (void*)p; p += (bytes + 255) & ~(size_t)255; return r; };
    ushort_t* wskip_bf = (ushort_t*)alloc(256 * 192 * 2);
    ushort_t* wres0_bf = (ushort_t*)alloc(256 * 2304 * 2);
    ushort_t* wres1_bf = (ushort_t*)alloc(256 * 2304 * 2);
    ushort_t* wqkv_bf  = (ushort_t*)alloc(768 * 256 * 2);
    ushort_t* wproj_bf = (ushort_t*)alloc(256 * 256 * 2);
    float*    cvec     = (float*)alloc(16 * 256 * 4);
    ushort_t* zbuf     = (ushort_t*)alloc(1024);
    ushort_t* xT   = (ushort_t*)alloc((size_t)16 * 1024 * 192 * 2);
    ushort_t* sxT  = (ushort_t*)alloc((size_t)16 * 1024 * 256 * 2);
    ushort_t* ysT  = (ushort_t*)alloc((size_t)16 * 1024 * 256 * 2);
    ushort_t* x2T  = (ushort_t*)alloc((size_t)16 * 1024 * 256 * 2);
    ushort_t* aT   = (ushort_t*)alloc((size_t)16 * 1024 * 256 * 2);
    float*    xn   = (float*)alloc((size_t)16 * 256 * 1024 * 4);
    ushort_t* qkT  = (ushort_t*)alloc((size_t)16 * 1024 * 512 * 2);
    ushort_t* vbuf = (ushort_t*)alloc((size_t)16 * 256 * 1024 * 2);

    // fused prologue: all weight norms + x transpose + zbuf
    prep_all<<<2561, 256, 0, stream>>>(w_skip, w_res0, w_res1, w_qkv, w_proj, x,
                                       wskip_bf, wres0_bf, wres1_bf, wqkv_bf, wproj_bf,
                                       xT, (uint4*)zbuf);
    emb_mm<<<16, 256, 0, stream>>>(emb, w_emb, e_gain, cvec);

    skip_fused<<<dim3(32, 1, 16), 256, 0, stream>>>(wskip_bf, xT, xn, sxT);
    gemm_glds<2304, true, 1><<<dim3(16, 2, 16), 256, 0, stream>>>(wres0_bf, sxT, zbuf, nullptr, nullptr, ysT, nullptr, cvec);
    gemm_glds<2304, true, 2><<<dim3(16, 2, 16), 256, 0, stream>>>(wres1_bf, ysT, zbuf, xn, nullptr, x2T, nullptr, nullptr);
    gemm_glds<256, false, 4><<<dim3(16, 6, 16), 256, 0, stream>>>(wqkv_bf, x2T, zbuf, nullptr, nullptr, qkT, vbuf, nullptr);
    attn_mfma<<<dim3(8, 4, 16), 256, 0, stream>>>(qkT, vbuf, aT);
    gemm_glds<256, false, 3><<<dim3(16, 2, 16), 256, 0, stream>>>(wproj_bf, aT, zbuf, xn, out, nullptr, nullptr, nullptr);
}